// Round 3
// baseline (458.335 us; speedup 1.0000x reference)
//
#include <hip/hip_runtime.h>
#include <hip/hip_bf16.h>
#include <hip/hip_fp16.h>

// R10:
//  - full_attn v6: K fragments loaded DIRECTLY from global (L2/L3-resident,
//    bit-identical bytes) instead of via LDS — removes the 4x-redundant
//    per-wave kf LDS reads, all K staging writes, and halves LDS to 18.4KB.
//    V keeps the R9 double-buffer + 1 barrier/tile (transpose needs LDS).
//  - prep_all: fuses f32_to_f16(x/Wqkv/Wf) + transpose_wo + bias_fuse into
//    ONE dispatch (block-range dispatch; all 5 ops are mutually independent).
//    13 -> 9 dispatches total.
//  - gemm_mfma_nt_w64: 128x64-tile GEMM for the final projection (N=512):
//    grid 1024 blocks = 4 blocks/CU (was 2) on the K=1536 deep loop.
// qkv GEMM and win_attn unchanged from R9.

using f16 = _Float16;
typedef _Float16 f16x8 __attribute__((ext_vector_type(8)));
typedef _Float16 f16x2 __attribute__((ext_vector_type(2)));
typedef float    f32x4 __attribute__((ext_vector_type(4)));

__device__ inline void storeC(float* p, float v) { *p = v; }
__device__ inline void storeC(f16* p, float v)   { *p = (f16)v; }

// async 16B global -> LDS (dest = wave-uniform base + lane*16)
__device__ inline void async_cp16(const f16* g, f16* l) {
    __builtin_amdgcn_global_load_lds(
        (const __attribute__((address_space(1))) unsigned int*)g,
        (__attribute__((address_space(3))) unsigned int*)l,
        16, 0, 0);
}

// ---------------------------------------------------------------------------
// prep_all: block-range fused {x->f16, Wqkv->f16, Wf->f16, Wo transpose,
// bias fuse}.  All sections independent; grid = 4096+1152+384+768+128 = 6528.
// ---------------------------------------------------------------------------
__global__ __launch_bounds__(256) void prep_all(
    const float* __restrict__ x, const float* __restrict__ Wqkv,
    const float* __restrict__ Wf, const float* __restrict__ Wo,
    const float* __restrict__ bo, const float* __restrict__ bfv,
    f16* __restrict__ xh, f16* __restrict__ wqkvh, f16* __restrict__ wfh,
    f16* __restrict__ WoT, float* __restrict__ bp)
{
    __shared__ float t[32][33];
    const int bid = blockIdx.x;
    const int tid = threadIdx.x;

    if (bid < 5632) {
        // fp32 -> fp16, 2048 elements per block
        const float* in; f16* outp; int base;
        if (bid < 4096)      { in = x;    outp = xh;    base = bid; }
        else if (bid < 5248) { in = Wqkv; outp = wqkvh; base = bid - 4096; }
        else                 { in = Wf;   outp = wfh;   base = bid - 5248; }
        int i = (base * 256 + tid) * 8;
        float4 a = *(const float4*)(in + i);
        float4 b = *(const float4*)(in + i + 4);
        f16x8 h = { (f16)a.x, (f16)a.y, (f16)a.z, (f16)a.w,
                    (f16)b.x, (f16)b.y, (f16)b.z, (f16)b.w };
        *(f16x8*)(outp + i) = h;
    } else if (bid < 6400) {
        // Wo[z] (512x512 f32) -> WoT[z] f16 transposed
        const int idx = bid - 5632;
        const int z  = idx >> 8;
        const int bx = (idx & 15) * 32;
        const int by = ((idx >> 4) & 15) * 32;
        const int tx = tid & 31;
        const int ty = tid >> 5;
#pragma unroll
        for (int r = ty; r < 32; r += 8)
            t[r][tx] = Wo[(size_t)z * 262144 + (by + r) * 512 + bx + tx];
        __syncthreads();
#pragma unroll
        for (int r = ty; r < 32; r += 8)
            WoT[(size_t)z * 262144 + (bx + r) * 512 + by + tx] = (f16)t[tx][r];
    } else {
        // b'[o] = bf[o] + sum_j Wf[o][j]*bo[j], one wave per o
        const int o = (bid - 6400) * 4 + (tid >> 6);
        const int lane = tid & 63;
        float s = 0.f;
        for (int j = lane; j < 1536; j += 64) s += Wf[o * 1536 + j] * bo[j];
#pragma unroll
        for (int msk = 1; msk < 64; msk <<= 1) s += __shfl_xor(s, msk, 64);
        if (lane == 0) bp[o] = s + bfv[o];
    }
}

// ---------------------------------------------------------------------------
// MFMA GEMM:  C[m,n] = sum_k A[m,k]*B[n,k] (+ bias[n])   (NT, fp16 in)
// 128x128 tile. z-batched via blockIdx.z. bias nullable.
// ---------------------------------------------------------------------------
template <typename TC>
__global__ __launch_bounds__(256) void gemm_mfma_nt(
    const f16* __restrict__ A, int lda, long azs,
    const f16* __restrict__ B, int ldb, long bzs,
    const float* __restrict__ bias,
    TC* __restrict__ C, int ldc, long czs,
    int K)
{
    __shared__ __align__(16) f16 As[128 * 32];
    __shared__ __align__(16) f16 Bs[128 * 32];

    const int tid  = threadIdx.x;
    const int lane = tid & 63;
    const int wave = tid >> 6;
    const int wm = (wave >> 1) * 64;
    const int wn = (wave & 1) * 64;
    const int bm = blockIdx.y * 128;
    const int bn = blockIdx.x * 128;
    const int z  = blockIdx.z;

    const int srow = tid >> 2;
    const int scol = (tid & 3) * 8;

    const f16* Ag = A + (size_t)z * azs + (size_t)(bm + srow) * lda + scol;
    const f16* Bg = B + (size_t)z * bzs + (size_t)(bn + srow) * ldb + scol;
    f16* AsW = As + srow * 32 + scol;
    f16* BsW = Bs + srow * 32 + scol;

    f32x4 acc[4][4];
#pragma unroll
    for (int i = 0; i < 4; ++i)
#pragma unroll
        for (int j = 0; j < 4; ++j)
            acc[i][j] = (f32x4){0.f, 0.f, 0.f, 0.f};

    const int fr = lane & 15;
    const int fk = (lane >> 4) * 8;

    for (int k0 = 0; k0 < K; k0 += 32) {
        __syncthreads();
        async_cp16(Ag + k0, AsW);
        async_cp16(Ag + k0 + (size_t)64 * lda, AsW + 64 * 32);
        async_cp16(Bg + k0, BsW);
        async_cp16(Bg + k0 + (size_t)64 * ldb, BsW + 64 * 32);
        __syncthreads();

        f16x8 af[4], bfr[4];
#pragma unroll
        for (int i = 0; i < 4; ++i)
            af[i] = *(const f16x8*)&As[(wm + i * 16 + fr) * 32 + fk];
#pragma unroll
        for (int j = 0; j < 4; ++j)
            bfr[j] = *(const f16x8*)&Bs[(wn + j * 16 + fr) * 32 + fk];
#pragma unroll
        for (int i = 0; i < 4; ++i)
#pragma unroll
            for (int j = 0; j < 4; ++j)
                acc[i][j] = __builtin_amdgcn_mfma_f32_16x16x32_f16(
                    af[i], bfr[j], acc[i][j], 0, 0, 0);
    }

    const int cn  = lane & 15;
    const int cr4 = (lane >> 4) * 4;
#pragma unroll
    for (int i = 0; i < 4; ++i) {
#pragma unroll
        for (int j = 0; j < 4; ++j) {
            const int col = bn + wn + j * 16 + cn;
            const float bv = bias ? bias[col] : 0.f;
#pragma unroll
            for (int r = 0; r < 4; ++r) {
                const int row = bm + wm + i * 16 + cr4 + r;
                storeC(&C[(size_t)z * czs + (size_t)row * ldc + col],
                       acc[i][j][r] + bv);
            }
        }
    }
}

// ---------------------------------------------------------------------------
// MFMA GEMM, 128x64 tile (for narrow-N outputs; 4 waves stacked in M).
// ---------------------------------------------------------------------------
template <typename TC>
__global__ __launch_bounds__(256) void gemm_mfma_nt_w64(
    const f16* __restrict__ A, int lda,
    const f16* __restrict__ B, int ldb,
    const float* __restrict__ bias,
    TC* __restrict__ C, int ldc,
    int K)
{
    __shared__ __align__(16) f16 As[128 * 32];
    __shared__ __align__(16) f16 Bs[64 * 32];

    const int tid  = threadIdx.x;
    const int lane = tid & 63;
    const int wave = tid >> 6;
    const int wm = wave * 32;
    const int bm = blockIdx.y * 128;
    const int bn = blockIdx.x * 64;

    const int srow = tid >> 2;
    const int scol = (tid & 3) * 8;

    const f16* Ag = A + (size_t)(bm + srow) * lda + scol;
    const f16* Bg = B + (size_t)(bn + srow) * ldb + scol;
    f16* AsW = As + srow * 32 + scol;
    f16* BsW = Bs + srow * 32 + scol;

    f32x4 acc[2][4];
#pragma unroll
    for (int i = 0; i < 2; ++i)
#pragma unroll
        for (int j = 0; j < 4; ++j)
            acc[i][j] = (f32x4){0.f, 0.f, 0.f, 0.f};

    const int fr = lane & 15;
    const int fk = (lane >> 4) * 8;

    for (int k0 = 0; k0 < K; k0 += 32) {
        __syncthreads();
        async_cp16(Ag + k0, AsW);
        async_cp16(Ag + k0 + (size_t)64 * lda, AsW + 64 * 32);
        async_cp16(Bg + k0, BsW);
        __syncthreads();

        f16x8 af[2], bfr[4];
#pragma unroll
        for (int i = 0; i < 2; ++i)
            af[i] = *(const f16x8*)&As[(wm + i * 16 + fr) * 32 + fk];
#pragma unroll
        for (int j = 0; j < 4; ++j)
            bfr[j] = *(const f16x8*)&Bs[(j * 16 + fr) * 32 + fk];
#pragma unroll
        for (int i = 0; i < 2; ++i)
#pragma unroll
            for (int j = 0; j < 4; ++j)
                acc[i][j] = __builtin_amdgcn_mfma_f32_16x16x32_f16(
                    af[i], bfr[j], acc[i][j], 0, 0, 0);
    }

    const int cn  = lane & 15;
    const int cr4 = (lane >> 4) * 4;
#pragma unroll
    for (int i = 0; i < 2; ++i) {
#pragma unroll
        for (int j = 0; j < 4; ++j) {
            const int col = bn + j * 16 + cn;
            const float bv = bias ? bias[col] : 0.f;
#pragma unroll
            for (int r = 0; r < 4; ++r) {
                const int row = bm + wm + i * 16 + cr4 + r;
                storeC(&C[(size_t)row * ldc + col], acc[i][j][r] + bv);
            }
        }
    }
}

// ---------------------------------------------------------------------------
// Windowed causal attention via MFMA (unchanged from R9).
// ---------------------------------------------------------------------------
__global__ __launch_bounds__(256) void win_attn_mfma(
    const f16* __restrict__ qkv, f16* __restrict__ out, int w)
{
    __shared__ __align__(16) f16 Vs[4][64 * 40];   // per-wave [dim64][key32]
    __shared__ __align__(16) f16 Ps[4][16 * 40];   // per-wave [q16][key32]

    const int tid  = threadIdx.x;
    const int lane = tid & 63;
    const int wave = tid >> 6;
    const int b  = blockIdx.y;
    const int h  = blockIdx.z;
    const int q0 = (blockIdx.x * 4 + wave) * 16;
    const size_t bs = (size_t)b * 1024;

    const int fr  = lane & 15;
    const int grp = lane >> 4;
    const int fk8 = grp * 8;

    // Q A-frags, scaled by 1/8 * log2(e) so p = exp2(s)
    f16x8 aq[2];
    {
        const f16* qp = qkv + (bs + q0 + fr) * 1536 + h * 64 + fk8;
        aq[0] = *(const f16x8*)qp;
        aq[1] = *(const f16x8*)(qp + 32);
#pragma unroll
        for (int e = 0; e < 8; ++e) {
            aq[0][e] *= (f16)0.18033688;
            aq[1][e] *= (f16)0.18033688;
        }
    }

    // K B-frags, 2 groups of 16 keys (rows clamped; clamped keys get P=0)
    f16x8 bk[2][2];
#pragma unroll
    for (int g = 0; g < 2; ++g) {
        int krow = q0 - 16 + g * 16 + fr;
        int kcl  = krow < 0 ? 0 : krow;
        const f16* kp = qkv + (bs + kcl) * 1536 + 512 + h * 64 + fk8;
        bk[g][0] = *(const f16x8*)kp;
        bk[g][1] = *(const f16x8*)(kp + 32);
    }

    // stage V transposed into wave-private LDS: Vs[d][key], 32 keys
    {
        const int vk = lane & 31;
        const int vd = (lane >> 5) * 32;
        int vrow = q0 - 16 + vk;
        int vcl  = vrow < 0 ? 0 : vrow;
        const f16* vp = qkv + (bs + vcl) * 1536 + 1024 + h * 64 + vd;
        f16* vsw = Vs[wave];
#pragma unroll
        for (int t = 0; t < 4; ++t) {
            f16x8 vv = *(const f16x8*)(vp + t * 8);
#pragma unroll
            for (int e = 0; e < 8; ++e)
                vsw[(vd + t * 8 + e) * 40 + vk] = vv[e];
        }
    }

    // QK^T: 16q x 32keys, 4 MFMAs
    f32x4 s[2];
#pragma unroll
    for (int g = 0; g < 2; ++g) {
        f32x4 z = (f32x4){0.f, 0.f, 0.f, 0.f};
        z = __builtin_amdgcn_mfma_f32_16x16x32_f16(aq[0], bk[g][0], z, 0, 0, 0);
        s[g] = __builtin_amdgcn_mfma_f32_16x16x32_f16(aq[1], bk[g][1], z, 0, 0, 0);
    }

    // mask: 0 <= q-k < w AND absolute key position >= 0, then flat exp2
    float l[4] = {0.f, 0.f, 0.f, 0.f};
#pragma unroll
    for (int g = 0; g < 2; ++g) {
        const int kpos = q0 - 16 + g * 16 + fr;    // absolute key position
#pragma unroll
        for (int r = 0; r < 4; ++r) {
            const int diff = (grp * 4 + r) - (g * 16 + fr) + 16;   // q - k
            const bool ok = (diff >= 0) && (diff < w) && (kpos >= 0);
            float p = ok ? exp2f(fminf(s[g][r], 15.9f)) : 0.f;
            l[r] += p;
            Ps[wave][(grp * 4 + r) * 40 + g * 16 + fr] = (f16)p;
        }
    }

    __builtin_amdgcn_wave_barrier();   // wave-local LDS writes before reads

    // PV: O[16q][64d] = P(16x32) * V^T, 4 MFMAs (one K=32 contraction each)
    f16x8 pa = *(const f16x8*)&Ps[wave][fr * 40 + fk8];
    f32x4 acc[4];
#pragma unroll
    for (int j = 0; j < 4; ++j) {
        f16x8 bv = *(const f16x8*)&Vs[wave][(j * 16 + fr) * 40 + fk8];
        f32x4 z = (f32x4){0.f, 0.f, 0.f, 0.f};
        acc[j] = __builtin_amdgcn_mfma_f32_16x16x32_f16(pa, bv, z, 0, 0, 0);
    }

    // reduce l across the 16-lane group, write O
#pragma unroll
    for (int r = 0; r < 4; ++r)
#pragma unroll
        for (int msk = 1; msk < 16; msk <<= 1)
            l[r] += __shfl_xor(l[r], msk, 64);

#pragma unroll
    for (int j = 0; j < 4; ++j)
#pragma unroll
        for (int r = 0; r < 4; ++r) {
            const int q = q0 + grp * 4 + r;
            out[(bs + q) * 1536 + h * 64 + j * 16 + fr] = (f16)(acc[j][r] / l[r]);
        }
}

// ---------------------------------------------------------------------------
// Full attention, MFMA flash v6: K fragments direct from global (no K LDS),
// V double-buffered in LDS, register P via permlane swaps, l via ones-MFMA.
// ---------------------------------------------------------------------------
__global__ __launch_bounds__(256, 4) void full_attn_mfma(
    const f16* __restrict__ qkv, f16* __restrict__ out)
{
    __shared__ __align__(16) f16 Vs[2][64 * 72];   // [d][key]

    const int tid  = threadIdx.x;
    const int lane = tid & 63;
    const int wave = tid >> 6;
    const int q0 = blockIdx.x * 128;
    const int b  = blockIdx.y;
    const int h  = blockIdx.z;
    const size_t bs = (size_t)b * 1024;

    const int fr  = lane & 15;
    const int grp = lane >> 4;
    const int fk8 = grp * 8;

    // Q B-frags (rows = queries), scaled by 1/8 * log2(e) so p = exp2(s)
    f16x8 aq[2][2];
#pragma unroll
    for (int qt = 0; qt < 2; ++qt) {
        const f16* qp = qkv + (bs + q0 + wave * 32 + qt * 16 + fr) * 1536
                        + h * 64 + fk8;
        aq[qt][0] = *(const f16x8*)qp;
        aq[qt][1] = *(const f16x8*)(qp + 32);
#pragma unroll
        for (int e = 0; e < 8; ++e) {
            aq[qt][0][e] *= (f16)0.18033688;
            aq[qt][1][e] *= (f16)0.18033688;
        }
    }

    // all-ones B-fragment for the l-MFMA (C[q][n] = sum_k P[q][k])
    f16x8 onesf;
#pragma unroll
    for (int e = 0; e < 8; ++e) onesf[e] = (f16)1.0f;

    const f32x4 fz = (f32x4){0.f, 0.f, 0.f, 0.f};
    f32x4 lacc[2] = {fz, fz};
    f32x4 acc[2][4];
#pragma unroll
    for (int qt = 0; qt < 2; ++qt)
#pragma unroll
        for (int j = 0; j < 4; ++j)
            acc[qt][j] = fz;

    // V staging partition: thread holds key-pair kp x 8 dims cb
    const int kp = (tid & 31) * 2, cb = (tid >> 5) * 8;
    const f16* vgp = qkv + (bs + kp) * 1536 + 1024 + h * 64 + cb;

    // per-wave K fragment base (direct global gather, 16B/lane)
    const f16* kfb = qkv + (bs + fr) * 1536 + 512 + h * 64 + fk8;

    f16x8 va, vb;
    // load V tile 0
    va = *(const f16x8*)vgp; vb = *(const f16x8*)(vgp + 1536);
    // stage V tile 0 -> buf 0 (ordered before first compute by iter-0 barrier)
    {
        f16* vs = &Vs[0][kp];
#pragma unroll
        for (int e = 0; e < 8; ++e) {
            f16x2 pr = { va[e], vb[e] };
            *(f16x2*)&vs[(cb + e) * 72] = pr;
        }
    }
    // load V tile 1
    vgp += 64 * 1536;
    va = *(const f16x8*)vgp; vb = *(const f16x8*)(vgp + 1536);

    for (int t = 0; t < 16; ++t) {
        __syncthreads();   // certifies: buf[p^1] reads (tile t-1) drained,
                           // and stage of tile t (into buf[p]) visible
        const int p = t & 1;

        // issue K gathers for this tile up front (latency covered by staging)
        f16x8 kf[4][2];
        {
            const f16* kt = kfb + (size_t)t * 64 * 1536;
#pragma unroll
            for (int j = 0; j < 4; ++j)
#pragma unroll
                for (int c = 0; c < 2; ++c)
                    kf[j][c] = *(const f16x8*)(kt + (size_t)(j * 16) * 1536
                                               + c * 32);
        }

        if (t + 1 < 16) {
            // stage V tile t+1 -> buf[p^1]
            f16* vs = &Vs[p ^ 1][kp];
#pragma unroll
            for (int e = 0; e < 8; ++e) {
                f16x2 pr = { va[e], vb[e] };
                *(f16x2*)&vs[(cb + e) * 72] = pr;
            }
            if (t + 2 < 16) {
                vgp += 64 * 1536;
                va = *(const f16x8*)vgp; vb = *(const f16x8*)(vgp + 1536);
            }
        }

        // per q-tile: swapped QK^T -> softmax -> permlane redistribute -> l-MFMA
        f16x8 paf[2][2];
#pragma unroll
        for (int qt = 0; qt < 2; ++qt) {
            f32x4 s2[4];
#pragma unroll
            for (int j = 0; j < 4; ++j) {
                f32x4 z = __builtin_amdgcn_mfma_f32_16x16x32_f16(
                        kf[j][0], aq[qt][0], fz, 0, 0, 0);
                s2[j] = __builtin_amdgcn_mfma_f32_16x16x32_f16(
                        kf[j][1], aq[qt][1], z, 0, 0, 0);
            }

            unsigned int dw[4][2];
#pragma unroll
            for (int j = 0; j < 4; ++j) {
                float p0 = exp2f(fminf(s2[j][0], 15.9f));
                float p1 = exp2f(fminf(s2[j][1], 15.9f));
                float p2 = exp2f(fminf(s2[j][2], 15.9f));
                float p3 = exp2f(fminf(s2[j][3], 15.9f));
                f16x2 h0 = { (f16)p0, (f16)p1 };
                f16x2 h1 = { (f16)p2, (f16)p3 };
                dw[j][0] = __builtin_bit_cast(unsigned int, h0);
                dw[j][1] = __builtin_bit_cast(unsigned int, h1);
            }

            // lane-quarter algebra (R8's verified shuffle spec):
            // P32 then P16 on (X=dw[2c][T], Y=dw[2c+1][T]) yields
            // O_h0=[x0,x2,y0,y2], O_h1=[x1,x3,y1,y3].  pdw[c][2h+T].
            unsigned int pdw[2][4];
#pragma unroll
            for (int c = 0; c < 2; ++c)
#pragma unroll
                for (int T = 0; T < 2; ++T) {
                    unsigned int X = dw[2 * c][T];
                    unsigned int Y = dw[2 * c + 1][T];
                    asm("v_permlane32_swap_b32 %0, %1" : "+v"(X), "+v"(Y));
                    asm("v_permlane16_swap_b32 %0, %1" : "+v"(X), "+v"(Y));
                    pdw[c][T]     = X;
                    pdw[c][2 + T] = Y;
                }
            union { unsigned int u[4]; f16x8 hv; } cu;
#pragma unroll
            for (int c = 0; c < 2; ++c) {
                cu.u[0] = pdw[c][0]; cu.u[1] = pdw[c][1];
                cu.u[2] = pdw[c][2]; cu.u[3] = pdw[c][3];
                paf[qt][c] = cu.hv;
            }

            // l[q] += sum_k P[q][k]  (lands at lane(grp,fr) reg r = q grp*4+r)
            lacc[qt] = __builtin_amdgcn_mfma_f32_16x16x32_f16(
                paf[qt][0], onesf, lacc[qt], 0, 0, 0);
            lacc[qt] = __builtin_amdgcn_mfma_f32_16x16x32_f16(
                paf[qt][1], onesf, lacc[qt], 0, 0, 0);
        }

        // hoisted V fragments (qt-invariant): V^T[j*16+fr][c*32 + grp*8 + e]
        f16x8 vf[4][2];
#pragma unroll
        for (int j = 0; j < 4; ++j)
#pragma unroll
            for (int c = 0; c < 2; ++c)
                vf[j][c] = *(const f16x8*)&Vs[p][(j * 16 + fr) * 72 + c * 32 + fk8];

#pragma unroll
        for (int qt = 0; qt < 2; ++qt)
#pragma unroll
            for (int j = 0; j < 4; ++j)
#pragma unroll
                for (int c = 0; c < 2; ++c)
                    acc[qt][j] = __builtin_amdgcn_mfma_f32_16x16x32_f16(
                        paf[qt][c], vf[j][c], acc[qt][j], 0, 0, 0);
    }

    // epilogue: every lane already holds l for its own output rows
#pragma unroll
    for (int qt = 0; qt < 2; ++qt) {
        float inv[4];
#pragma unroll
        for (int r = 0; r < 4; ++r) inv[r] = 1.0f / lacc[qt][r];
#pragma unroll
        for (int j = 0; j < 4; ++j)
#pragma unroll
            for (int r = 0; r < 4; ++r) {
                const int q = q0 + wave * 32 + qt * 16 + grp * 4 + r;
                out[(bs + q) * 1536 + h * 64 + j * 16 + fr] =
                    (f16)(acc[qt][j][r] * inv[r]);
            }
    }
}

// ---------------------------------------------------------------------------
// launch
// ---------------------------------------------------------------------------
extern "C" void kernel_launch(void* const* d_in, const int* in_sizes, int n_in,
                              void* d_out, int out_size, void* d_ws, size_t ws_size,
                              hipStream_t stream)
{
    const float* x    = (const float*)d_in[0];   // [16,1024,512]
    const float* Wqkv = (const float*)d_in[1];   // [3,1536,512]
    const float* bqkv = (const float*)d_in[2];   // [3,1536]
    const float* Wo   = (const float*)d_in[3];   // [3,512,512]
    const float* bo   = (const float*)d_in[4];   // [3,512] (flat 1536)
    const float* Wf   = (const float*)d_in[5];   // [512,1536]
    const float* bfin = (const float*)d_in[6];   // [512]
    float* out = (float*)d_out;                  // [16,1024,512] fp32

    char* ws = (char*)d_ws;
    f16*   qkvbuf   = (f16*)ws;                        // 16384x1536 (50,331,648)
    f16*   attn_cat = (f16*)(ws + 50331648);           // 16384x1536 (50,331,648)
    f16*   wfh      = (f16*)(ws + 100663296);          // 512x1536   (1,572,864)
    f16*   WoT      = (f16*)(ws + 102236160);          // 3x512x512  (1,572,864)
    f16*   Wfo      = (f16*)(ws + 103809024);          // 512x1536   (1,572,864)
    float* bp       = (float*)(ws + 105381888);        // 512        (2,048)

    f16* xh    = (f16*)d_out;                          // 8,388,608 el (16.8 MB)
    f16* wqkvh = (f16*)((char*)d_out + 16777216);      // 2,359,296 el (4.7 MB)

    // fused prep: x/Wqkv/Wf -> f16, Wo transpose, bias fuse (one dispatch)
    prep_all<<<dim3(6528), 256, 0, stream>>>(
        x, Wqkv, Wf, Wo, bo, bfin, xh, wqkvh, wfh, WoT, bp);

    // Wfo[z] = Wf[:, 512z:512z+512] @ Wo[z]
    gemm_mfma_nt<f16><<<dim3(4, 4, 3), 256, 0, stream>>>(
        wfh, 1536, 512, WoT, 512, 262144, nullptr, Wfo, 1536, 512, 512);

    for (int i = 0; i < 3; ++i) {
        // qkv_i = x @ Wqkv[i]^T + bqkv[i]  -> [16384,1536] f16
        gemm_mfma_nt<f16><<<dim3(12, 128, 1), 256, 0, stream>>>(
            xh, 512, 0, wqkvh + (size_t)i * 786432, 512, 0, bqkv + i * 1536,
            qkvbuf, 1536, 0, 512);

        if (i == 0)
            win_attn_mfma<<<dim3(16, 16, 8), 256, 0, stream>>>(
                qkvbuf, attn_cat + 0 * 512, 5);
        else if (i == 1)
            win_attn_mfma<<<dim3(16, 16, 8), 256, 0, stream>>>(
                qkvbuf, attn_cat + 1 * 512, 10);
        else
            full_attn_mfma<<<dim3(8, 16, 8), 256, 0, stream>>>(
                qkvbuf, attn_cat + 2 * 512);
    }

    // out = attn_cat @ Wfo^T + b'  (fp32 out), M=16384 N=512 K=1536
    gemm_mfma_nt_w64<float><<<dim3(8, 128, 1), 256, 0, stream>>>(
        attn_cat, 1536, Wfo, 1536, bp, out, 512, 1536);
}

// Round 4
// 427.090 us; speedup vs baseline: 1.0732x; 1.0732x over previous
//
#include <hip/hip_runtime.h>
#include <hip/hip_bf16.h>
#include <hip/hip_fp16.h>

// R11:
//  - full_attn: reverted to R9 (K staged in LDS, V dbuf, permlane P, l-MFMA).
//    R10's direct-global K gather put 8 uncoalesced L2 gathers on the
//    critical path right after the barrier (74 -> 95 us). LDS amortization
//    of K across 4 waves was the right design.
//  - gemm_mfma_nt / _w64: stage-after-barrier DOUBLE-BUFFERED pipeline
//    (the R9 full_attn V-path pattern): barrier -> issue async_cp16 of tile
//    t+1 into buf^1 -> ds_read+MFMA tile t. Halves barriers (1/K-step) and
//    overlaps global->LDS DMA with the whole MFMA phase. LDS 32KB.
//  - prep_all fusion kept (9 dispatches total).

using f16 = _Float16;
typedef _Float16 f16x8 __attribute__((ext_vector_type(8)));
typedef _Float16 f16x2 __attribute__((ext_vector_type(2)));
typedef float    f32x4 __attribute__((ext_vector_type(4)));

__device__ inline void storeC(float* p, float v) { *p = v; }
__device__ inline void storeC(f16* p, float v)   { *p = (f16)v; }

// async 16B global -> LDS (dest = wave-uniform base + lane*16)
__device__ inline void async_cp16(const f16* g, f16* l) {
    __builtin_amdgcn_global_load_lds(
        (const __attribute__((address_space(1))) unsigned int*)g,
        (__attribute__((address_space(3))) unsigned int*)l,
        16, 0, 0);
}

// ---------------------------------------------------------------------------
// prep_all: block-range fused {x->f16, Wqkv->f16, Wf->f16, Wo transpose,
// bias fuse}.  All sections independent; grid = 4096+1152+384+768+128 = 6528.
// ---------------------------------------------------------------------------
__global__ __launch_bounds__(256) void prep_all(
    const float* __restrict__ x, const float* __restrict__ Wqkv,
    const float* __restrict__ Wf, const float* __restrict__ Wo,
    const float* __restrict__ bo, const float* __restrict__ bfv,
    f16* __restrict__ xh, f16* __restrict__ wqkvh, f16* __restrict__ wfh,
    f16* __restrict__ WoT, float* __restrict__ bp)
{
    __shared__ float t[32][33];
    const int bid = blockIdx.x;
    const int tid = threadIdx.x;

    if (bid < 5632) {
        // fp32 -> fp16, 2048 elements per block
        const float* in; f16* outp; int base;
        if (bid < 4096)      { in = x;    outp = xh;    base = bid; }
        else if (bid < 5248) { in = Wqkv; outp = wqkvh; base = bid - 4096; }
        else                 { in = Wf;   outp = wfh;   base = bid - 5248; }
        int i = (base * 256 + tid) * 8;
        float4 a = *(const float4*)(in + i);
        float4 b = *(const float4*)(in + i + 4);
        f16x8 h = { (f16)a.x, (f16)a.y, (f16)a.z, (f16)a.w,
                    (f16)b.x, (f16)b.y, (f16)b.z, (f16)b.w };
        *(f16x8*)(outp + i) = h;
    } else if (bid < 6400) {
        // Wo[z] (512x512 f32) -> WoT[z] f16 transposed
        const int idx = bid - 5632;
        const int z  = idx >> 8;
        const int bx = (idx & 15) * 32;
        const int by = ((idx >> 4) & 15) * 32;
        const int tx = tid & 31;
        const int ty = tid >> 5;
#pragma unroll
        for (int r = ty; r < 32; r += 8)
            t[r][tx] = Wo[(size_t)z * 262144 + (by + r) * 512 + bx + tx];
        __syncthreads();
#pragma unroll
        for (int r = ty; r < 32; r += 8)
            WoT[(size_t)z * 262144 + (bx + r) * 512 + by + tx] = (f16)t[tx][r];
    } else {
        // b'[o] = bf[o] + sum_j Wf[o][j]*bo[j], one wave per o
        const int o = (bid - 6400) * 4 + (tid >> 6);
        const int lane = tid & 63;
        float s = 0.f;
        for (int j = lane; j < 1536; j += 64) s += Wf[o * 1536 + j] * bo[j];
#pragma unroll
        for (int msk = 1; msk < 64; msk <<= 1) s += __shfl_xor(s, msk, 64);
        if (lane == 0) bp[o] = s + bfv[o];
    }
}

// ---------------------------------------------------------------------------
// MFMA GEMM:  C[m,n] = sum_k A[m,k]*B[n,k] (+ bias[n])   (NT, fp16 in)
// 128x128 tile, double-buffered stage-after-barrier pipeline (1 barrier/step).
// z-batched via blockIdx.z. bias nullable.
// ---------------------------------------------------------------------------
template <typename TC>
__global__ __launch_bounds__(256) void gemm_mfma_nt(
    const f16* __restrict__ A, int lda, long azs,
    const f16* __restrict__ B, int ldb, long bzs,
    const float* __restrict__ bias,
    TC* __restrict__ C, int ldc, long czs,
    int K)
{
    __shared__ __align__(16) f16 As[2][128 * 32];
    __shared__ __align__(16) f16 Bs[2][128 * 32];

    const int tid  = threadIdx.x;
    const int lane = tid & 63;
    const int wave = tid >> 6;
    const int wm = (wave >> 1) * 64;
    const int wn = (wave & 1) * 64;
    const int bm = blockIdx.y * 128;
    const int bn = blockIdx.x * 128;
    const int z  = blockIdx.z;

    const int srow = tid >> 2;
    const int scol = (tid & 3) * 8;
    const int soff = srow * 32 + scol;

    const f16* Ag = A + (size_t)z * azs + (size_t)(bm + srow) * lda + scol;
    const f16* Bg = B + (size_t)z * bzs + (size_t)(bn + srow) * ldb + scol;

    f32x4 acc[4][4];
#pragma unroll
    for (int i = 0; i < 4; ++i)
#pragma unroll
        for (int j = 0; j < 4; ++j)
            acc[i][j] = (f32x4){0.f, 0.f, 0.f, 0.f};

    const int fr = lane & 15;
    const int fk = (lane >> 4) * 8;

    // prologue: stage tile 0 -> buf 0
    async_cp16(Ag, &As[0][soff]);
    async_cp16(Ag + (size_t)64 * lda, &As[0][soff + 64 * 32]);
    async_cp16(Bg, &Bs[0][soff]);
    async_cp16(Bg + (size_t)64 * ldb, &Bs[0][soff + 64 * 32]);

    const int nt = K >> 5;
    for (int t = 0; t < nt; ++t) {
        __syncthreads();   // implicit vmcnt(0)+lgkmcnt(0): stage of buf[p]
                           // landed; all prior reads of buf[p^1] drained
        const int p = t & 1;
        if (t + 1 < nt) {
            const int k1 = (t + 1) * 32;
            async_cp16(Ag + k1, &As[p ^ 1][soff]);
            async_cp16(Ag + k1 + (size_t)64 * lda, &As[p ^ 1][soff + 64 * 32]);
            async_cp16(Bg + k1, &Bs[p ^ 1][soff]);
            async_cp16(Bg + k1 + (size_t)64 * ldb, &Bs[p ^ 1][soff + 64 * 32]);
        }

        f16x8 af[4], bfr[4];
#pragma unroll
        for (int i = 0; i < 4; ++i)
            af[i] = *(const f16x8*)&As[p][(wm + i * 16 + fr) * 32 + fk];
#pragma unroll
        for (int j = 0; j < 4; ++j)
            bfr[j] = *(const f16x8*)&Bs[p][(wn + j * 16 + fr) * 32 + fk];
#pragma unroll
        for (int i = 0; i < 4; ++i)
#pragma unroll
            for (int j = 0; j < 4; ++j)
                acc[i][j] = __builtin_amdgcn_mfma_f32_16x16x32_f16(
                    af[i], bfr[j], acc[i][j], 0, 0, 0);
    }

    const int cn  = lane & 15;
    const int cr4 = (lane >> 4) * 4;
#pragma unroll
    for (int i = 0; i < 4; ++i) {
#pragma unroll
        for (int j = 0; j < 4; ++j) {
            const int col = bn + wn + j * 16 + cn;
            const float bv = bias ? bias[col] : 0.f;
#pragma unroll
            for (int r = 0; r < 4; ++r) {
                const int row = bm + wm + i * 16 + cr4 + r;
                storeC(&C[(size_t)z * czs + (size_t)row * ldc + col],
                       acc[i][j][r] + bv);
            }
        }
    }
}

// ---------------------------------------------------------------------------
// MFMA GEMM, 128x64 tile, same stage-after-barrier dbuf pipeline.
// ---------------------------------------------------------------------------
template <typename TC>
__global__ __launch_bounds__(256) void gemm_mfma_nt_w64(
    const f16* __restrict__ A, int lda,
    const f16* __restrict__ B, int ldb,
    const float* __restrict__ bias,
    TC* __restrict__ C, int ldc,
    int K)
{
    __shared__ __align__(16) f16 As[2][128 * 32];
    __shared__ __align__(16) f16 Bs[2][64 * 32];

    const int tid  = threadIdx.x;
    const int lane = tid & 63;
    const int wave = tid >> 6;
    const int wm = wave * 32;
    const int bm = blockIdx.y * 128;
    const int bn = blockIdx.x * 64;

    const int srow = tid >> 2;
    const int scol = (tid & 3) * 8;
    const int soff = srow * 32 + scol;

    const f16* Ag = A + (size_t)(bm + srow) * lda + scol;
    const f16* Bg = B + (size_t)(bn + srow) * ldb + scol;

    f32x4 acc[2][4];
#pragma unroll
    for (int i = 0; i < 2; ++i)
#pragma unroll
        for (int j = 0; j < 4; ++j)
            acc[i][j] = (f32x4){0.f, 0.f, 0.f, 0.f};

    const int fr = lane & 15;
    const int fk = (lane >> 4) * 8;

    // prologue: stage tile 0 -> buf 0
    async_cp16(Ag, &As[0][soff]);
    async_cp16(Ag + (size_t)64 * lda, &As[0][soff + 64 * 32]);
    async_cp16(Bg, &Bs[0][soff]);

    const int nt = K >> 5;
    for (int t = 0; t < nt; ++t) {
        __syncthreads();
        const int p = t & 1;
        if (t + 1 < nt) {
            const int k1 = (t + 1) * 32;
            async_cp16(Ag + k1, &As[p ^ 1][soff]);
            async_cp16(Ag + k1 + (size_t)64 * lda, &As[p ^ 1][soff + 64 * 32]);
            async_cp16(Bg + k1, &Bs[p ^ 1][soff]);
        }

        f16x8 af[2], bfr[4];
#pragma unroll
        for (int i = 0; i < 2; ++i)
            af[i] = *(const f16x8*)&As[p][(wm + i * 16 + fr) * 32 + fk];
#pragma unroll
        for (int j = 0; j < 4; ++j)
            bfr[j] = *(const f16x8*)&Bs[p][(j * 16 + fr) * 32 + fk];
#pragma unroll
        for (int i = 0; i < 2; ++i)
#pragma unroll
            for (int j = 0; j < 4; ++j)
                acc[i][j] = __builtin_amdgcn_mfma_f32_16x16x32_f16(
                    af[i], bfr[j], acc[i][j], 0, 0, 0);
    }

    const int cn  = lane & 15;
    const int cr4 = (lane >> 4) * 4;
#pragma unroll
    for (int i = 0; i < 2; ++i) {
#pragma unroll
        for (int j = 0; j < 4; ++j) {
            const int col = bn + j * 16 + cn;
            const float bv = bias ? bias[col] : 0.f;
#pragma unroll
            for (int r = 0; r < 4; ++r) {
                const int row = bm + wm + i * 16 + cr4 + r;
                storeC(&C[(size_t)row * ldc + col], acc[i][j][r] + bv);
            }
        }
    }
}

// ---------------------------------------------------------------------------
// Windowed causal attention via MFMA (unchanged).
// ---------------------------------------------------------------------------
__global__ __launch_bounds__(256) void win_attn_mfma(
    const f16* __restrict__ qkv, f16* __restrict__ out, int w)
{
    __shared__ __align__(16) f16 Vs[4][64 * 40];   // per-wave [dim64][key32]
    __shared__ __align__(16) f16 Ps[4][16 * 40];   // per-wave [q16][key32]

    const int tid  = threadIdx.x;
    const int lane = tid & 63;
    const int wave = tid >> 6;
    const int b  = blockIdx.y;
    const int h  = blockIdx.z;
    const int q0 = (blockIdx.x * 4 + wave) * 16;
    const size_t bs = (size_t)b * 1024;

    const int fr  = lane & 15;
    const int grp = lane >> 4;
    const int fk8 = grp * 8;

    // Q A-frags, scaled by 1/8 * log2(e) so p = exp2(s)
    f16x8 aq[2];
    {
        const f16* qp = qkv + (bs + q0 + fr) * 1536 + h * 64 + fk8;
        aq[0] = *(const f16x8*)qp;
        aq[1] = *(const f16x8*)(qp + 32);
#pragma unroll
        for (int e = 0; e < 8; ++e) {
            aq[0][e] *= (f16)0.18033688;
            aq[1][e] *= (f16)0.18033688;
        }
    }

    // K B-frags, 2 groups of 16 keys (rows clamped; clamped keys get P=0)
    f16x8 bk[2][2];
#pragma unroll
    for (int g = 0; g < 2; ++g) {
        int krow = q0 - 16 + g * 16 + fr;
        int kcl  = krow < 0 ? 0 : krow;
        const f16* kp = qkv + (bs + kcl) * 1536 + 512 + h * 64 + fk8;
        bk[g][0] = *(const f16x8*)kp;
        bk[g][1] = *(const f16x8*)(kp + 32);
    }

    // stage V transposed into wave-private LDS: Vs[d][key], 32 keys
    {
        const int vk = lane & 31;
        const int vd = (lane >> 5) * 32;
        int vrow = q0 - 16 + vk;
        int vcl  = vrow < 0 ? 0 : vrow;
        const f16* vp = qkv + (bs + vcl) * 1536 + 1024 + h * 64 + vd;
        f16* vsw = Vs[wave];
#pragma unroll
        for (int t = 0; t < 4; ++t) {
            f16x8 vv = *(const f16x8*)(vp + t * 8);
#pragma unroll
            for (int e = 0; e < 8; ++e)
                vsw[(vd + t * 8 + e) * 40 + vk] = vv[e];
        }
    }

    // QK^T: 16q x 32keys, 4 MFMAs
    f32x4 s[2];
#pragma unroll
    for (int g = 0; g < 2; ++g) {
        f32x4 z = (f32x4){0.f, 0.f, 0.f, 0.f};
        z = __builtin_amdgcn_mfma_f32_16x16x32_f16(aq[0], bk[g][0], z, 0, 0, 0);
        s[g] = __builtin_amdgcn_mfma_f32_16x16x32_f16(aq[1], bk[g][1], z, 0, 0, 0);
    }

    // mask: 0 <= q-k < w AND absolute key position >= 0, then flat exp2
    float l[4] = {0.f, 0.f, 0.f, 0.f};
#pragma unroll
    for (int g = 0; g < 2; ++g) {
        const int kpos = q0 - 16 + g * 16 + fr;    // absolute key position
#pragma unroll
        for (int r = 0; r < 4; ++r) {
            const int diff = (grp * 4 + r) - (g * 16 + fr) + 16;   // q - k
            const bool ok = (diff >= 0) && (diff < w) && (kpos >= 0);
            float p = ok ? exp2f(fminf(s[g][r], 15.9f)) : 0.f;
            l[r] += p;
            Ps[wave][(grp * 4 + r) * 40 + g * 16 + fr] = (f16)p;
        }
    }

    __builtin_amdgcn_wave_barrier();   // wave-local LDS writes before reads

    // PV: O[16q][64d] = P(16x32) * V^T, 4 MFMAs (one K=32 contraction each)
    f16x8 pa = *(const f16x8*)&Ps[wave][fr * 40 + fk8];
    f32x4 acc[4];
#pragma unroll
    for (int j = 0; j < 4; ++j) {
        f16x8 bv = *(const f16x8*)&Vs[wave][(j * 16 + fr) * 40 + fk8];
        f32x4 z = (f32x4){0.f, 0.f, 0.f, 0.f};
        acc[j] = __builtin_amdgcn_mfma_f32_16x16x32_f16(pa, bv, z, 0, 0, 0);
    }

    // reduce l across the 16-lane group, write O
#pragma unroll
    for (int r = 0; r < 4; ++r)
#pragma unroll
        for (int msk = 1; msk < 16; msk <<= 1)
            l[r] += __shfl_xor(l[r], msk, 64);

#pragma unroll
    for (int j = 0; j < 4; ++j)
#pragma unroll
        for (int r = 0; r < 4; ++r) {
            const int q = q0 + grp * 4 + r;
            out[(bs + q) * 1536 + h * 64 + j * 16 + fr] = (f16)(acc[j][r] / l[r]);
        }
}

// ---------------------------------------------------------------------------
// Full attention, MFMA flash v5 (R9, proven 74us): swapped QK^T, register P
// via permlane swaps, double-buffered K/V (1 barrier/tile), paired V scatter,
// l via ones-MFMA.
// ---------------------------------------------------------------------------
__global__ __launch_bounds__(256, 4) void full_attn_mfma(
    const f16* __restrict__ qkv, f16* __restrict__ out)
{
    __shared__ __align__(16) f16 Ks[2][64 * 72];   // [key][d]
    __shared__ __align__(16) f16 Vs[2][64 * 72];   // [d][key]

    const int tid  = threadIdx.x;
    const int lane = tid & 63;
    const int wave = tid >> 6;
    const int q0 = blockIdx.x * 128;
    const int b  = blockIdx.y;
    const int h  = blockIdx.z;
    const size_t bs = (size_t)b * 1024;

    const int fr  = lane & 15;
    const int grp = lane >> 4;
    const int fk8 = grp * 8;

    // Q B-frags (rows = queries), scaled by 1/8 * log2(e) so p = exp2(s)
    f16x8 aq[2][2];
#pragma unroll
    for (int qt = 0; qt < 2; ++qt) {
        const f16* qp = qkv + (bs + q0 + wave * 32 + qt * 16 + fr) * 1536
                        + h * 64 + fk8;
        aq[qt][0] = *(const f16x8*)qp;
        aq[qt][1] = *(const f16x8*)(qp + 32);
#pragma unroll
        for (int e = 0; e < 8; ++e) {
            aq[qt][0][e] *= (f16)0.18033688;
            aq[qt][1][e] *= (f16)0.18033688;
        }
    }

    // all-ones B-fragment for the l-MFMA (C[q][n] = sum_k P[q][k])
    f16x8 onesf;
#pragma unroll
    for (int e = 0; e < 8; ++e) onesf[e] = (f16)1.0f;

    const f32x4 fz = (f32x4){0.f, 0.f, 0.f, 0.f};
    f32x4 lacc[2] = {fz, fz};
    f32x4 acc[2][4];
#pragma unroll
    for (int qt = 0; qt < 2; ++qt)
#pragma unroll
        for (int j = 0; j < 4; ++j)
            acc[qt][j] = fz;

    // staging partitions: K by (row, 32B col chunk); V by (key-pair, 8-col block)
    const int kr = tid >> 2, kc = (tid & 3) * 16;
    const int kp = (tid & 31) * 2, cb = (tid >> 5) * 8;

    const f16* kgp = qkv + (bs + kr) * 1536 + 512 + h * 64 + kc;
    const f16* vgp = qkv + (bs + kp) * 1536 + 1024 + h * 64 + cb;

    f16x8 ka, kb, va, vb;
    // load tile 0
    ka = *(const f16x8*)kgp; kb = *(const f16x8*)(kgp + 8);
    va = *(const f16x8*)vgp; vb = *(const f16x8*)(vgp + 1536);

    // stage tile 0 -> buf 0 (ordered before first compute by iter-0 barrier)
    {
        f16* ks = &Ks[0][kr * 72 + kc];
        *(f16x8*)ks = ka; *(f16x8*)(ks + 8) = kb;
        f16* vs = &Vs[0][kp];
#pragma unroll
        for (int e = 0; e < 8; ++e) {
            f16x2 pr = { va[e], vb[e] };
            *(f16x2*)&vs[(cb + e) * 72] = pr;
        }
    }
    // load tile 1
    kgp += 64 * 1536; vgp += 64 * 1536;
    ka = *(const f16x8*)kgp; kb = *(const f16x8*)(kgp + 8);
    va = *(const f16x8*)vgp; vb = *(const f16x8*)(vgp + 1536);

    for (int t = 0; t < 16; ++t) {
        __syncthreads();   // certifies: buf[p^1] reads (tile t-1) drained,
                           // and stage of tile t (into buf[p]) visible
        const int p = t & 1;

        if (t + 1 < 16) {
            // stage tile t+1 -> buf[p^1]
            f16* ks = &Ks[p ^ 1][kr * 72 + kc];
            *(f16x8*)ks = ka; *(f16x8*)(ks + 8) = kb;
            f16* vs = &Vs[p ^ 1][kp];
#pragma unroll
            for (int e = 0; e < 8; ++e) {
                f16x2 pr = { va[e], vb[e] };
                *(f16x2*)&vs[(cb + e) * 72] = pr;
            }
            if (t + 2 < 16) {
                kgp += 64 * 1536; vgp += 64 * 1536;
                ka = *(const f16x8*)kgp; kb = *(const f16x8*)(kgp + 8);
                va = *(const f16x8*)vgp; vb = *(const f16x8*)(vgp + 1536);
            }
        }

        // hoisted K fragments (qt-invariant): K[j*16+fr][c*32 + grp*8 + e]
        f16x8 kf[4][2];
#pragma unroll
        for (int j = 0; j < 4; ++j)
#pragma unroll
            for (int c = 0; c < 2; ++c)
                kf[j][c] = *(const f16x8*)&Ks[p][(j * 16 + fr) * 72 + c * 32 + fk8];

        // per q-tile: swapped QK^T -> softmax -> permlane redistribute -> l-MFMA
        f16x8 paf[2][2];
#pragma unroll
        for (int qt = 0; qt < 2; ++qt) {
            f32x4 s2[4];
#pragma unroll
            for (int j = 0; j < 4; ++j) {
                f32x4 z = __builtin_amdgcn_mfma_f32_16x16x32_f16(
                        kf[j][0], aq[qt][0], fz, 0, 0, 0);
                s2[j] = __builtin_amdgcn_mfma_f32_16x16x32_f16(
                        kf[j][1], aq[qt][1], z, 0, 0, 0);
            }

            unsigned int dw[4][2];
#pragma unroll
            for (int j = 0; j < 4; ++j) {
                float p0 = exp2f(fminf(s2[j][0], 15.9f));
                float p1 = exp2f(fminf(s2[j][1], 15.9f));
                float p2 = exp2f(fminf(s2[j][2], 15.9f));
                float p3 = exp2f(fminf(s2[j][3], 15.9f));
                f16x2 h0 = { (f16)p0, (f16)p1 };
                f16x2 h1 = { (f16)p2, (f16)p3 };
                dw[j][0] = __builtin_bit_cast(unsigned int, h0);
                dw[j][1] = __builtin_bit_cast(unsigned int, h1);
            }

            // lane-quarter algebra (R8's verified shuffle spec):
            // P32 then P16 on (X=dw[2c][T], Y=dw[2c+1][T]) yields
            // O_h0=[x0,x2,y0,y2], O_h1=[x1,x3,y1,y3].  pdw[c][2h+T].
            unsigned int pdw[2][4];
#pragma unroll
            for (int c = 0; c < 2; ++c)
#pragma unroll
                for (int T = 0; T < 2; ++T) {
                    unsigned int X = dw[2 * c][T];
                    unsigned int Y = dw[2 * c + 1][T];
                    asm("v_permlane32_swap_b32 %0, %1" : "+v"(X), "+v"(Y));
                    asm("v_permlane16_swap_b32 %0, %1" : "+v"(X), "+v"(Y));
                    pdw[c][T]     = X;
                    pdw[c][2 + T] = Y;
                }
            union { unsigned int u[4]; f16x8 hv; } cu;
#pragma unroll
            for (int c = 0; c < 2; ++c) {
                cu.u[0] = pdw[c][0]; cu.u[1] = pdw[c][1];
                cu.u[2] = pdw[c][2]; cu.u[3] = pdw[c][3];
                paf[qt][c] = cu.hv;
            }

            // l[q] += sum_k P[q][k]  (lands at lane(grp,fr) reg r = q grp*4+r)
            lacc[qt] = __builtin_amdgcn_mfma_f32_16x16x32_f16(
                paf[qt][0], onesf, lacc[qt], 0, 0, 0);
            lacc[qt] = __builtin_amdgcn_mfma_f32_16x16x32_f16(
                paf[qt][1], onesf, lacc[qt], 0, 0, 0);
        }

        // hoisted V fragments (qt-invariant): V^T[j*16+fr][c*32 + grp*8 + e]
        f16x8 vf[4][2];
#pragma unroll
        for (int j = 0; j < 4; ++j)
#pragma unroll
            for (int c = 0; c < 2; ++c)
                vf[j][c] = *(const f16x8*)&Vs[p][(j * 16 + fr) * 72 + c * 32 + fk8];

#pragma unroll
        for (int qt = 0; qt < 2; ++qt)
#pragma unroll
            for (int j = 0; j < 4; ++j)
#pragma unroll
                for (int c = 0; c < 2; ++c)
                    acc[qt][j] = __builtin_amdgcn_mfma_f32_16x16x32_f16(
                        paf[qt][c], vf[j][c], acc[qt][j], 0, 0, 0);
    }

    // epilogue: every lane already holds l for its own output rows
#pragma unroll
    for (int qt = 0; qt < 2; ++qt) {
        float inv[4];
#pragma unroll
        for (int r = 0; r < 4; ++r) inv[r] = 1.0f / lacc[qt][r];
#pragma unroll
        for (int j = 0; j < 4; ++j)
#pragma unroll
            for (int r = 0; r < 4; ++r) {
                const int q = q0 + wave * 32 + qt * 16 + grp * 4 + r;
                out[(bs + q) * 1536 + h * 64 + j * 16 + fr] =
                    (f16)(acc[qt][j][r] * inv[r]);
            }
    }
}

// ---------------------------------------------------------------------------
// launch
// ---------------------------------------------------------------------------
extern "C" void kernel_launch(void* const* d_in, const int* in_sizes, int n_in,
                              void* d_out, int out_size, void* d_ws, size_t ws_size,
                              hipStream_t stream)
{
    const float* x    = (const float*)d_in[0];   // [16,1024,512]
    const float* Wqkv = (const float*)d_in[1];   // [3,1536,512]
    const float* bqkv = (const float*)d_in[2];   // [3,1536]
    const float* Wo   = (const float*)d_in[3];   // [3,512,512]
    const float* bo   = (const float*)d_in[4];   // [3,512] (flat 1536)
    const float* Wf   = (const float*)d_in[5];   // [512,1536]
    const float* bfin = (const float*)d_in[6];   // [512]
    float* out = (float*)d_out;                  // [16,1024,512] fp32

    char* ws = (char*)d_ws;
    f16*   qkvbuf   = (f16*)ws;                        // 16384x1536 (50,331,648)
    f16*   attn_cat = (f16*)(ws + 50331648);           // 16384x1536 (50,331,648)
    f16*   wfh      = (f16*)(ws + 100663296);          // 512x1536   (1,572,864)
    f16*   WoT      = (f16*)(ws + 102236160);          // 3x512x512  (1,572,864)
    f16*   Wfo      = (f16*)(ws + 103809024);          // 512x1536   (1,572,864)
    float* bp       = (float*)(ws + 105381888);        // 512        (2,048)

    f16* xh    = (f16*)d_out;                          // 8,388,608 el (16.8 MB)
    f16* wqkvh = (f16*)((char*)d_out + 16777216);      // 2,359,296 el (4.7 MB)

    // fused prep: x/Wqkv/Wf -> f16, Wo transpose, bias fuse (one dispatch)
    prep_all<<<dim3(6528), 256, 0, stream>>>(
        x, Wqkv, Wf, Wo, bo, bfin, xh, wqkvh, wfh, WoT, bp);

    // Wfo[z] = Wf[:, 512z:512z+512] @ Wo[z]
    gemm_mfma_nt<f16><<<dim3(4, 4, 3), 256, 0, stream>>>(
        wfh, 1536, 512, WoT, 512, 262144, nullptr, Wfo, 1536, 512, 512);

    for (int i = 0; i < 3; ++i) {
        // qkv_i = x @ Wqkv[i]^T + bqkv[i]  -> [16384,1536] f16
        gemm_mfma_nt<f16><<<dim3(12, 128, 1), 256, 0, stream>>>(
            xh, 512, 0, wqkvh + (size_t)i * 786432, 512, 0, bqkv + i * 1536,
            qkvbuf, 1536, 0, 512);

        if (i == 0)
            win_attn_mfma<<<dim3(16, 16, 8), 256, 0, stream>>>(
                qkvbuf, attn_cat + 0 * 512, 5);
        else if (i == 1)
            win_attn_mfma<<<dim3(16, 16, 8), 256, 0, stream>>>(
                qkvbuf, attn_cat + 1 * 512, 10);
        else
            full_attn_mfma<<<dim3(8, 16, 8), 256, 0, stream>>>(
                qkvbuf, attn_cat + 2 * 512);
    }

    // out = attn_cat @ Wfo^T + b'  (fp32 out), M=16384 N=512 K=1536
    gemm_mfma_nt_w64<float><<<dim3(8, 128, 1), 256, 0, stream>>>(
        attn_cat, 1536, Wfo, 1536, bp, out, 512, 1536);
}

// Round 5
// 386.354 us; speedup vs baseline: 1.1863x; 1.1054x over previous
//
#include <hip/hip_runtime.h>
#include <hip/hip_bf16.h>
#include <hip/hip_fp16.h>

// R12: 8-phase counted-vmcnt GEMM (T3+T4+T2+T5) for the 4 big GEMMs.
//  - BM=256, BN=NR*64 (NR=3 qkv -> 512 blocks = 2 exact CU-rounds; NR=2
//    final -> 256 blocks = 1 round). 512 thr / 8 waves (2Mx4N), BK=64,
//    LDS 112/96 KB dbuf, 1 block/CU.
//  - counted vmcnt(4+NR) in-loop (never 0 except last iter); raw s_barrier;
//    per-quad {issue-next-ds_reads -> lgkmcnt(0)+sched_barrier -> setprio(1)
//    16/12 MFMA -> setprio(0)}; stage t+2 after read-done barrier.
//  - LDS swizzle: phys chunk = (ks*4+grp) ^ (fr&7) / stage src col
//    ((tid&7)^((tid>>3)&7))*8 — 16-way -> 2-way (free) read conflicts,
//    element-verified. Both-sides-or-neither rule respected.
// full_attn (R9/R11 proven 74us), win_attn, prep_all, Wfo GEMM unchanged.

using f16 = _Float16;
typedef _Float16 f16x8 __attribute__((ext_vector_type(8)));
typedef _Float16 f16x2 __attribute__((ext_vector_type(2)));
typedef float    f32x4 __attribute__((ext_vector_type(4)));

__device__ inline void storeC(float* p, float v) { *p = v; }
__device__ inline void storeC(f16* p, float v)   { *p = (f16)v; }

// async 16B global -> LDS (dest = wave-uniform base + lane*16)
__device__ inline void async_cp16(const f16* g, f16* l) {
    __builtin_amdgcn_global_load_lds(
        (const __attribute__((address_space(1))) unsigned int*)g,
        (__attribute__((address_space(3))) unsigned int*)l,
        16, 0, 0);
}

// ---------------------------------------------------------------------------
// prep_all: block-range fused {x->f16, Wqkv->f16, Wf->f16, Wo transpose,
// bias fuse}.  All sections independent; grid = 4096+1152+384+768+128 = 6528.
// ---------------------------------------------------------------------------
__global__ __launch_bounds__(256) void prep_all(
    const float* __restrict__ x, const float* __restrict__ Wqkv,
    const float* __restrict__ Wf, const float* __restrict__ Wo,
    const float* __restrict__ bo, const float* __restrict__ bfv,
    f16* __restrict__ xh, f16* __restrict__ wqkvh, f16* __restrict__ wfh,
    f16* __restrict__ WoT, float* __restrict__ bp)
{
    __shared__ float t[32][33];
    const int bid = blockIdx.x;
    const int tid = threadIdx.x;

    if (bid < 5632) {
        const float* in; f16* outp; int base;
        if (bid < 4096)      { in = x;    outp = xh;    base = bid; }
        else if (bid < 5248) { in = Wqkv; outp = wqkvh; base = bid - 4096; }
        else                 { in = Wf;   outp = wfh;   base = bid - 5248; }
        int i = (base * 256 + tid) * 8;
        float4 a = *(const float4*)(in + i);
        float4 b = *(const float4*)(in + i + 4);
        f16x8 h = { (f16)a.x, (f16)a.y, (f16)a.z, (f16)a.w,
                    (f16)b.x, (f16)b.y, (f16)b.z, (f16)b.w };
        *(f16x8*)(outp + i) = h;
    } else if (bid < 6400) {
        const int idx = bid - 5632;
        const int z  = idx >> 8;
        const int bx = (idx & 15) * 32;
        const int by = ((idx >> 4) & 15) * 32;
        const int tx = tid & 31;
        const int ty = tid >> 5;
#pragma unroll
        for (int r = ty; r < 32; r += 8)
            t[r][tx] = Wo[(size_t)z * 262144 + (by + r) * 512 + bx + tx];
        __syncthreads();
#pragma unroll
        for (int r = ty; r < 32; r += 8)
            WoT[(size_t)z * 262144 + (bx + r) * 512 + by + tx] = (f16)t[tx][r];
    } else {
        const int o = (bid - 6400) * 4 + (tid >> 6);
        const int lane = tid & 63;
        float s = 0.f;
        for (int j = lane; j < 1536; j += 64) s += Wf[o * 1536 + j] * bo[j];
#pragma unroll
        for (int msk = 1; msk < 64; msk <<= 1) s += __shfl_xor(s, msk, 64);
        if (lane == 0) bp[o] = s + bfv[o];
    }
}

// ---------------------------------------------------------------------------
// small 128x128 2-phase GEMM (kept for the 48-block Wfo product only)
// ---------------------------------------------------------------------------
template <typename TC>
__global__ __launch_bounds__(256) void gemm_mfma_nt(
    const f16* __restrict__ A, int lda, long azs,
    const f16* __restrict__ B, int ldb, long bzs,
    const float* __restrict__ bias,
    TC* __restrict__ C, int ldc, long czs,
    int K)
{
    __shared__ __align__(16) f16 As[2][128 * 32];
    __shared__ __align__(16) f16 Bs[2][128 * 32];

    const int tid  = threadIdx.x;
    const int lane = tid & 63;
    const int wave = tid >> 6;
    const int wm = (wave >> 1) * 64;
    const int wn = (wave & 1) * 64;
    const int bm = blockIdx.y * 128;
    const int bn = blockIdx.x * 128;
    const int z  = blockIdx.z;

    const int srow = tid >> 2;
    const int scol = (tid & 3) * 8;
    const int soff = srow * 32 + scol;

    const f16* Ag = A + (size_t)z * azs + (size_t)(bm + srow) * lda + scol;
    const f16* Bg = B + (size_t)z * bzs + (size_t)(bn + srow) * ldb + scol;

    f32x4 acc[4][4];
#pragma unroll
    for (int i = 0; i < 4; ++i)
#pragma unroll
        for (int j = 0; j < 4; ++j)
            acc[i][j] = (f32x4){0.f, 0.f, 0.f, 0.f};

    const int fr = lane & 15;
    const int fk = (lane >> 4) * 8;

    async_cp16(Ag, &As[0][soff]);
    async_cp16(Ag + (size_t)64 * lda, &As[0][soff + 64 * 32]);
    async_cp16(Bg, &Bs[0][soff]);
    async_cp16(Bg + (size_t)64 * ldb, &Bs[0][soff + 64 * 32]);

    const int nt = K >> 5;
    for (int t = 0; t < nt; ++t) {
        __syncthreads();
        const int p = t & 1;
        if (t + 1 < nt) {
            const int k1 = (t + 1) * 32;
            async_cp16(Ag + k1, &As[p ^ 1][soff]);
            async_cp16(Ag + k1 + (size_t)64 * lda, &As[p ^ 1][soff + 64 * 32]);
            async_cp16(Bg + k1, &Bs[p ^ 1][soff]);
            async_cp16(Bg + k1 + (size_t)64 * ldb, &Bs[p ^ 1][soff + 64 * 32]);
        }

        f16x8 af[4], bfr[4];
#pragma unroll
        for (int i = 0; i < 4; ++i)
            af[i] = *(const f16x8*)&As[p][(wm + i * 16 + fr) * 32 + fk];
#pragma unroll
        for (int j = 0; j < 4; ++j)
            bfr[j] = *(const f16x8*)&Bs[p][(wn + j * 16 + fr) * 32 + fk];
#pragma unroll
        for (int i = 0; i < 4; ++i)
#pragma unroll
            for (int j = 0; j < 4; ++j)
                acc[i][j] = __builtin_amdgcn_mfma_f32_16x16x32_f16(
                    af[i], bfr[j], acc[i][j], 0, 0, 0);
    }

    const int cn  = lane & 15;
    const int cr4 = (lane >> 4) * 4;
#pragma unroll
    for (int i = 0; i < 4; ++i) {
#pragma unroll
        for (int j = 0; j < 4; ++j) {
            const int col = bn + wn + j * 16 + cn;
            const float bv = bias ? bias[col] : 0.f;
#pragma unroll
            for (int r = 0; r < 4; ++r) {
                const int row = bm + wm + i * 16 + cr4 + r;
                storeC(&C[(size_t)z * czs + (size_t)row * ldc + col],
                       acc[i][j][r] + bv);
            }
        }
    }
}

// ---------------------------------------------------------------------------
// 8-phase counted-vmcnt GEMM: C[m,n] = sum_k A[m,k]*B[n,k] + bias[n].
// BM=256, BN=NR*64, BK=64, 512 threads / 8 waves (2M x 4N), dbuf LDS,
// swizzled layout, 1 block/CU. Requires M%256==0, N%(NR*64)==0, K%64==0,
// K>=128.
// ---------------------------------------------------------------------------
template <int NR, typename TC>
__global__ __launch_bounds__(512, 2) void gemm_mfma_8ph(
    const f16* __restrict__ A, int lda,
    const f16* __restrict__ B, int ldb,
    const float* __restrict__ bias,
    TC* __restrict__ C, int ldc, int K)
{
    __shared__ __align__(16) f16 As[2][256 * 64];
    __shared__ __align__(16) f16 Bs[2][NR * 64 * 64];

    const int tid  = threadIdx.x;
    const int lane = tid & 63;
    const int wave = tid >> 6;
    const int wr = wave >> 2;            // 0..1  (M wave)
    const int wc = wave & 3;             // 0..3  (N wave)
    const int bm = blockIdx.y * 256;
    const int bn = blockIdx.x * (NR * 64);
    const int fr  = lane & 15;
    const int grp = lane >> 4;

    // swizzle: physical 16B chunk = (ks*4 + grp) ^ (fr&7); per-lane constants
    const int c0 = ((0 + grp) ^ (fr & 7)) * 8;   // f16 offset, ks=0
    const int c1 = ((4 + grp) ^ (fr & 7)) * 8;   // f16 offset, ks=1

    // staging: thread tid owns linear dest byte tid*16 (+ inst*8192);
    // source col XOR'd to match (content at phys b = logical b^((row&7)<<4))
    const int srow = tid >> 3;                           // 0..63
    const int scol = ((tid & 7) ^ (srow & 7)) * 8;       // f16
    const f16* Ag = A + (size_t)(bm + srow) * lda + scol;
    const f16* Bg = B + (size_t)(bn + srow) * ldb + scol;

    f32x4 acc[8][NR];
#pragma unroll
    for (int m = 0; m < 8; ++m)
#pragma unroll
        for (int n = 0; n < NR; ++n)
            acc[m][n] = (f32x4){0.f, 0.f, 0.f, 0.f};

    const int arow = wr * 128 + fr;          // + m*16
    const int brow = wc * (NR * 16) + fr;    // + n*16

    f16x8 bfrag[NR][2];
    f16x8 aP[2][2], aQ[2][2];

    auto stage = [&](int p, int kt) {
        const f16* a_ = Ag + (size_t)kt * 64;
        const f16* b_ = Bg + (size_t)kt * 64;
        f16* al = &As[p][tid * 8];
        f16* bl = &Bs[p][tid * 8];
#pragma unroll
        for (int i = 0; i < 4; ++i)
            async_cp16(a_ + (size_t)(i * 64) * lda, al + i * 4096);
#pragma unroll
        for (int i = 0; i < NR; ++i)
            async_cp16(b_ + (size_t)(i * 64) * ldb, bl + i * 4096);
    };

    const int nt = K >> 6;

    // prologue: two tiles in flight
    stage(0, 0);
    stage(1, 1);

    for (int t = 0; t < nt; ++t) {
        const int p = t & 1;
        if (t + 1 < nt) {
            if constexpr (NR == 3)
                asm volatile("s_waitcnt vmcnt(7)" ::: "memory");
            else
                asm volatile("s_waitcnt vmcnt(6)" ::: "memory");
        } else {
            asm volatile("s_waitcnt vmcnt(0)" ::: "memory");
        }
        __builtin_amdgcn_s_barrier();

        const f16* asb = As[p];
        const f16* bsb = Bs[p];

        auto loada = [&](f16x8 (&d)[2][2], int mq) {
#pragma unroll
            for (int m2 = 0; m2 < 2; ++m2) {
                const int ro = (arow + (mq * 2 + m2) * 16) * 64;
                d[m2][0] = *(const f16x8*)&asb[ro + c0];
                d[m2][1] = *(const f16x8*)&asb[ro + c1];
            }
        };
        auto qmfma = [&](const f16x8 (&a_)[2][2], int mq) {
            __builtin_amdgcn_s_setprio(1);
#pragma unroll
            for (int m2 = 0; m2 < 2; ++m2)
#pragma unroll
                for (int n = 0; n < NR; ++n) {
                    f32x4 z = __builtin_amdgcn_mfma_f32_16x16x32_f16(
                        a_[m2][0], bfrag[n][0], acc[mq * 2 + m2][n], 0, 0, 0);
                    acc[mq * 2 + m2][n] = __builtin_amdgcn_mfma_f32_16x16x32_f16(
                        a_[m2][1], bfrag[n][1], z, 0, 0, 0);
                }
            __builtin_amdgcn_s_setprio(0);
        };

        // phase 0 preload: all B frags + A quad 0
#pragma unroll
        for (int n = 0; n < NR; ++n) {
            const int ro = (brow + n * 16) * 64;
            bfrag[n][0] = *(const f16x8*)&bsb[ro + c0];
            bfrag[n][1] = *(const f16x8*)&bsb[ro + c1];
        }
        loada(aP, 0);
        asm volatile("s_waitcnt lgkmcnt(0)" ::: "memory");
        __builtin_amdgcn_sched_barrier(0);

        loada(aQ, 1);          // issue quad1 reads, then compute quad0
        qmfma(aP, 0);
        asm volatile("s_waitcnt lgkmcnt(0)" ::: "memory");
        __builtin_amdgcn_sched_barrier(0);

        loada(aP, 2);
        qmfma(aQ, 1);
        asm volatile("s_waitcnt lgkmcnt(0)" ::: "memory");
        __builtin_amdgcn_sched_barrier(0);

        loada(aQ, 3);
        qmfma(aP, 2);
        asm volatile("s_waitcnt lgkmcnt(0)" ::: "memory");
        __builtin_amdgcn_sched_barrier(0);

        __builtin_amdgcn_s_barrier();      // all reads of buf[p] complete
        if (t + 2 < nt) stage(p, t + 2);   // overwrite freed buffer
        qmfma(aQ, 3);                      // last quad overlaps the DMA
    }

    const int cn  = lane & 15;
    const int cr4 = (lane >> 4) * 4;
#pragma unroll
    for (int m = 0; m < 8; ++m)
#pragma unroll
        for (int n = 0; n < NR; ++n) {
            const int col = bn + wc * (NR * 16) + n * 16 + cn;
            const float bv = bias ? bias[col] : 0.f;
#pragma unroll
            for (int r = 0; r < 4; ++r) {
                const int row = bm + wr * 128 + m * 16 + cr4 + r;
                storeC(&C[(size_t)row * ldc + col], acc[m][n][r] + bv);
            }
        }
}

// ---------------------------------------------------------------------------
// Windowed causal attention via MFMA (unchanged).
// ---------------------------------------------------------------------------
__global__ __launch_bounds__(256) void win_attn_mfma(
    const f16* __restrict__ qkv, f16* __restrict__ out, int w)
{
    __shared__ __align__(16) f16 Vs[4][64 * 40];   // per-wave [dim64][key32]
    __shared__ __align__(16) f16 Ps[4][16 * 40];   // per-wave [q16][key32]

    const int tid  = threadIdx.x;
    const int lane = tid & 63;
    const int wave = tid >> 6;
    const int b  = blockIdx.y;
    const int h  = blockIdx.z;
    const int q0 = (blockIdx.x * 4 + wave) * 16;
    const size_t bs = (size_t)b * 1024;

    const int fr  = lane & 15;
    const int grp = lane >> 4;
    const int fk8 = grp * 8;

    f16x8 aq[2];
    {
        const f16* qp = qkv + (bs + q0 + fr) * 1536 + h * 64 + fk8;
        aq[0] = *(const f16x8*)qp;
        aq[1] = *(const f16x8*)(qp + 32);
#pragma unroll
        for (int e = 0; e < 8; ++e) {
            aq[0][e] *= (f16)0.18033688;
            aq[1][e] *= (f16)0.18033688;
        }
    }

    f16x8 bk[2][2];
#pragma unroll
    for (int g = 0; g < 2; ++g) {
        int krow = q0 - 16 + g * 16 + fr;
        int kcl  = krow < 0 ? 0 : krow;
        const f16* kp = qkv + (bs + kcl) * 1536 + 512 + h * 64 + fk8;
        bk[g][0] = *(const f16x8*)kp;
        bk[g][1] = *(const f16x8*)(kp + 32);
    }

    {
        const int vk = lane & 31;
        const int vd = (lane >> 5) * 32;
        int vrow = q0 - 16 + vk;
        int vcl  = vrow < 0 ? 0 : vrow;
        const f16* vp = qkv + (bs + vcl) * 1536 + 1024 + h * 64 + vd;
        f16* vsw = Vs[wave];
#pragma unroll
        for (int t = 0; t < 4; ++t) {
            f16x8 vv = *(const f16x8*)(vp + t * 8);
#pragma unroll
            for (int e = 0; e < 8; ++e)
                vsw[(vd + t * 8 + e) * 40 + vk] = vv[e];
        }
    }

    f32x4 s[2];
#pragma unroll
    for (int g = 0; g < 2; ++g) {
        f32x4 z = (f32x4){0.f, 0.f, 0.f, 0.f};
        z = __builtin_amdgcn_mfma_f32_16x16x32_f16(aq[0], bk[g][0], z, 0, 0, 0);
        s[g] = __builtin_amdgcn_mfma_f32_16x16x32_f16(aq[1], bk[g][1], z, 0, 0, 0);
    }

    float l[4] = {0.f, 0.f, 0.f, 0.f};
#pragma unroll
    for (int g = 0; g < 2; ++g) {
        const int kpos = q0 - 16 + g * 16 + fr;
#pragma unroll
        for (int r = 0; r < 4; ++r) {
            const int diff = (grp * 4 + r) - (g * 16 + fr) + 16;
            const bool ok = (diff >= 0) && (diff < w) && (kpos >= 0);
            float p = ok ? exp2f(fminf(s[g][r], 15.9f)) : 0.f;
            l[r] += p;
            Ps[wave][(grp * 4 + r) * 40 + g * 16 + fr] = (f16)p;
        }
    }

    __builtin_amdgcn_wave_barrier();

    f16x8 pa = *(const f16x8*)&Ps[wave][fr * 40 + fk8];
    f32x4 acc[4];
#pragma unroll
    for (int j = 0; j < 4; ++j) {
        f16x8 bv = *(const f16x8*)&Vs[wave][(j * 16 + fr) * 40 + fk8];
        f32x4 z = (f32x4){0.f, 0.f, 0.f, 0.f};
        acc[j] = __builtin_amdgcn_mfma_f32_16x16x32_f16(pa, bv, z, 0, 0, 0);
    }

#pragma unroll
    for (int r = 0; r < 4; ++r)
#pragma unroll
        for (int msk = 1; msk < 16; msk <<= 1)
            l[r] += __shfl_xor(l[r], msk, 64);

#pragma unroll
    for (int j = 0; j < 4; ++j)
#pragma unroll
        for (int r = 0; r < 4; ++r) {
            const int q = q0 + grp * 4 + r;
            out[(bs + q) * 1536 + h * 64 + j * 16 + fr] = (f16)(acc[j][r] / l[r]);
        }
}

// ---------------------------------------------------------------------------
// Full attention, MFMA flash v5 (proven 74us).
// ---------------------------------------------------------------------------
__global__ __launch_bounds__(256, 4) void full_attn_mfma(
    const f16* __restrict__ qkv, f16* __restrict__ out)
{
    __shared__ __align__(16) f16 Ks[2][64 * 72];   // [key][d]
    __shared__ __align__(16) f16 Vs[2][64 * 72];   // [d][key]

    const int tid  = threadIdx.x;
    const int lane = tid & 63;
    const int wave = tid >> 6;
    const int q0 = blockIdx.x * 128;
    const int b  = blockIdx.y;
    const int h  = blockIdx.z;
    const size_t bs = (size_t)b * 1024;

    const int fr  = lane & 15;
    const int grp = lane >> 4;
    const int fk8 = grp * 8;

    f16x8 aq[2][2];
#pragma unroll
    for (int qt = 0; qt < 2; ++qt) {
        const f16* qp = qkv + (bs + q0 + wave * 32 + qt * 16 + fr) * 1536
                        + h * 64 + fk8;
        aq[qt][0] = *(const f16x8*)qp;
        aq[qt][1] = *(const f16x8*)(qp + 32);
#pragma unroll
        for (int e = 0; e < 8; ++e) {
            aq[qt][0][e] *= (f16)0.18033688;
            aq[qt][1][e] *= (f16)0.18033688;
        }
    }

    f16x8 onesf;
#pragma unroll
    for (int e = 0; e < 8; ++e) onesf[e] = (f16)1.0f;

    const f32x4 fz = (f32x4){0.f, 0.f, 0.f, 0.f};
    f32x4 lacc[2] = {fz, fz};
    f32x4 acc[2][4];
#pragma unroll
    for (int qt = 0; qt < 2; ++qt)
#pragma unroll
        for (int j = 0; j < 4; ++j)
            acc[qt][j] = fz;

    const int kr = tid >> 2, kc = (tid & 3) * 16;
    const int kp = (tid & 31) * 2, cb = (tid >> 5) * 8;

    const f16* kgp = qkv + (bs + kr) * 1536 + 512 + h * 64 + kc;
    const f16* vgp = qkv + (bs + kp) * 1536 + 1024 + h * 64 + cb;

    f16x8 ka, kb, va, vb;
    ka = *(const f16x8*)kgp; kb = *(const f16x8*)(kgp + 8);
    va = *(const f16x8*)vgp; vb = *(const f16x8*)(vgp + 1536);

    {
        f16* ks = &Ks[0][kr * 72 + kc];
        *(f16x8*)ks = ka; *(f16x8*)(ks + 8) = kb;
        f16* vs = &Vs[0][kp];
#pragma unroll
        for (int e = 0; e < 8; ++e) {
            f16x2 pr = { va[e], vb[e] };
            *(f16x2*)&vs[(cb + e) * 72] = pr;
        }
    }
    kgp += 64 * 1536; vgp += 64 * 1536;
    ka = *(const f16x8*)kgp; kb = *(const f16x8*)(kgp + 8);
    va = *(const f16x8*)vgp; vb = *(const f16x8*)(vgp + 1536);

    for (int t = 0; t < 16; ++t) {
        __syncthreads();
        const int p = t & 1;

        if (t + 1 < 16) {
            f16* ks = &Ks[p ^ 1][kr * 72 + kc];
            *(f16x8*)ks = ka; *(f16x8*)(ks + 8) = kb;
            f16* vs = &Vs[p ^ 1][kp];
#pragma unroll
            for (int e = 0; e < 8; ++e) {
                f16x2 pr = { va[e], vb[e] };
                *(f16x2*)&vs[(cb + e) * 72] = pr;
            }
            if (t + 2 < 16) {
                kgp += 64 * 1536; vgp += 64 * 1536;
                ka = *(const f16x8*)kgp; kb = *(const f16x8*)(kgp + 8);
                va = *(const f16x8*)vgp; vb = *(const f16x8*)(vgp + 1536);
            }
        }

        f16x8 kf[4][2];
#pragma unroll
        for (int j = 0; j < 4; ++j)
#pragma unroll
            for (int c = 0; c < 2; ++c)
                kf[j][c] = *(const f16x8*)&Ks[p][(j * 16 + fr) * 72 + c * 32 + fk8];

        f16x8 paf[2][2];
#pragma unroll
        for (int qt = 0; qt < 2; ++qt) {
            f32x4 s2[4];
#pragma unroll
            for (int j = 0; j < 4; ++j) {
                f32x4 z = __builtin_amdgcn_mfma_f32_16x16x32_f16(
                        kf[j][0], aq[qt][0], fz, 0, 0, 0);
                s2[j] = __builtin_amdgcn_mfma_f32_16x16x32_f16(
                        kf[j][1], aq[qt][1], z, 0, 0, 0);
            }

            unsigned int dw[4][2];
#pragma unroll
            for (int j = 0; j < 4; ++j) {
                float p0 = exp2f(fminf(s2[j][0], 15.9f));
                float p1 = exp2f(fminf(s2[j][1], 15.9f));
                float p2 = exp2f(fminf(s2[j][2], 15.9f));
                float p3 = exp2f(fminf(s2[j][3], 15.9f));
                f16x2 h0 = { (f16)p0, (f16)p1 };
                f16x2 h1 = { (f16)p2, (f16)p3 };
                dw[j][0] = __builtin_bit_cast(unsigned int, h0);
                dw[j][1] = __builtin_bit_cast(unsigned int, h1);
            }

            unsigned int pdw[2][4];
#pragma unroll
            for (int c = 0; c < 2; ++c)
#pragma unroll
                for (int T = 0; T < 2; ++T) {
                    unsigned int X = dw[2 * c][T];
                    unsigned int Y = dw[2 * c + 1][T];
                    asm("v_permlane32_swap_b32 %0, %1" : "+v"(X), "+v"(Y));
                    asm("v_permlane16_swap_b32 %0, %1" : "+v"(X), "+v"(Y));
                    pdw[c][T]     = X;
                    pdw[c][2 + T] = Y;
                }
            union { unsigned int u[4]; f16x8 hv; } cu;
#pragma unroll
            for (int c = 0; c < 2; ++c) {
                cu.u[0] = pdw[c][0]; cu.u[1] = pdw[c][1];
                cu.u[2] = pdw[c][2]; cu.u[3] = pdw[c][3];
                paf[qt][c] = cu.hv;
            }

            lacc[qt] = __builtin_amdgcn_mfma_f32_16x16x32_f16(
                paf[qt][0], onesf, lacc[qt], 0, 0, 0);
            lacc[qt] = __builtin_amdgcn_mfma_f32_16x16x32_f16(
                paf[qt][1], onesf, lacc[qt], 0, 0, 0);
        }

        f16x8 vf[4][2];
#pragma unroll
        for (int j = 0; j < 4; ++j)
#pragma unroll
            for (int c = 0; c < 2; ++c)
                vf[j][c] = *(const f16x8*)&Vs[p][(j * 16 + fr) * 72 + c * 32 + fk8];

#pragma unroll
        for (int qt = 0; qt < 2; ++qt)
#pragma unroll
            for (int j = 0; j < 4; ++j)
#pragma unroll
                for (int c = 0; c < 2; ++c)
                    acc[qt][j] = __builtin_amdgcn_mfma_f32_16x16x32_f16(
                        paf[qt][c], vf[j][c], acc[qt][j], 0, 0, 0);
    }

#pragma unroll
    for (int qt = 0; qt < 2; ++qt) {
        float inv[4];
#pragma unroll
        for (int r = 0; r < 4; ++r) inv[r] = 1.0f / lacc[qt][r];
#pragma unroll
        for (int j = 0; j < 4; ++j)
#pragma unroll
            for (int r = 0; r < 4; ++r) {
                const int q = q0 + wave * 32 + qt * 16 + grp * 4 + r;
                out[(bs + q) * 1536 + h * 64 + j * 16 + fr] =
                    (f16)(acc[qt][j][r] * inv[r]);
            }
    }
}

// ---------------------------------------------------------------------------
// launch
// ---------------------------------------------------------------------------
extern "C" void kernel_launch(void* const* d_in, const int* in_sizes, int n_in,
                              void* d_out, int out_size, void* d_ws, size_t ws_size,
                              hipStream_t stream)
{
    const float* x    = (const float*)d_in[0];   // [16,1024,512]
    const float* Wqkv = (const float*)d_in[1];   // [3,1536,512]
    const float* bqkv = (const float*)d_in[2];   // [3,1536]
    const float* Wo   = (const float*)d_in[3];   // [3,512,512]
    const float* bo   = (const float*)d_in[4];   // [3,512] (flat 1536)
    const float* Wf   = (const float*)d_in[5];   // [512,1536]
    const float* bfin = (const float*)d_in[6];   // [512]
    float* out = (float*)d_out;                  // [16,1024,512] fp32

    char* ws = (char*)d_ws;
    f16*   qkvbuf   = (f16*)ws;                        // 16384x1536 (50,331,648)
    f16*   attn_cat = (f16*)(ws + 50331648);           // 16384x1536 (50,331,648)
    f16*   wfh      = (f16*)(ws + 100663296);          // 512x1536   (1,572,864)
    f16*   WoT      = (f16*)(ws + 102236160);          // 3x512x512  (1,572,864)
    f16*   Wfo      = (f16*)(ws + 103809024);          // 512x1536   (1,572,864)
    float* bp       = (float*)(ws + 105381888);        // 512        (2,048)

    f16* xh    = (f16*)d_out;                          // 8,388,608 el (16.8 MB)
    f16* wqkvh = (f16*)((char*)d_out + 16777216);      // 2,359,296 el (4.7 MB)

    // fused prep: x/Wqkv/Wf -> f16, Wo transpose, bias fuse (one dispatch)
    prep_all<<<dim3(6528), 256, 0, stream>>>(
        x, Wqkv, Wf, Wo, bo, bfin, xh, wqkvh, wfh, WoT, bp);

    // Wfo[z] = Wf[:, 512z:512z+512] @ Wo[z]  (small; 2-phase kernel)
    gemm_mfma_nt<f16><<<dim3(4, 4, 3), 256, 0, stream>>>(
        wfh, 1536, 512, WoT, 512, 262144, nullptr, Wfo, 1536, 512, 512);

    for (int i = 0; i < 3; ++i) {
        // qkv_i = x @ Wqkv[i]^T + bqkv[i]  -> [16384,1536] f16
        // 8-phase GEMM: BN=192, grid 8x64 = 512 blocks (2 exact CU rounds)
        gemm_mfma_8ph<3, f16><<<dim3(8, 64), 512, 0, stream>>>(
            xh, 512, wqkvh + (size_t)i * 786432, 512, bqkv + i * 1536,
            qkvbuf, 1536, 512);

        if (i == 0)
            win_attn_mfma<<<dim3(16, 16, 8), 256, 0, stream>>>(
                qkvbuf, attn_cat + 0 * 512, 5);
        else if (i == 1)
            win_attn_mfma<<<dim3(16, 16, 8), 256, 0, stream>>>(
                qkvbuf, attn_cat + 1 * 512, 10);
        else
            full_attn_mfma<<<dim3(8, 16, 8), 256, 0, stream>>>(
                qkvbuf, attn_cat + 2 * 512);
    }

    // out = attn_cat @ Wfo^T + b'  (fp32 out), M=16384 N=512 K=1536
    // 8-phase GEMM: BN=128, grid 4x64 = 256 blocks (1 exact CU round)
    gemm_mfma_8ph<2, float><<<dim3(4, 64), 512, 0, stream>>>(
        attn_cat, 1536, Wfo, 1536, bp, out, 512, 1536);
}

// Round 6
// 369.643 us; speedup vs baseline: 1.2399x; 1.0452x over previous
//
#include <hip/hip_runtime.h>
#include <hip/hip_bf16.h>
#include <hip/hip_fp16.h>

// R13:
//  - attn_all: ONE dispatch fusing full_attn (1024 blocks, first) + win5
//    (2048) + win10 (2048). Independent work; win blocks backfill CUs while
//    long full blocks run. Gated on ws_size >= 206MB (needs 3 qkv buffers);
//    fallback = R12 serial flow.
//  - qkv GEMMs z-batched into one dispatch (fused path): grid (8,64,3).
//  - win_attn v2: swapped QK^T + permlane P redistribute + l via ones-MFMA
//    (full_attn's proven tricks). No Ps buffer, no shfl reduce, LDS 20.5KB.
//  - 8ph GEMM gains z-stride params (bzs/bizs/czs). Everything else as R12.

using f16 = _Float16;
typedef _Float16 f16x8 __attribute__((ext_vector_type(8)));
typedef _Float16 f16x2 __attribute__((ext_vector_type(2)));
typedef float    f32x4 __attribute__((ext_vector_type(4)));

__device__ inline void storeC(float* p, float v) { *p = v; }
__device__ inline void storeC(f16* p, float v)   { *p = (f16)v; }

__device__ inline void async_cp16(const f16* g, f16* l) {
    __builtin_amdgcn_global_load_lds(
        (const __attribute__((address_space(1))) unsigned int*)g,
        (__attribute__((address_space(3))) unsigned int*)l,
        16, 0, 0);
}

// ---------------------------------------------------------------------------
// prep_all (unchanged from R12)
// ---------------------------------------------------------------------------
__global__ __launch_bounds__(256) void prep_all(
    const float* __restrict__ x, const float* __restrict__ Wqkv,
    const float* __restrict__ Wf, const float* __restrict__ Wo,
    const float* __restrict__ bo, const float* __restrict__ bfv,
    f16* __restrict__ xh, f16* __restrict__ wqkvh, f16* __restrict__ wfh,
    f16* __restrict__ WoT, float* __restrict__ bp)
{
    __shared__ float t[32][33];
    const int bid = blockIdx.x;
    const int tid = threadIdx.x;

    if (bid < 5632) {
        const float* in; f16* outp; int base;
        if (bid < 4096)      { in = x;    outp = xh;    base = bid; }
        else if (bid < 5248) { in = Wqkv; outp = wqkvh; base = bid - 4096; }
        else                 { in = Wf;   outp = wfh;   base = bid - 5248; }
        int i = (base * 256 + tid) * 8;
        float4 a = *(const float4*)(in + i);
        float4 b = *(const float4*)(in + i + 4);
        f16x8 h = { (f16)a.x, (f16)a.y, (f16)a.z, (f16)a.w,
                    (f16)b.x, (f16)b.y, (f16)b.z, (f16)b.w };
        *(f16x8*)(outp + i) = h;
    } else if (bid < 6400) {
        const int idx = bid - 5632;
        const int z  = idx >> 8;
        const int bx = (idx & 15) * 32;
        const int by = ((idx >> 4) & 15) * 32;
        const int tx = tid & 31;
        const int ty = tid >> 5;
#pragma unroll
        for (int r = ty; r < 32; r += 8)
            t[r][tx] = Wo[(size_t)z * 262144 + (by + r) * 512 + bx + tx];
        __syncthreads();
#pragma unroll
        for (int r = ty; r < 32; r += 8)
            WoT[(size_t)z * 262144 + (bx + r) * 512 + by + tx] = (f16)t[tx][r];
    } else {
        const int o = (bid - 6400) * 4 + (tid >> 6);
        const int lane = tid & 63;
        float s = 0.f;
        for (int j = lane; j < 1536; j += 64) s += Wf[o * 1536 + j] * bo[j];
#pragma unroll
        for (int msk = 1; msk < 64; msk <<= 1) s += __shfl_xor(s, msk, 64);
        if (lane == 0) bp[o] = s + bfv[o];
    }
}

// ---------------------------------------------------------------------------
// small 128x128 2-phase GEMM (Wfo product only)
// ---------------------------------------------------------------------------
template <typename TC>
__global__ __launch_bounds__(256) void gemm_mfma_nt(
    const f16* __restrict__ A, int lda, long azs,
    const f16* __restrict__ B, int ldb, long bzs,
    const float* __restrict__ bias,
    TC* __restrict__ C, int ldc, long czs,
    int K)
{
    __shared__ __align__(16) f16 As[2][128 * 32];
    __shared__ __align__(16) f16 Bs[2][128 * 32];

    const int tid  = threadIdx.x;
    const int lane = tid & 63;
    const int wave = tid >> 6;
    const int wm = (wave >> 1) * 64;
    const int wn = (wave & 1) * 64;
    const int bm = blockIdx.y * 128;
    const int bn = blockIdx.x * 128;
    const int z  = blockIdx.z;

    const int srow = tid >> 2;
    const int scol = (tid & 3) * 8;
    const int soff = srow * 32 + scol;

    const f16* Ag = A + (size_t)z * azs + (size_t)(bm + srow) * lda + scol;
    const f16* Bg = B + (size_t)z * bzs + (size_t)(bn + srow) * ldb + scol;

    f32x4 acc[4][4];
#pragma unroll
    for (int i = 0; i < 4; ++i)
#pragma unroll
        for (int j = 0; j < 4; ++j)
            acc[i][j] = (f32x4){0.f, 0.f, 0.f, 0.f};

    const int fr = lane & 15;
    const int fk = (lane >> 4) * 8;

    async_cp16(Ag, &As[0][soff]);
    async_cp16(Ag + (size_t)64 * lda, &As[0][soff + 64 * 32]);
    async_cp16(Bg, &Bs[0][soff]);
    async_cp16(Bg + (size_t)64 * ldb, &Bs[0][soff + 64 * 32]);

    const int nt = K >> 5;
    for (int t = 0; t < nt; ++t) {
        __syncthreads();
        const int p = t & 1;
        if (t + 1 < nt) {
            const int k1 = (t + 1) * 32;
            async_cp16(Ag + k1, &As[p ^ 1][soff]);
            async_cp16(Ag + k1 + (size_t)64 * lda, &As[p ^ 1][soff + 64 * 32]);
            async_cp16(Bg + k1, &Bs[p ^ 1][soff]);
            async_cp16(Bg + k1 + (size_t)64 * ldb, &Bs[p ^ 1][soff + 64 * 32]);
        }

        f16x8 af[4], bfr[4];
#pragma unroll
        for (int i = 0; i < 4; ++i)
            af[i] = *(const f16x8*)&As[p][(wm + i * 16 + fr) * 32 + fk];
#pragma unroll
        for (int j = 0; j < 4; ++j)
            bfr[j] = *(const f16x8*)&Bs[p][(wn + j * 16 + fr) * 32 + fk];
#pragma unroll
        for (int i = 0; i < 4; ++i)
#pragma unroll
            for (int j = 0; j < 4; ++j)
                acc[i][j] = __builtin_amdgcn_mfma_f32_16x16x32_f16(
                    af[i], bfr[j], acc[i][j], 0, 0, 0);
    }

    const int cn  = lane & 15;
    const int cr4 = (lane >> 4) * 4;
#pragma unroll
    for (int i = 0; i < 4; ++i) {
#pragma unroll
        for (int j = 0; j < 4; ++j) {
            const int col = bn + wn + j * 16 + cn;
            const float bv = bias ? bias[col] : 0.f;
#pragma unroll
            for (int r = 0; r < 4; ++r) {
                const int row = bm + wm + i * 16 + cr4 + r;
                storeC(&C[(size_t)z * czs + (size_t)row * ldc + col],
                       acc[i][j][r] + bv);
            }
        }
    }
}

// ---------------------------------------------------------------------------
// 8-phase counted-vmcnt GEMM (R12, + z-batch strides).
// ---------------------------------------------------------------------------
template <int NR, typename TC>
__global__ __launch_bounds__(512, 2) void gemm_mfma_8ph(
    const f16* __restrict__ A, int lda,
    const f16* __restrict__ B, int ldb, long bzs,
    const float* __restrict__ bias, long bizs,
    TC* __restrict__ C, int ldc, long czs, int K)
{
    __shared__ __align__(16) f16 As[2][256 * 64];
    __shared__ __align__(16) f16 Bs[2][NR * 64 * 64];

    const int z = blockIdx.z;
    B += (size_t)z * bzs;
    C += (size_t)z * czs;
    const float* biasz = bias ? bias + (size_t)z * bizs : nullptr;

    const int tid  = threadIdx.x;
    const int lane = tid & 63;
    const int wave = tid >> 6;
    const int wr = wave >> 2;
    const int wc = wave & 3;
    const int bm = blockIdx.y * 256;
    const int bn = blockIdx.x * (NR * 64);
    const int fr  = lane & 15;
    const int grp = lane >> 4;

    const int c0 = ((0 + grp) ^ (fr & 7)) * 8;
    const int c1 = ((4 + grp) ^ (fr & 7)) * 8;

    const int srow = tid >> 3;
    const int scol = ((tid & 7) ^ (srow & 7)) * 8;
    const f16* Ag = A + (size_t)(bm + srow) * lda + scol;
    const f16* Bg = B + (size_t)(bn + srow) * ldb + scol;

    f32x4 acc[8][NR];
#pragma unroll
    for (int m = 0; m < 8; ++m)
#pragma unroll
        for (int n = 0; n < NR; ++n)
            acc[m][n] = (f32x4){0.f, 0.f, 0.f, 0.f};

    const int arow = wr * 128 + fr;
    const int brow = wc * (NR * 16) + fr;

    f16x8 bfrag[NR][2];
    f16x8 aP[2][2], aQ[2][2];

    auto stage = [&](int p, int kt) {
        const f16* a_ = Ag + (size_t)kt * 64;
        const f16* b_ = Bg + (size_t)kt * 64;
        f16* al = &As[p][tid * 8];
        f16* bl = &Bs[p][tid * 8];
#pragma unroll
        for (int i = 0; i < 4; ++i)
            async_cp16(a_ + (size_t)(i * 64) * lda, al + i * 4096);
#pragma unroll
        for (int i = 0; i < NR; ++i)
            async_cp16(b_ + (size_t)(i * 64) * ldb, bl + i * 4096);
    };

    const int nt = K >> 6;
    stage(0, 0);
    stage(1, 1);

    for (int t = 0; t < nt; ++t) {
        const int p = t & 1;
        if (t + 1 < nt) {
            if constexpr (NR == 3)
                asm volatile("s_waitcnt vmcnt(7)" ::: "memory");
            else
                asm volatile("s_waitcnt vmcnt(6)" ::: "memory");
        } else {
            asm volatile("s_waitcnt vmcnt(0)" ::: "memory");
        }
        __builtin_amdgcn_s_barrier();

        const f16* asb = As[p];
        const f16* bsb = Bs[p];

        auto loada = [&](f16x8 (&d)[2][2], int mq) {
#pragma unroll
            for (int m2 = 0; m2 < 2; ++m2) {
                const int ro = (arow + (mq * 2 + m2) * 16) * 64;
                d[m2][0] = *(const f16x8*)&asb[ro + c0];
                d[m2][1] = *(const f16x8*)&asb[ro + c1];
            }
        };
        auto qmfma = [&](const f16x8 (&a_)[2][2], int mq) {
            __builtin_amdgcn_s_setprio(1);
#pragma unroll
            for (int m2 = 0; m2 < 2; ++m2)
#pragma unroll
                for (int n = 0; n < NR; ++n) {
                    f32x4 zz = __builtin_amdgcn_mfma_f32_16x16x32_f16(
                        a_[m2][0], bfrag[n][0], acc[mq * 2 + m2][n], 0, 0, 0);
                    acc[mq * 2 + m2][n] = __builtin_amdgcn_mfma_f32_16x16x32_f16(
                        a_[m2][1], bfrag[n][1], zz, 0, 0, 0);
                }
            __builtin_amdgcn_s_setprio(0);
        };

#pragma unroll
        for (int n = 0; n < NR; ++n) {
            const int ro = (brow + n * 16) * 64;
            bfrag[n][0] = *(const f16x8*)&bsb[ro + c0];
            bfrag[n][1] = *(const f16x8*)&bsb[ro + c1];
        }
        loada(aP, 0);
        asm volatile("s_waitcnt lgkmcnt(0)" ::: "memory");
        __builtin_amdgcn_sched_barrier(0);

        loada(aQ, 1);
        qmfma(aP, 0);
        asm volatile("s_waitcnt lgkmcnt(0)" ::: "memory");
        __builtin_amdgcn_sched_barrier(0);

        loada(aP, 2);
        qmfma(aQ, 1);
        asm volatile("s_waitcnt lgkmcnt(0)" ::: "memory");
        __builtin_amdgcn_sched_barrier(0);

        loada(aQ, 3);
        qmfma(aP, 2);
        asm volatile("s_waitcnt lgkmcnt(0)" ::: "memory");
        __builtin_amdgcn_sched_barrier(0);

        __builtin_amdgcn_s_barrier();
        if (t + 2 < nt) stage(p, t + 2);
        qmfma(aQ, 3);
    }

    const int cn  = lane & 15;
    const int cr4 = (lane >> 4) * 4;
#pragma unroll
    for (int m = 0; m < 8; ++m)
#pragma unroll
        for (int n = 0; n < NR; ++n) {
            const int col = bn + wc * (NR * 16) + n * 16 + cn;
            const float bv = biasz ? biasz[col] : 0.f;
#pragma unroll
            for (int r = 0; r < 4; ++r) {
                const int row = bm + wr * 128 + m * 16 + cr4 + r;
                storeC(&C[(size_t)row * ldc + col], acc[m][n][r] + bv);
            }
        }
}

// ---------------------------------------------------------------------------
// Windowed attention body v2: swapped QK^T, permlane P, l via ones-MFMA.
// sm: >= 4*64*40 f16 (20480 B). out pre-offset to attn_cat slice.
// ---------------------------------------------------------------------------
__device__ __forceinline__ void win_attn_body(
    const f16* __restrict__ qkv, f16* __restrict__ out, f16* sm,
    int w, int bx, int b, int h)
{
    const int tid  = threadIdx.x;
    const int lane = tid & 63;
    const int wave = tid >> 6;
    const int q0 = (bx * 4 + wave) * 16;
    const size_t bs = (size_t)b * 1024;

    const int fr  = lane & 15;
    const int grp = lane >> 4;
    const int fk8 = grp * 8;

    f16* vsw = sm + wave * 2560;   // [dim64][key32] stride 40

    // Q B-frags (swapped: Q is the B operand), scaled by 1/8*log2(e)
    f16x8 aq[2];
    {
        const f16* qp = qkv + (bs + q0 + fr) * 1536 + h * 64 + fk8;
        aq[0] = *(const f16x8*)qp;
        aq[1] = *(const f16x8*)(qp + 32);
#pragma unroll
        for (int e = 0; e < 8; ++e) {
            aq[0][e] *= (f16)0.18033688;
            aq[1][e] *= (f16)0.18033688;
        }
    }

    // K A-frags, key row = q0-16+g*16+fr (clamped; masked by kpos>=0)
    f16x8 bk[2][2];
#pragma unroll
    for (int g = 0; g < 2; ++g) {
        int krow = q0 - 16 + g * 16 + fr;
        int kcl  = krow < 0 ? 0 : krow;
        const f16* kp = qkv + (bs + kcl) * 1536 + 512 + h * 64 + fk8;
        bk[g][0] = *(const f16x8*)kp;
        bk[g][1] = *(const f16x8*)(kp + 32);
    }

    // stage V transposed: vsw[d][key]
    {
        const int vk = lane & 31;
        const int vd = (lane >> 5) * 32;
        int vrow = q0 - 16 + vk;
        int vcl  = vrow < 0 ? 0 : vrow;
        const f16* vp = qkv + (bs + vcl) * 1536 + 1024 + h * 64 + vd;
#pragma unroll
        for (int t = 0; t < 4; ++t) {
            f16x8 vv = *(const f16x8*)(vp + t * 8);
#pragma unroll
            for (int e = 0; e < 8; ++e)
                vsw[(vd + t * 8 + e) * 40 + vk] = vv[e];
        }
    }

    // swapped QK^T: s[g][r] = S[k = g*16+grp*4+r][q = fr]
    const f32x4 fz = (f32x4){0.f, 0.f, 0.f, 0.f};
    f32x4 s[2];
#pragma unroll
    for (int g = 0; g < 2; ++g) {
        f32x4 z = __builtin_amdgcn_mfma_f32_16x16x32_f16(
            bk[g][0], aq[0], fz, 0, 0, 0);
        s[g] = __builtin_amdgcn_mfma_f32_16x16x32_f16(
            bk[g][1], aq[1], z, 0, 0, 0);
    }

    // mask + exp2 + pack (lane holds k = g*16+grp*4+r, q = fr)
    unsigned int dw[2][2];
#pragma unroll
    for (int g = 0; g < 2; ++g) {
        float p[4];
#pragma unroll
        for (int r = 0; r < 4; ++r) {
            const int kin  = g * 16 + grp * 4 + r;       // key idx in window
            const int kpos = q0 - 16 + kin;              // absolute key
            const int diff = fr - kin + 16;              // q - k
            const bool ok = (diff >= 0) && (diff < w) && (kpos >= 0);
            p[r] = ok ? exp2f(fminf(s[g][r], 15.9f)) : 0.f;
        }
        f16x2 h0 = { (f16)p[0], (f16)p[1] };
        f16x2 h1 = { (f16)p[2], (f16)p[3] };
        dw[g][0] = __builtin_bit_cast(unsigned int, h0);
        dw[g][1] = __builtin_bit_cast(unsigned int, h1);
    }

    // permlane redistribute (c=0 instance of the verified algebra):
    // paf = P[q=fr][k = grp*8 + e], k in [0,32)
    unsigned int pdw[4];
#pragma unroll
    for (int T = 0; T < 2; ++T) {
        unsigned int X = dw[0][T];
        unsigned int Y = dw[1][T];
        asm("v_permlane32_swap_b32 %0, %1" : "+v"(X), "+v"(Y));
        asm("v_permlane16_swap_b32 %0, %1" : "+v"(X), "+v"(Y));
        pdw[T]     = X;
        pdw[2 + T] = Y;
    }
    union { unsigned int u[4]; f16x8 hv; } cu;
    cu.u[0] = pdw[0]; cu.u[1] = pdw[1]; cu.u[2] = pdw[2]; cu.u[3] = pdw[3];
    const f16x8 paf = cu.hv;

    // l via ones-MFMA: lacc[r] = l[q = grp*4+r]
    f16x8 onesf;
#pragma unroll
    for (int e = 0; e < 8; ++e) onesf[e] = (f16)1.0f;
    f32x4 lacc = __builtin_amdgcn_mfma_f32_16x16x32_f16(paf, onesf, fz, 0, 0, 0);

    __builtin_amdgcn_wave_barrier();   // order V scatter before Vs reads

    // PV: acc[j][r] = O[q=grp*4+r][d=j*16+fr]
    f32x4 acc[4];
#pragma unroll
    for (int j = 0; j < 4; ++j) {
        f16x8 bv = *(const f16x8*)&vsw[(j * 16 + fr) * 40 + fk8];
        acc[j] = __builtin_amdgcn_mfma_f32_16x16x32_f16(paf, bv, fz, 0, 0, 0);
    }

    float inv[4];
#pragma unroll
    for (int r = 0; r < 4; ++r) inv[r] = 1.0f / lacc[r];
#pragma unroll
    for (int j = 0; j < 4; ++j)
#pragma unroll
        for (int r = 0; r < 4; ++r) {
            const int q = q0 + grp * 4 + r;
            out[(bs + q) * 1536 + h * 64 + j * 16 + fr] =
                (f16)(acc[j][r] * inv[r]);
        }
}

// ---------------------------------------------------------------------------
// Full attention body (R9/R11 proven). sm: >= 18432 f16 (36864 B).
// Layout: Ks[p] at p*4608, Vs[p] at 9216 + p*4608 (f16 units).
// ---------------------------------------------------------------------------
__device__ __forceinline__ void full_attn_body(
    const f16* __restrict__ qkv, f16* __restrict__ out, f16* sm,
    int bx, int b, int h)
{
    const int tid  = threadIdx.x;
    const int lane = tid & 63;
    const int wave = tid >> 6;
    const int q0 = bx * 128;
    const size_t bs = (size_t)b * 1024;

    const int fr  = lane & 15;
    const int grp = lane >> 4;
    const int fk8 = grp * 8;

    f16x8 aq[2][2];
#pragma unroll
    for (int qt = 0; qt < 2; ++qt) {
        const f16* qp = qkv + (bs + q0 + wave * 32 + qt * 16 + fr) * 1536
                        + h * 64 + fk8;
        aq[qt][0] = *(const f16x8*)qp;
        aq[qt][1] = *(const f16x8*)(qp + 32);
#pragma unroll
        for (int e = 0; e < 8; ++e) {
            aq[qt][0][e] *= (f16)0.18033688;
            aq[qt][1][e] *= (f16)0.18033688;
        }
    }

    f16x8 onesf;
#pragma unroll
    for (int e = 0; e < 8; ++e) onesf[e] = (f16)1.0f;

    const f32x4 fz = (f32x4){0.f, 0.f, 0.f, 0.f};
    f32x4 lacc[2] = {fz, fz};
    f32x4 acc[2][4];
#pragma unroll
    for (int qt = 0; qt < 2; ++qt)
#pragma unroll
        for (int j = 0; j < 4; ++j)
            acc[qt][j] = fz;

    const int kr = tid >> 2, kc = (tid & 3) * 16;
    const int kp = (tid & 31) * 2, cb = (tid >> 5) * 8;

    const f16* kgp = qkv + (bs + kr) * 1536 + 512 + h * 64 + kc;
    const f16* vgp = qkv + (bs + kp) * 1536 + 1024 + h * 64 + cb;

    f16x8 ka, kb, va, vb;
    ka = *(const f16x8*)kgp; kb = *(const f16x8*)(kgp + 8);
    va = *(const f16x8*)vgp; vb = *(const f16x8*)(vgp + 1536);

    {
        f16* ks = sm + kr * 72 + kc;
        *(f16x8*)ks = ka; *(f16x8*)(ks + 8) = kb;
        f16* vs = sm + 9216 + kp;
#pragma unroll
        for (int e = 0; e < 8; ++e) {
            f16x2 pr = { va[e], vb[e] };
            *(f16x2*)&vs[(cb + e) * 72] = pr;
        }
    }
    kgp += 64 * 1536; vgp += 64 * 1536;
    ka = *(const f16x8*)kgp; kb = *(const f16x8*)(kgp + 8);
    va = *(const f16x8*)vgp; vb = *(const f16x8*)(vgp + 1536);

    for (int t = 0; t < 16; ++t) {
        __syncthreads();
        const int p = t & 1;
        const f16* Ksp = sm + p * 4608;
        const f16* Vsp = sm + 9216 + p * 4608;

        if (t + 1 < 16) {
            f16* ks = sm + (p ^ 1) * 4608 + kr * 72 + kc;
            *(f16x8*)ks = ka; *(f16x8*)(ks + 8) = kb;
            f16* vs = sm + 9216 + (p ^ 1) * 4608 + kp;
#pragma unroll
            for (int e = 0; e < 8; ++e) {
                f16x2 pr = { va[e], vb[e] };
                *(f16x2*)&vs[(cb + e) * 72] = pr;
            }
            if (t + 2 < 16) {
                kgp += 64 * 1536; vgp += 64 * 1536;
                ka = *(const f16x8*)kgp; kb = *(const f16x8*)(kgp + 8);
                va = *(const f16x8*)vgp; vb = *(const f16x8*)(vgp + 1536);
            }
        }

        f16x8 kf[4][2];
#pragma unroll
        for (int j = 0; j < 4; ++j)
#pragma unroll
            for (int c = 0; c < 2; ++c)
                kf[j][c] = *(const f16x8*)&Ksp[(j * 16 + fr) * 72 + c * 32 + fk8];

        f16x8 paf[2][2];
#pragma unroll
        for (int qt = 0; qt < 2; ++qt) {
            f32x4 s2[4];
#pragma unroll
            for (int j = 0; j < 4; ++j) {
                f32x4 z = __builtin_amdgcn_mfma_f32_16x16x32_f16(
                        kf[j][0], aq[qt][0], fz, 0, 0, 0);
                s2[j] = __builtin_amdgcn_mfma_f32_16x16x32_f16(
                        kf[j][1], aq[qt][1], z, 0, 0, 0);
            }

            unsigned int dw[4][2];
#pragma unroll
            for (int j = 0; j < 4; ++j) {
                float p0 = exp2f(fminf(s2[j][0], 15.9f));
                float p1 = exp2f(fminf(s2[j][1], 15.9f));
                float p2 = exp2f(fminf(s2[j][2], 15.9f));
                float p3 = exp2f(fminf(s2[j][3], 15.9f));
                f16x2 h0 = { (f16)p0, (f16)p1 };
                f16x2 h1 = { (f16)p2, (f16)p3 };
                dw[j][0] = __builtin_bit_cast(unsigned int, h0);
                dw[j][1] = __builtin_bit_cast(unsigned int, h1);
            }

            unsigned int pdw[2][4];
#pragma unroll
            for (int c = 0; c < 2; ++c)
#pragma unroll
                for (int T = 0; T < 2; ++T) {
                    unsigned int X = dw[2 * c][T];
                    unsigned int Y = dw[2 * c + 1][T];
                    asm("v_permlane32_swap_b32 %0, %1" : "+v"(X), "+v"(Y));
                    asm("v_permlane16_swap_b32 %0, %1" : "+v"(X), "+v"(Y));
                    pdw[c][T]     = X;
                    pdw[c][2 + T] = Y;
                }
            union { unsigned int u[4]; f16x8 hv; } cu;
#pragma unroll
            for (int c = 0; c < 2; ++c) {
                cu.u[0] = pdw[c][0]; cu.u[1] = pdw[c][1];
                cu.u[2] = pdw[c][2]; cu.u[3] = pdw[c][3];
                paf[qt][c] = cu.hv;
            }

            lacc[qt] = __builtin_amdgcn_mfma_f32_16x16x32_f16(
                paf[qt][0], onesf, lacc[qt], 0, 0, 0);
            lacc[qt] = __builtin_amdgcn_mfma_f32_16x16x32_f16(
                paf[qt][1], onesf, lacc[qt], 0, 0, 0);
        }

        f16x8 vf[4][2];
#pragma unroll
        for (int j = 0; j < 4; ++j)
#pragma unroll
            for (int c = 0; c < 2; ++c)
                vf[j][c] = *(const f16x8*)&Vsp[(j * 16 + fr) * 72 + c * 32 + fk8];

#pragma unroll
        for (int qt = 0; qt < 2; ++qt)
#pragma unroll
            for (int j = 0; j < 4; ++j)
#pragma unroll
                for (int c = 0; c < 2; ++c)
                    acc[qt][j] = __builtin_amdgcn_mfma_f32_16x16x32_f16(
                        paf[qt][c], vf[j][c], acc[qt][j], 0, 0, 0);
    }

#pragma unroll
    for (int qt = 0; qt < 2; ++qt) {
        float inv[4];
#pragma unroll
        for (int r = 0; r < 4; ++r) inv[r] = 1.0f / lacc[qt][r];
#pragma unroll
        for (int j = 0; j < 4; ++j)
#pragma unroll
            for (int r = 0; r < 4; ++r) {
                const int q = q0 + wave * 32 + qt * 16 + grp * 4 + r;
                out[(bs + q) * 1536 + h * 64 + j * 16 + fr] =
                    (f16)(acc[qt][j][r] * inv[r]);
            }
    }
}

// ---------------------------------------------------------------------------
// standalone kernels (fallback path)
// ---------------------------------------------------------------------------
__global__ __launch_bounds__(256) void win_attn_mfma(
    const f16* __restrict__ qkv, f16* __restrict__ out, int w)
{
    __shared__ __align__(16) f16 sm[4 * 2560];
    win_attn_body(qkv, out, sm, w, blockIdx.x, blockIdx.y, blockIdx.z);
}

__global__ __launch_bounds__(256, 4) void full_attn_mfma(
    const f16* __restrict__ qkv, f16* __restrict__ out)
{
    __shared__ __align__(16) f16 sm[18432];
    full_attn_body(qkv, out, sm, blockIdx.x, blockIdx.y, blockIdx.z);
}

// ---------------------------------------------------------------------------
// fused attention: 5120 blocks. [0,1024): full on qkv2 (longest first);
// [1024,3072): win w=5 on qkv0; [3072,5120): win w=10 on qkv1.
// ---------------------------------------------------------------------------
__global__ __launch_bounds__(256, 4) void attn_all(
    const f16* __restrict__ q0b, const f16* __restrict__ q1b,
    const f16* __restrict__ q2b, f16* __restrict__ cat)
{
    __shared__ __align__(16) f16 sm[18432];
    const int bid = blockIdx.x;
    if (bid < 1024) {
        full_attn_body(q2b, cat + 1024, sm, bid & 7, (bid >> 3) & 15, bid >> 7);
    } else if (bid < 3072) {
        const int i = bid - 1024;
        win_attn_body(q0b, cat, sm, 5, i & 15, (i >> 4) & 15, i >> 8);
    } else {
        const int i = bid - 3072;
        win_attn_body(q1b, cat + 512, sm, 10, i & 15, (i >> 4) & 15, i >> 8);
    }
}

// ---------------------------------------------------------------------------
// launch
// ---------------------------------------------------------------------------
extern "C" void kernel_launch(void* const* d_in, const int* in_sizes, int n_in,
                              void* d_out, int out_size, void* d_ws, size_t ws_size,
                              hipStream_t stream)
{
    const float* x    = (const float*)d_in[0];   // [16,1024,512]
    const float* Wqkv = (const float*)d_in[1];   // [3,1536,512]
    const float* bqkv = (const float*)d_in[2];   // [3,1536]
    const float* Wo   = (const float*)d_in[3];   // [3,512,512]
    const float* bo   = (const float*)d_in[4];   // [3,512] (flat 1536)
    const float* Wf   = (const float*)d_in[5];   // [512,1536]
    const float* bfin = (const float*)d_in[6];   // [512]
    float* out = (float*)d_out;                  // [16,1024,512] fp32

    f16* xh    = (f16*)d_out;                          // 16.8 MB scratch
    f16* wqkvh = (f16*)((char*)d_out + 16777216);      // 4.7 MB scratch
    char* ws = (char*)d_ws;

    const size_t QKV_EL = 25165824;          // 16384*1536 f16 elements
    const size_t QKV_B  = 50331648;          // bytes

    // fused path needs 3 qkv buffers + attn_cat + weights = 206,047,232 B
    const bool fused = ws_size >= (size_t)206047232;

    if (fused) {
        f16*   qkv0     = (f16*)ws;                          // 3 x 50.33 MB
        f16*   attn_cat = (f16*)(ws + 3 * QKV_B);            // 50.33 MB
        f16*   wfh      = (f16*)(ws + 3 * QKV_B + QKV_B);
        f16*   WoT      = (f16*)((char*)wfh + 1572864);
        f16*   Wfo      = (f16*)((char*)WoT + 1572864);
        float* bp       = (float*)((char*)Wfo + 1572864);

        prep_all<<<dim3(6528), 256, 0, stream>>>(
            x, Wqkv, Wf, Wo, bo, bfin, xh, wqkvh, wfh, WoT, bp);

        gemm_mfma_nt<f16><<<dim3(4, 4, 3), 256, 0, stream>>>(
            wfh, 1536, 512, WoT, 512, 262144, nullptr, Wfo, 1536, 512, 512);

        // all three qkv projections, z-batched (1536 blocks = 6 CU rounds)
        gemm_mfma_8ph<3, f16><<<dim3(8, 64, 3), 512, 0, stream>>>(
            xh, 512, wqkvh, 512, 786432, bqkv, 1536,
            qkv0, 1536, (long)QKV_EL, 512);

        // all three attentions in one dispatch
        attn_all<<<dim3(5120), 256, 0, stream>>>(
            qkv0, qkv0 + QKV_EL, qkv0 + 2 * QKV_EL, attn_cat);

        gemm_mfma_8ph<2, float><<<dim3(4, 64, 1), 512, 0, stream>>>(
            attn_cat, 1536, Wfo, 1536, 0, bp, 0, out, 512, 0, 1536);
    } else {
        // R12 serial flow (single qkv buffer)
        f16*   qkvbuf   = (f16*)ws;
        f16*   attn_cat = (f16*)(ws + QKV_B);
        f16*   wfh      = (f16*)(ws + 2 * QKV_B);
        f16*   WoT      = (f16*)(ws + 2 * QKV_B + 1572864);
        f16*   Wfo      = (f16*)(ws + 2 * QKV_B + 2 * 1572864);
        float* bp       = (float*)(ws + 2 * QKV_B + 3 * 1572864);

        prep_all<<<dim3(6528), 256, 0, stream>>>(
            x, Wqkv, Wf, Wo, bo, bfin, xh, wqkvh, wfh, WoT, bp);

        gemm_mfma_nt<f16><<<dim3(4, 4, 3), 256, 0, stream>>>(
            wfh, 1536, 512, WoT, 512, 262144, nullptr, Wfo, 1536, 512, 512);

        for (int i = 0; i < 3; ++i) {
            gemm_mfma_8ph<3, f16><<<dim3(8, 64, 1), 512, 0, stream>>>(
                xh, 512, wqkvh + (size_t)i * 786432, 512, 0,
                bqkv + i * 1536, 0, qkvbuf, 1536, 0, 512);

            if (i == 0)
                win_attn_mfma<<<dim3(16, 16, 8), 256, 0, stream>>>(
                    qkvbuf, attn_cat + 0 * 512, 5);
            else if (i == 1)
                win_attn_mfma<<<dim3(16, 16, 8), 256, 0, stream>>>(
                    qkvbuf, attn_cat + 1 * 512, 10);
            else
                full_attn_mfma<<<dim3(8, 16, 8), 256, 0, stream>>>(
                    qkvbuf, attn_cat + 2 * 512);
        }

        gemm_mfma_8ph<2, float><<<dim3(4, 64, 1), 512, 0, stream>>>(
            attn_cat, 1536, Wfo, 1536, 0, bp, 0, out, 512, 0, 1536);
    }
}

// Round 8
// 335.675 us; speedup vs baseline: 1.3654x; 1.1012x over previous
//
#include <hip/hip_runtime.h>
#include <hip/hip_bf16.h>
#include <hip/hip_fp16.h>

// R14 (resubmit — previous round hit GPUAcquisitionTimeout, never measured):
//   + XCD-chunked bijective block swizzle in gemm_mfma_8ph (T1).
//   R13 counters: qkv z-batched GEMM = 135us, FETCH 201MB vs ~22MB ideal —
//   the 8 consecutive blocks sharing an A panel round-robin onto 8 DIFFERENT
//   XCD L2s, so every A panel is HBM-fetched once per XCD; with 1 block/CU
//   there is no cross-block MLP to hide the per-CU HBM gate.
//   Fix: lid = (raw%8)*(nwg/8) + raw/8 (nwg%8==0 -> bijective). Co-resident
//   set per XCD becomes 4 by x 8 bx: A 1MB + B 1.57MB < 4MiB L2.
//   Output bit-identical (pure block permutation). Everything else = R13.

using f16 = _Float16;
typedef _Float16 f16x8 __attribute__((ext_vector_type(8)));
typedef _Float16 f16x2 __attribute__((ext_vector_type(2)));
typedef float    f32x4 __attribute__((ext_vector_type(4)));

__device__ inline void storeC(float* p, float v) { *p = v; }
__device__ inline void storeC(f16* p, float v)   { *p = (f16)v; }

__device__ inline void async_cp16(const f16* g, f16* l) {
    __builtin_amdgcn_global_load_lds(
        (const __attribute__((address_space(1))) unsigned int*)g,
        (__attribute__((address_space(3))) unsigned int*)l,
        16, 0, 0);
}

// ---------------------------------------------------------------------------
// prep_all (unchanged)
// ---------------------------------------------------------------------------
__global__ __launch_bounds__(256) void prep_all(
    const float* __restrict__ x, const float* __restrict__ Wqkv,
    const float* __restrict__ Wf, const float* __restrict__ Wo,
    const float* __restrict__ bo, const float* __restrict__ bfv,
    f16* __restrict__ xh, f16* __restrict__ wqkvh, f16* __restrict__ wfh,
    f16* __restrict__ WoT, float* __restrict__ bp)
{
    __shared__ float t[32][33];
    const int bid = blockIdx.x;
    const int tid = threadIdx.x;

    if (bid < 5632) {
        const float* in; f16* outp; int base;
        if (bid < 4096)      { in = x;    outp = xh;    base = bid; }
        else if (bid < 5248) { in = Wqkv; outp = wqkvh; base = bid - 4096; }
        else                 { in = Wf;   outp = wfh;   base = bid - 5248; }
        int i = (base * 256 + tid) * 8;
        float4 a = *(const float4*)(in + i);
        float4 b = *(const float4*)(in + i + 4);
        f16x8 h = { (f16)a.x, (f16)a.y, (f16)a.z, (f16)a.w,
                    (f16)b.x, (f16)b.y, (f16)b.z, (f16)b.w };
        *(f16x8*)(outp + i) = h;
    } else if (bid < 6400) {
        const int idx = bid - 5632;
        const int z  = idx >> 8;
        const int bx = (idx & 15) * 32;
        const int by = ((idx >> 4) & 15) * 32;
        const int tx = tid & 31;
        const int ty = tid >> 5;
#pragma unroll
        for (int r = ty; r < 32; r += 8)
            t[r][tx] = Wo[(size_t)z * 262144 + (by + r) * 512 + bx + tx];
        __syncthreads();
#pragma unroll
        for (int r = ty; r < 32; r += 8)
            WoT[(size_t)z * 262144 + (bx + r) * 512 + by + tx] = (f16)t[tx][r];
    } else {
        const int o = (bid - 6400) * 4 + (tid >> 6);
        const int lane = tid & 63;
        float s = 0.f;
        for (int j = lane; j < 1536; j += 64) s += Wf[o * 1536 + j] * bo[j];
#pragma unroll
        for (int msk = 1; msk < 64; msk <<= 1) s += __shfl_xor(s, msk, 64);
        if (lane == 0) bp[o] = s + bfv[o];
    }
}

// ---------------------------------------------------------------------------
// small 128x128 2-phase GEMM (Wfo product only)
// ---------------------------------------------------------------------------
template <typename TC>
__global__ __launch_bounds__(256) void gemm_mfma_nt(
    const f16* __restrict__ A, int lda, long azs,
    const f16* __restrict__ B, int ldb, long bzs,
    const float* __restrict__ bias,
    TC* __restrict__ C, int ldc, long czs,
    int K)
{
    __shared__ __align__(16) f16 As[2][128 * 32];
    __shared__ __align__(16) f16 Bs[2][128 * 32];

    const int tid  = threadIdx.x;
    const int lane = tid & 63;
    const int wave = tid >> 6;
    const int wm = (wave >> 1) * 64;
    const int wn = (wave & 1) * 64;
    const int bm = blockIdx.y * 128;
    const int bn = blockIdx.x * 128;
    const int z  = blockIdx.z;

    const int srow = tid >> 2;
    const int scol = (tid & 3) * 8;
    const int soff = srow * 32 + scol;

    const f16* Ag = A + (size_t)z * azs + (size_t)(bm + srow) * lda + scol;
    const f16* Bg = B + (size_t)z * bzs + (size_t)(bn + srow) * ldb + scol;

    f32x4 acc[4][4];
#pragma unroll
    for (int i = 0; i < 4; ++i)
#pragma unroll
        for (int j = 0; j < 4; ++j)
            acc[i][j] = (f32x4){0.f, 0.f, 0.f, 0.f};

    const int fr = lane & 15;
    const int fk = (lane >> 4) * 8;

    async_cp16(Ag, &As[0][soff]);
    async_cp16(Ag + (size_t)64 * lda, &As[0][soff + 64 * 32]);
    async_cp16(Bg, &Bs[0][soff]);
    async_cp16(Bg + (size_t)64 * ldb, &Bs[0][soff + 64 * 32]);

    const int nt = K >> 5;
    for (int t = 0; t < nt; ++t) {
        __syncthreads();
        const int p = t & 1;
        if (t + 1 < nt) {
            const int k1 = (t + 1) * 32;
            async_cp16(Ag + k1, &As[p ^ 1][soff]);
            async_cp16(Ag + k1 + (size_t)64 * lda, &As[p ^ 1][soff + 64 * 32]);
            async_cp16(Bg + k1, &Bs[p ^ 1][soff]);
            async_cp16(Bg + k1 + (size_t)64 * ldb, &Bs[p ^ 1][soff + 64 * 32]);
        }

        f16x8 af[4], bfr[4];
#pragma unroll
        for (int i = 0; i < 4; ++i)
            af[i] = *(const f16x8*)&As[p][(wm + i * 16 + fr) * 32 + fk];
#pragma unroll
        for (int j = 0; j < 4; ++j)
            bfr[j] = *(const f16x8*)&Bs[p][(wn + j * 16 + fr) * 32 + fk];
#pragma unroll
        for (int i = 0; i < 4; ++i)
#pragma unroll
            for (int j = 0; j < 4; ++j)
                acc[i][j] = __builtin_amdgcn_mfma_f32_16x16x32_f16(
                    af[i], bfr[j], acc[i][j], 0, 0, 0);
    }

    const int cn  = lane & 15;
    const int cr4 = (lane >> 4) * 4;
#pragma unroll
    for (int i = 0; i < 4; ++i) {
#pragma unroll
        for (int j = 0; j < 4; ++j) {
            const int col = bn + wn + j * 16 + cn;
            const float bv = bias ? bias[col] : 0.f;
#pragma unroll
            for (int r = 0; r < 4; ++r) {
                const int row = bm + wm + i * 16 + cr4 + r;
                storeC(&C[(size_t)z * czs + (size_t)row * ldc + col],
                       acc[i][j][r] + bv);
            }
        }
    }
}

// ---------------------------------------------------------------------------
// 8-phase counted-vmcnt GEMM + XCD-chunked block swizzle.
// ---------------------------------------------------------------------------
template <int NR, typename TC>
__global__ __launch_bounds__(512, 2) void gemm_mfma_8ph(
    const f16* __restrict__ A, int lda,
    const f16* __restrict__ B, int ldb, long bzs,
    const float* __restrict__ bias, long bizs,
    TC* __restrict__ C, int ldc, long czs, int K)
{
    __shared__ __align__(16) f16 As[2][256 * 64];
    __shared__ __align__(16) f16 Bs[2][NR * 64 * 64];

    const int z = blockIdx.z;
    B += (size_t)z * bzs;
    C += (size_t)z * czs;
    const float* biasz = bias ? bias + (size_t)z * bizs : nullptr;

    // XCD-chunked bijective swizzle: raw dispatch order round-robins XCDs;
    // give each XCD a contiguous chunk of the logical (by,bx) space so
    // co-resident blocks share A panels in one L2. nwg = GX*64, nwg%8==0.
    constexpr int GX   = (NR == 3) ? 8 : 4;   // grid.x
    constexpr int LGX  = (NR == 3) ? 3 : 2;   // log2(GX)
    const int raw = blockIdx.y * GX + blockIdx.x;
    const int lid = (raw & 7) * (GX * 8) + (raw >> 3);
    const int bxs = lid & (GX - 1);
    const int bys = lid >> LGX;

    const int tid  = threadIdx.x;
    const int lane = tid & 63;
    const int wave = tid >> 6;
    const int wr = wave >> 2;
    const int wc = wave & 3;
    const int bm = bys * 256;
    const int bn = bxs * (NR * 64);
    const int fr  = lane & 15;
    const int grp = lane >> 4;

    const int c0 = ((0 + grp) ^ (fr & 7)) * 8;
    const int c1 = ((4 + grp) ^ (fr & 7)) * 8;

    const int srow = tid >> 3;
    const int scol = ((tid & 7) ^ (srow & 7)) * 8;
    const f16* Ag = A + (size_t)(bm + srow) * lda + scol;
    const f16* Bg = B + (size_t)(bn + srow) * ldb + scol;

    f32x4 acc[8][NR];
#pragma unroll
    for (int m = 0; m < 8; ++m)
#pragma unroll
        for (int n = 0; n < NR; ++n)
            acc[m][n] = (f32x4){0.f, 0.f, 0.f, 0.f};

    const int arow = wr * 128 + fr;
    const int brow = wc * (NR * 16) + fr;

    f16x8 bfrag[NR][2];
    f16x8 aP[2][2], aQ[2][2];

    auto stage = [&](int p, int kt) {
        const f16* a_ = Ag + (size_t)kt * 64;
        const f16* b_ = Bg + (size_t)kt * 64;
        f16* al = &As[p][tid * 8];
        f16* bl = &Bs[p][tid * 8];
#pragma unroll
        for (int i = 0; i < 4; ++i)
            async_cp16(a_ + (size_t)(i * 64) * lda, al + i * 4096);
#pragma unroll
        for (int i = 0; i < NR; ++i)
            async_cp16(b_ + (size_t)(i * 64) * ldb, bl + i * 4096);
    };

    const int nt = K >> 6;
    stage(0, 0);
    stage(1, 1);

    for (int t = 0; t < nt; ++t) {
        const int p = t & 1;
        if (t + 1 < nt) {
            if constexpr (NR == 3)
                asm volatile("s_waitcnt vmcnt(7)" ::: "memory");
            else
                asm volatile("s_waitcnt vmcnt(6)" ::: "memory");
        } else {
            asm volatile("s_waitcnt vmcnt(0)" ::: "memory");
        }
        __builtin_amdgcn_s_barrier();

        const f16* asb = As[p];
        const f16* bsb = Bs[p];

        auto loada = [&](f16x8 (&d)[2][2], int mq) {
#pragma unroll
            for (int m2 = 0; m2 < 2; ++m2) {
                const int ro = (arow + (mq * 2 + m2) * 16) * 64;
                d[m2][0] = *(const f16x8*)&asb[ro + c0];
                d[m2][1] = *(const f16x8*)&asb[ro + c1];
            }
        };
        auto qmfma = [&](const f16x8 (&a_)[2][2], int mq) {
            __builtin_amdgcn_s_setprio(1);
#pragma unroll
            for (int m2 = 0; m2 < 2; ++m2)
#pragma unroll
                for (int n = 0; n < NR; ++n) {
                    f32x4 zz = __builtin_amdgcn_mfma_f32_16x16x32_f16(
                        a_[m2][0], bfrag[n][0], acc[mq * 2 + m2][n], 0, 0, 0);
                    acc[mq * 2 + m2][n] = __builtin_amdgcn_mfma_f32_16x16x32_f16(
                        a_[m2][1], bfrag[n][1], zz, 0, 0, 0);
                }
            __builtin_amdgcn_s_setprio(0);
        };

#pragma unroll
        for (int n = 0; n < NR; ++n) {
            const int ro = (brow + n * 16) * 64;
            bfrag[n][0] = *(const f16x8*)&bsb[ro + c0];
            bfrag[n][1] = *(const f16x8*)&bsb[ro + c1];
        }
        loada(aP, 0);
        asm volatile("s_waitcnt lgkmcnt(0)" ::: "memory");
        __builtin_amdgcn_sched_barrier(0);

        loada(aQ, 1);
        qmfma(aP, 0);
        asm volatile("s_waitcnt lgkmcnt(0)" ::: "memory");
        __builtin_amdgcn_sched_barrier(0);

        loada(aP, 2);
        qmfma(aQ, 1);
        asm volatile("s_waitcnt lgkmcnt(0)" ::: "memory");
        __builtin_amdgcn_sched_barrier(0);

        loada(aQ, 3);
        qmfma(aP, 2);
        asm volatile("s_waitcnt lgkmcnt(0)" ::: "memory");
        __builtin_amdgcn_sched_barrier(0);

        __builtin_amdgcn_s_barrier();
        if (t + 2 < nt) stage(p, t + 2);
        qmfma(aQ, 3);
    }

    const int cn  = lane & 15;
    const int cr4 = (lane >> 4) * 4;
#pragma unroll
    for (int m = 0; m < 8; ++m)
#pragma unroll
        for (int n = 0; n < NR; ++n) {
            const int col = bn + wc * (NR * 16) + n * 16 + cn;
            const float bv = biasz ? biasz[col] : 0.f;
#pragma unroll
            for (int r = 0; r < 4; ++r) {
                const int row = bm + wr * 128 + m * 16 + cr4 + r;
                storeC(&C[(size_t)row * ldc + col], acc[m][n][r] + bv);
            }
        }
}

// ---------------------------------------------------------------------------
// Windowed attention body v2 (unchanged from R13)
// ---------------------------------------------------------------------------
__device__ __forceinline__ void win_attn_body(
    const f16* __restrict__ qkv, f16* __restrict__ out, f16* sm,
    int w, int bx, int b, int h)
{
    const int tid  = threadIdx.x;
    const int lane = tid & 63;
    const int wave = tid >> 6;
    const int q0 = (bx * 4 + wave) * 16;
    const size_t bs = (size_t)b * 1024;

    const int fr  = lane & 15;
    const int grp = lane >> 4;
    const int fk8 = grp * 8;

    f16* vsw = sm + wave * 2560;

    f16x8 aq[2];
    {
        const f16* qp = qkv + (bs + q0 + fr) * 1536 + h * 64 + fk8;
        aq[0] = *(const f16x8*)qp;
        aq[1] = *(const f16x8*)(qp + 32);
#pragma unroll
        for (int e = 0; e < 8; ++e) {
            aq[0][e] *= (f16)0.18033688;
            aq[1][e] *= (f16)0.18033688;
        }
    }

    f16x8 bk[2][2];
#pragma unroll
    for (int g = 0; g < 2; ++g) {
        int krow = q0 - 16 + g * 16 + fr;
        int kcl  = krow < 0 ? 0 : krow;
        const f16* kp = qkv + (bs + kcl) * 1536 + 512 + h * 64 + fk8;
        bk[g][0] = *(const f16x8*)kp;
        bk[g][1] = *(const f16x8*)(kp + 32);
    }

    {
        const int vk = lane & 31;
        const int vd = (lane >> 5) * 32;
        int vrow = q0 - 16 + vk;
        int vcl  = vrow < 0 ? 0 : vrow;
        const f16* vp = qkv + (bs + vcl) * 1536 + 1024 + h * 64 + vd;
#pragma unroll
        for (int t = 0; t < 4; ++t) {
            f16x8 vv = *(const f16x8*)(vp + t * 8);
#pragma unroll
            for (int e = 0; e < 8; ++e)
                vsw[(vd + t * 8 + e) * 40 + vk] = vv[e];
        }
    }

    const f32x4 fz = (f32x4){0.f, 0.f, 0.f, 0.f};
    f32x4 s[2];
#pragma unroll
    for (int g = 0; g < 2; ++g) {
        f32x4 z = __builtin_amdgcn_mfma_f32_16x16x32_f16(
            bk[g][0], aq[0], fz, 0, 0, 0);
        s[g] = __builtin_amdgcn_mfma_f32_16x16x32_f16(
            bk[g][1], aq[1], z, 0, 0, 0);
    }

    unsigned int dw[2][2];
#pragma unroll
    for (int g = 0; g < 2; ++g) {
        float p[4];
#pragma unroll
        for (int r = 0; r < 4; ++r) {
            const int kin  = g * 16 + grp * 4 + r;
            const int kpos = q0 - 16 + kin;
            const int diff = fr - kin + 16;
            const bool ok = (diff >= 0) && (diff < w) && (kpos >= 0);
            p[r] = ok ? exp2f(fminf(s[g][r], 15.9f)) : 0.f;
        }
        f16x2 h0 = { (f16)p[0], (f16)p[1] };
        f16x2 h1 = { (f16)p[2], (f16)p[3] };
        dw[g][0] = __builtin_bit_cast(unsigned int, h0);
        dw[g][1] = __builtin_bit_cast(unsigned int, h1);
    }

    unsigned int pdw[4];
#pragma unroll
    for (int T = 0; T < 2; ++T) {
        unsigned int X = dw[0][T];
        unsigned int Y = dw[1][T];
        asm("v_permlane32_swap_b32 %0, %1" : "+v"(X), "+v"(Y));
        asm("v_permlane16_swap_b32 %0, %1" : "+v"(X), "+v"(Y));
        pdw[T]     = X;
        pdw[2 + T] = Y;
    }
    union { unsigned int u[4]; f16x8 hv; } cu;
    cu.u[0] = pdw[0]; cu.u[1] = pdw[1]; cu.u[2] = pdw[2]; cu.u[3] = pdw[3];
    const f16x8 paf = cu.hv;

    f16x8 onesf;
#pragma unroll
    for (int e = 0; e < 8; ++e) onesf[e] = (f16)1.0f;
    f32x4 lacc = __builtin_amdgcn_mfma_f32_16x16x32_f16(paf, onesf, fz, 0, 0, 0);

    __builtin_amdgcn_wave_barrier();

    f32x4 acc[4];
#pragma unroll
    for (int j = 0; j < 4; ++j) {
        f16x8 bv = *(const f16x8*)&vsw[(j * 16 + fr) * 40 + fk8];
        acc[j] = __builtin_amdgcn_mfma_f32_16x16x32_f16(paf, bv, fz, 0, 0, 0);
    }

    float inv[4];
#pragma unroll
    for (int r = 0; r < 4; ++r) inv[r] = 1.0f / lacc[r];
#pragma unroll
    for (int j = 0; j < 4; ++j)
#pragma unroll
        for (int r = 0; r < 4; ++r) {
            const int q = q0 + grp * 4 + r;
            out[(bs + q) * 1536 + h * 64 + j * 16 + fr] =
                (f16)(acc[j][r] * inv[r]);
        }
}

// ---------------------------------------------------------------------------
// Full attention body (unchanged from R13)
// ---------------------------------------------------------------------------
__device__ __forceinline__ void full_attn_body(
    const f16* __restrict__ qkv, f16* __restrict__ out, f16* sm,
    int bx, int b, int h)
{
    const int tid  = threadIdx.x;
    const int lane = tid & 63;
    const int wave = tid >> 6;
    const int q0 = bx * 128;
    const size_t bs = (size_t)b * 1024;

    const int fr  = lane & 15;
    const int grp = lane >> 4;
    const int fk8 = grp * 8;

    f16x8 aq[2][2];
#pragma unroll
    for (int qt = 0; qt < 2; ++qt) {
        const f16* qp = qkv + (bs + q0 + wave * 32 + qt * 16 + fr) * 1536
                        + h * 64 + fk8;
        aq[qt][0] = *(const f16x8*)qp;
        aq[qt][1] = *(const f16x8*)(qp + 32);
#pragma unroll
        for (int e = 0; e < 8; ++e) {
            aq[qt][0][e] *= (f16)0.18033688;
            aq[qt][1][e] *= (f16)0.18033688;
        }
    }

    f16x8 onesf;
#pragma unroll
    for (int e = 0; e < 8; ++e) onesf[e] = (f16)1.0f;

    const f32x4 fz = (f32x4){0.f, 0.f, 0.f, 0.f};
    f32x4 lacc[2] = {fz, fz};
    f32x4 acc[2][4];
#pragma unroll
    for (int qt = 0; qt < 2; ++qt)
#pragma unroll
        for (int j = 0; j < 4; ++j)
            acc[qt][j] = fz;

    const int kr = tid >> 2, kc = (tid & 3) * 16;
    const int kp = (tid & 31) * 2, cb = (tid >> 5) * 8;

    const f16* kgp = qkv + (bs + kr) * 1536 + 512 + h * 64 + kc;
    const f16* vgp = qkv + (bs + kp) * 1536 + 1024 + h * 64 + cb;

    f16x8 ka, kb, va, vb;
    ka = *(const f16x8*)kgp; kb = *(const f16x8*)(kgp + 8);
    va = *(const f16x8*)vgp; vb = *(const f16x8*)(vgp + 1536);

    {
        f16* ks = sm + kr * 72 + kc;
        *(f16x8*)ks = ka; *(f16x8*)(ks + 8) = kb;
        f16* vs = sm + 9216 + kp;
#pragma unroll
        for (int e = 0; e < 8; ++e) {
            f16x2 pr = { va[e], vb[e] };
            *(f16x2*)&vs[(cb + e) * 72] = pr;
        }
    }
    kgp += 64 * 1536; vgp += 64 * 1536;
    ka = *(const f16x8*)kgp; kb = *(const f16x8*)(kgp + 8);
    va = *(const f16x8*)vgp; vb = *(const f16x8*)(vgp + 1536);

    for (int t = 0; t < 16; ++t) {
        __syncthreads();
        const int p = t & 1;
        const f16* Ksp = sm + p * 4608;
        const f16* Vsp = sm + 9216 + p * 4608;

        if (t + 1 < 16) {
            f16* ks = sm + (p ^ 1) * 4608 + kr * 72 + kc;
            *(f16x8*)ks = ka; *(f16x8*)(ks + 8) = kb;
            f16* vs = sm + 9216 + (p ^ 1) * 4608 + kp;
#pragma unroll
            for (int e = 0; e < 8; ++e) {
                f16x2 pr = { va[e], vb[e] };
                *(f16x2*)&vs[(cb + e) * 72] = pr;
            }
            if (t + 2 < 16) {
                kgp += 64 * 1536; vgp += 64 * 1536;
                ka = *(const f16x8*)kgp; kb = *(const f16x8*)(kgp + 8);
                va = *(const f16x8*)vgp; vb = *(const f16x8*)(vgp + 1536);
            }
        }

        f16x8 kf[4][2];
#pragma unroll
        for (int j = 0; j < 4; ++j)
#pragma unroll
            for (int c = 0; c < 2; ++c)
                kf[j][c] = *(const f16x8*)&Ksp[(j * 16 + fr) * 72 + c * 32 + fk8];

        f16x8 paf[2][2];
#pragma unroll
        for (int qt = 0; qt < 2; ++qt) {
            f32x4 s2[4];
#pragma unroll
            for (int j = 0; j < 4; ++j) {
                f32x4 z = __builtin_amdgcn_mfma_f32_16x16x32_f16(
                        kf[j][0], aq[qt][0], fz, 0, 0, 0);
                s2[j] = __builtin_amdgcn_mfma_f32_16x16x32_f16(
                        kf[j][1], aq[qt][1], z, 0, 0, 0);
            }

            unsigned int dw[4][2];
#pragma unroll
            for (int j = 0; j < 4; ++j) {
                float p0 = exp2f(fminf(s2[j][0], 15.9f));
                float p1 = exp2f(fminf(s2[j][1], 15.9f));
                float p2 = exp2f(fminf(s2[j][2], 15.9f));
                float p3 = exp2f(fminf(s2[j][3], 15.9f));
                f16x2 h0 = { (f16)p0, (f16)p1 };
                f16x2 h1 = { (f16)p2, (f16)p3 };
                dw[j][0] = __builtin_bit_cast(unsigned int, h0);
                dw[j][1] = __builtin_bit_cast(unsigned int, h1);
            }

            unsigned int pdw[2][4];
#pragma unroll
            for (int c = 0; c < 2; ++c)
#pragma unroll
                for (int T = 0; T < 2; ++T) {
                    unsigned int X = dw[2 * c][T];
                    unsigned int Y = dw[2 * c + 1][T];
                    asm("v_permlane32_swap_b32 %0, %1" : "+v"(X), "+v"(Y));
                    asm("v_permlane16_swap_b32 %0, %1" : "+v"(X), "+v"(Y));
                    pdw[c][T]     = X;
                    pdw[c][2 + T] = Y;
                }
            union { unsigned int u[4]; f16x8 hv; } cu;
#pragma unroll
            for (int c = 0; c < 2; ++c) {
                cu.u[0] = pdw[c][0]; cu.u[1] = pdw[c][1];
                cu.u[2] = pdw[c][2]; cu.u[3] = pdw[c][3];
                paf[qt][c] = cu.hv;
            }

            lacc[qt] = __builtin_amdgcn_mfma_f32_16x16x32_f16(
                paf[qt][0], onesf, lacc[qt], 0, 0, 0);
            lacc[qt] = __builtin_amdgcn_mfma_f32_16x16x32_f16(
                paf[qt][1], onesf, lacc[qt], 0, 0, 0);
        }

        f16x8 vf[4][2];
#pragma unroll
        for (int j = 0; j < 4; ++j)
#pragma unroll
            for (int c = 0; c < 2; ++c)
                vf[j][c] = *(const f16x8*)&Vsp[(j * 16 + fr) * 72 + c * 32 + fk8];

#pragma unroll
        for (int qt = 0; qt < 2; ++qt)
#pragma unroll
            for (int j = 0; j < 4; ++j)
#pragma unroll
                for (int c = 0; c < 2; ++c)
                    acc[qt][j] = __builtin_amdgcn_mfma_f32_16x16x32_f16(
                        paf[qt][c], vf[j][c], acc[qt][j], 0, 0, 0);
    }

#pragma unroll
    for (int qt = 0; qt < 2; ++qt) {
        float inv[4];
#pragma unroll
        for (int r = 0; r < 4; ++r) inv[r] = 1.0f / lacc[qt][r];
#pragma unroll
        for (int j = 0; j < 4; ++j)
#pragma unroll
            for (int r = 0; r < 4; ++r) {
                const int q = q0 + wave * 32 + qt * 16 + grp * 4 + r;
                out[(bs + q) * 1536 + h * 64 + j * 16 + fr] =
                    (f16)(acc[qt][j][r] * inv[r]);
            }
    }
}

// ---------------------------------------------------------------------------
// standalone kernels (fallback path)
// ---------------------------------------------------------------------------
__global__ __launch_bounds__(256) void win_attn_mfma(
    const f16* __restrict__ qkv, f16* __restrict__ out, int w)
{
    __shared__ __align__(16) f16 sm[4 * 2560];
    win_attn_body(qkv, out, sm, w, blockIdx.x, blockIdx.y, blockIdx.z);
}

__global__ __launch_bounds__(256, 4) void full_attn_mfma(
    const f16* __restrict__ qkv, f16* __restrict__ out)
{
    __shared__ __align__(16) f16 sm[18432];
    full_attn_body(qkv, out, sm, blockIdx.x, blockIdx.y, blockIdx.z);
}

// ---------------------------------------------------------------------------
// fused attention (unchanged from R13)
// ---------------------------------------------------------------------------
__global__ __launch_bounds__(256, 4) void attn_all(
    const f16* __restrict__ q0b, const f16* __restrict__ q1b,
    const f16* __restrict__ q2b, f16* __restrict__ cat)
{
    __shared__ __align__(16) f16 sm[18432];
    const int bid = blockIdx.x;
    if (bid < 1024) {
        full_attn_body(q2b, cat + 1024, sm, bid & 7, (bid >> 3) & 15, bid >> 7);
    } else if (bid < 3072) {
        const int i = bid - 1024;
        win_attn_body(q0b, cat, sm, 5, i & 15, (i >> 4) & 15, i >> 8);
    } else {
        const int i = bid - 3072;
        win_attn_body(q1b, cat + 512, sm, 10, i & 15, (i >> 4) & 15, i >> 8);
    }
}

// ---------------------------------------------------------------------------
// launch
// ---------------------------------------------------------------------------
extern "C" void kernel_launch(void* const* d_in, const int* in_sizes, int n_in,
                              void* d_out, int out_size, void* d_ws, size_t ws_size,
                              hipStream_t stream)
{
    const float* x    = (const float*)d_in[0];   // [16,1024,512]
    const float* Wqkv = (const float*)d_in[1];   // [3,1536,512]
    const float* bqkv = (const float*)d_in[2];   // [3,1536]
    const float* Wo   = (const float*)d_in[3];   // [3,512,512]
    const float* bo   = (const float*)d_in[4];   // [3,512] (flat 1536)
    const float* Wf   = (const float*)d_in[5];   // [512,1536]
    const float* bfin = (const float*)d_in[6];   // [512]
    float* out = (float*)d_out;                  // [16,1024,512] fp32

    f16* xh    = (f16*)d_out;                          // 16.8 MB scratch
    f16* wqkvh = (f16*)((char*)d_out + 16777216);      // 4.7 MB scratch
    char* ws = (char*)d_ws;

    const size_t QKV_EL = 25165824;          // 16384*1536 f16 elements
    const size_t QKV_B  = 50331648;          // bytes

    const bool fused = ws_size >= (size_t)206047232;

    if (fused) {
        f16*   qkv0     = (f16*)ws;
        f16*   attn_cat = (f16*)(ws + 3 * QKV_B);
        f16*   wfh      = (f16*)(ws + 3 * QKV_B + QKV_B);
        f16*   WoT      = (f16*)((char*)wfh + 1572864);
        f16*   Wfo      = (f16*)((char*)WoT + 1572864);
        float* bp       = (float*)((char*)Wfo + 1572864);

        prep_all<<<dim3(6528), 256, 0, stream>>>(
            x, Wqkv, Wf, Wo, bo, bfin, xh, wqkvh, wfh, WoT, bp);

        gemm_mfma_nt<f16><<<dim3(4, 4, 3), 256, 0, stream>>>(
            wfh, 1536, 512, WoT, 512, 262144, nullptr, Wfo, 1536, 512, 512);

        gemm_mfma_8ph<3, f16><<<dim3(8, 64, 3), 512, 0, stream>>>(
            xh, 512, wqkvh, 512, 786432, bqkv, 1536,
            qkv0, 1536, (long)QKV_EL, 512);

        attn_all<<<dim3(5120), 256, 0, stream>>>(
            qkv0, qkv0 + QKV_EL, qkv0 + 2 * QKV_EL, attn_cat);

        gemm_mfma_8ph<2, float><<<dim3(4, 64, 1), 512, 0, stream>>>(
            attn_cat, 1536, Wfo, 1536, 0, bp, 0, out, 512, 0, 1536);
    } else {
        f16*   qkvbuf   = (f16*)ws;
        f16*   attn_cat = (f16*)(ws + QKV_B);
        f16*   wfh      = (f16*)(ws + 2 * QKV_B);
        f16*   WoT      = (f16*)(ws + 2 * QKV_B + 1572864);
        f16*   Wfo      = (f16*)(ws + 2 * QKV_B + 2 * 1572864);
        float* bp       = (float*)(ws + 2 * QKV_B + 3 * 1572864);

        prep_all<<<dim3(6528), 256, 0, stream>>>(
            x, Wqkv, Wf, Wo, bo, bfin, xh, wqkvh, wfh, WoT, bp);

        gemm_mfma_nt<f16><<<dim3(4, 4, 3), 256, 0, stream>>>(
            wfh, 1536, 512, WoT, 512, 262144, nullptr, Wfo, 1536, 512, 512);

        for (int i = 0; i < 3; ++i) {
            gemm_mfma_8ph<3, f16><<<dim3(8, 64, 1), 512, 0, stream>>>(
                xh, 512, wqkvh + (size_t)i * 786432, 512, 0,
                bqkv + i * 1536, 0, qkvbuf, 1536, 0, 512);

            if (i == 0)
                win_attn_mfma<<<dim3(16, 16, 8), 256, 0, stream>>>(
                    qkvbuf, attn_cat + 0 * 512, 5);
            else if (i == 1)
                win_attn_mfma<<<dim3(16, 16, 8), 256, 0, stream>>>(
                    qkvbuf, attn_cat + 1 * 512, 10);
            else
                full_attn_mfma<<<dim3(8, 16, 8), 256, 0, stream>>>(
                    qkvbuf, attn_cat + 2 * 512);
        }

        gemm_mfma_8ph<2, float><<<dim3(4, 64, 1), 512, 0, stream>>>(
            attn_cat, 1536, Wfo, 1536, 0, bp, 0, out, 512, 0, 1536);
    }
}

// Round 10
// 331.700 us; speedup vs baseline: 1.3818x; 1.0120x over previous
//
#include <hip/hip_runtime.h>
#include <hip/hip_bf16.h>
#include <hip/hip_fp16.h>

// R16 = R15 with the compile bug fixed: full_attn_body's kf[4][2] declaration
// + load loop had been accidentally dropped (referenced undeclared -> hipcc
// error -> "container failed twice"). Restored; everything else identical.
//
// R15 change under test: gemm_mfma_8ph re-tiled BM=256 -> 128 for 2 blocks/CU.
//   R14 counters: qkv GEMM no longer fetch-bound (61.6MB, 1.88TB/s) but
//   nothing saturated (Mfma 28.5 / VALU 23.6 / Occ 21.6) -> latency-bound at
//   1 block/CU. Fix: BM=128 (LDS 80/64KB), launch_bounds(512,4) -> 2
//   blocks/CU, 16 waves/CU; cross-block overlap hides staging/prologue/
//   epilogue. Same k-order -> bit-identical. vmcnt 5/4. XCD swizzle
//   re-derived for grid.y=128 (bijective; 2.6MB/XCD < 4MiB L2).

using f16 = _Float16;
typedef _Float16 f16x8 __attribute__((ext_vector_type(8)));
typedef _Float16 f16x2 __attribute__((ext_vector_type(2)));
typedef float    f32x4 __attribute__((ext_vector_type(4)));

__device__ inline void storeC(float* p, float v) { *p = v; }
__device__ inline void storeC(f16* p, float v)   { *p = (f16)v; }

__device__ inline void async_cp16(const f16* g, f16* l) {
    __builtin_amdgcn_global_load_lds(
        (const __attribute__((address_space(1))) unsigned int*)g,
        (__attribute__((address_space(3))) unsigned int*)l,
        16, 0, 0);
}

// ---------------------------------------------------------------------------
// prep_all (unchanged)
// ---------------------------------------------------------------------------
__global__ __launch_bounds__(256) void prep_all(
    const float* __restrict__ x, const float* __restrict__ Wqkv,
    const float* __restrict__ Wf, const float* __restrict__ Wo,
    const float* __restrict__ bo, const float* __restrict__ bfv,
    f16* __restrict__ xh, f16* __restrict__ wqkvh, f16* __restrict__ wfh,
    f16* __restrict__ WoT, float* __restrict__ bp)
{
    __shared__ float t[32][33];
    const int bid = blockIdx.x;
    const int tid = threadIdx.x;

    if (bid < 5632) {
        const float* in; f16* outp; int base;
        if (bid < 4096)      { in = x;    outp = xh;    base = bid; }
        else if (bid < 5248) { in = Wqkv; outp = wqkvh; base = bid - 4096; }
        else                 { in = Wf;   outp = wfh;   base = bid - 5248; }
        int i = (base * 256 + tid) * 8;
        float4 a = *(const float4*)(in + i);
        float4 b = *(const float4*)(in + i + 4);
        f16x8 h = { (f16)a.x, (f16)a.y, (f16)a.z, (f16)a.w,
                    (f16)b.x, (f16)b.y, (f16)b.z, (f16)b.w };
        *(f16x8*)(outp + i) = h;
    } else if (bid < 6400) {
        const int idx = bid - 5632;
        const int z  = idx >> 8;
        const int bx = (idx & 15) * 32;
        const int by = ((idx >> 4) & 15) * 32;
        const int tx = tid & 31;
        const int ty = tid >> 5;
#pragma unroll
        for (int r = ty; r < 32; r += 8)
            t[r][tx] = Wo[(size_t)z * 262144 + (by + r) * 512 + bx + tx];
        __syncthreads();
#pragma unroll
        for (int r = ty; r < 32; r += 8)
            WoT[(size_t)z * 262144 + (bx + r) * 512 + by + tx] = (f16)t[tx][r];
    } else {
        const int o = (bid - 6400) * 4 + (tid >> 6);
        const int lane = tid & 63;
        float s = 0.f;
        for (int j = lane; j < 1536; j += 64) s += Wf[o * 1536 + j] * bo[j];
#pragma unroll
        for (int msk = 1; msk < 64; msk <<= 1) s += __shfl_xor(s, msk, 64);
        if (lane == 0) bp[o] = s + bfv[o];
    }
}

// ---------------------------------------------------------------------------
// small 128x128 2-phase GEMM (Wfo product only)
// ---------------------------------------------------------------------------
template <typename TC>
__global__ __launch_bounds__(256) void gemm_mfma_nt(
    const f16* __restrict__ A, int lda, long azs,
    const f16* __restrict__ B, int ldb, long bzs,
    const float* __restrict__ bias,
    TC* __restrict__ C, int ldc, long czs,
    int K)
{
    __shared__ __align__(16) f16 As[2][128 * 32];
    __shared__ __align__(16) f16 Bs[2][128 * 32];

    const int tid  = threadIdx.x;
    const int lane = tid & 63;
    const int wave = tid >> 6;
    const int wm = (wave >> 1) * 64;
    const int wn = (wave & 1) * 64;
    const int bm = blockIdx.y * 128;
    const int bn = blockIdx.x * 128;
    const int z  = blockIdx.z;

    const int srow = tid >> 2;
    const int scol = (tid & 3) * 8;
    const int soff = srow * 32 + scol;

    const f16* Ag = A + (size_t)z * azs + (size_t)(bm + srow) * lda + scol;
    const f16* Bg = B + (size_t)z * bzs + (size_t)(bn + srow) * ldb + scol;

    f32x4 acc[4][4];
#pragma unroll
    for (int i = 0; i < 4; ++i)
#pragma unroll
        for (int j = 0; j < 4; ++j)
            acc[i][j] = (f32x4){0.f, 0.f, 0.f, 0.f};

    const int fr = lane & 15;
    const int fk = (lane >> 4) * 8;

    async_cp16(Ag, &As[0][soff]);
    async_cp16(Ag + (size_t)64 * lda, &As[0][soff + 64 * 32]);
    async_cp16(Bg, &Bs[0][soff]);
    async_cp16(Bg + (size_t)64 * ldb, &Bs[0][soff + 64 * 32]);

    const int nt = K >> 5;
    for (int t = 0; t < nt; ++t) {
        __syncthreads();
        const int p = t & 1;
        if (t + 1 < nt) {
            const int k1 = (t + 1) * 32;
            async_cp16(Ag + k1, &As[p ^ 1][soff]);
            async_cp16(Ag + k1 + (size_t)64 * lda, &As[p ^ 1][soff + 64 * 32]);
            async_cp16(Bg + k1, &Bs[p ^ 1][soff]);
            async_cp16(Bg + k1 + (size_t)64 * ldb, &Bs[p ^ 1][soff + 64 * 32]);
        }

        f16x8 af[4], bfr[4];
#pragma unroll
        for (int i = 0; i < 4; ++i)
            af[i] = *(const f16x8*)&As[p][(wm + i * 16 + fr) * 32 + fk];
#pragma unroll
        for (int j = 0; j < 4; ++j)
            bfr[j] = *(const f16x8*)&Bs[p][(wn + j * 16 + fr) * 32 + fk];
#pragma unroll
        for (int i = 0; i < 4; ++i)
#pragma unroll
            for (int j = 0; j < 4; ++j)
                acc[i][j] = __builtin_amdgcn_mfma_f32_16x16x32_f16(
                    af[i], bfr[j], acc[i][j], 0, 0, 0);
    }

    const int cn  = lane & 15;
    const int cr4 = (lane >> 4) * 4;
#pragma unroll
    for (int i = 0; i < 4; ++i) {
#pragma unroll
        for (int j = 0; j < 4; ++j) {
            const int col = bn + wn + j * 16 + cn;
            const float bv = bias ? bias[col] : 0.f;
#pragma unroll
            for (int r = 0; r < 4; ++r) {
                const int row = bm + wm + i * 16 + cr4 + r;
                storeC(&C[(size_t)z * czs + (size_t)row * ldc + col],
                       acc[i][j][r] + bv);
            }
        }
    }
}

// ---------------------------------------------------------------------------
// 8-phase counted-vmcnt GEMM, BM=128, 2 blocks/CU, XCD-chunked swizzle.
// BN = NR*64. grid = (GX, 128, z); GX = 8 (NR=3) or 4 (NR=2).
// ---------------------------------------------------------------------------
template <int NR, typename TC>
__global__ __launch_bounds__(512, 4) void gemm_mfma_8ph(
    const f16* __restrict__ A, int lda,
    const f16* __restrict__ B, int ldb, long bzs,
    const float* __restrict__ bias, long bizs,
    TC* __restrict__ C, int ldc, long czs, int K)
{
    __shared__ __align__(16) f16 As[2][128 * 64];
    __shared__ __align__(16) f16 Bs[2][NR * 64 * 64];

    const int z = blockIdx.z;
    B += (size_t)z * bzs;
    C += (size_t)z * czs;
    const float* biasz = bias ? bias + (size_t)z * bizs : nullptr;

    // XCD-chunked bijective swizzle; nwg = GX*128, nwg%8==0.
    constexpr int GX   = (NR == 3) ? 8 : 4;
    constexpr int LGX  = (NR == 3) ? 3 : 2;
    const int raw = blockIdx.y * GX + blockIdx.x;
    const int lid = (raw & 7) * (GX * 16) + (raw >> 3);
    const int bxs = lid & (GX - 1);
    const int bys = lid >> LGX;

    const int tid  = threadIdx.x;
    const int lane = tid & 63;
    const int wave = tid >> 6;
    const int wr = wave >> 2;            // 0..1 (M wave, 64 rows each)
    const int wc = wave & 3;             // 0..3 (N wave, NR*16 cols each)
    const int bm = bys * 128;
    const int bn = bxs * (NR * 64);
    const int fr  = lane & 15;
    const int grp = lane >> 4;

    const int c0 = ((0 + grp) ^ (fr & 7)) * 8;
    const int c1 = ((4 + grp) ^ (fr & 7)) * 8;

    const int srow = tid >> 3;
    const int scol = ((tid & 7) ^ (srow & 7)) * 8;
    const f16* Ag = A + (size_t)(bm + srow) * lda + scol;
    const f16* Bg = B + (size_t)(bn + srow) * ldb + scol;

    f32x4 acc[4][NR];
#pragma unroll
    for (int m = 0; m < 4; ++m)
#pragma unroll
        for (int n = 0; n < NR; ++n)
            acc[m][n] = (f32x4){0.f, 0.f, 0.f, 0.f};

    const int arow = wr * 64 + fr;
    const int brow = wc * (NR * 16) + fr;

    f16x8 bfrag[NR][2];
    f16x8 aP[2], aQ[2];

    auto stage = [&](int p, int kt) {
        const f16* a_ = Ag + (size_t)kt * 64;
        const f16* b_ = Bg + (size_t)kt * 64;
        f16* al = &As[p][tid * 8];
        f16* bl = &Bs[p][tid * 8];
#pragma unroll
        for (int i = 0; i < 2; ++i)
            async_cp16(a_ + (size_t)(i * 64) * lda, al + i * 4096);
#pragma unroll
        for (int i = 0; i < NR; ++i)
            async_cp16(b_ + (size_t)(i * 64) * ldb, bl + i * 4096);
    };

    const int nt = K >> 6;
    stage(0, 0);
    stage(1, 1);

    for (int t = 0; t < nt; ++t) {
        const int p = t & 1;
        if (t + 1 < nt) {
            // one tile (2+NR loads) in flight across the compute
            if constexpr (NR == 3)
                asm volatile("s_waitcnt vmcnt(5)" ::: "memory");
            else
                asm volatile("s_waitcnt vmcnt(4)" ::: "memory");
        } else {
            asm volatile("s_waitcnt vmcnt(0)" ::: "memory");
        }
        __builtin_amdgcn_s_barrier();

        const f16* asb = As[p];
        const f16* bsb = Bs[p];

        auto loada = [&](f16x8 (&d)[2], int m) {
            const int ro = (arow + m * 16) * 64;
            d[0] = *(const f16x8*)&asb[ro + c0];
            d[1] = *(const f16x8*)&asb[ro + c1];
        };
        auto qmfma = [&](const f16x8 (&a_)[2], int m) {
            __builtin_amdgcn_s_setprio(1);
#pragma unroll
            for (int n = 0; n < NR; ++n) {
                f32x4 zz = __builtin_amdgcn_mfma_f32_16x16x32_f16(
                    a_[0], bfrag[n][0], acc[m][n], 0, 0, 0);
                acc[m][n] = __builtin_amdgcn_mfma_f32_16x16x32_f16(
                    a_[1], bfrag[n][1], zz, 0, 0, 0);
            }
            __builtin_amdgcn_s_setprio(0);
        };

#pragma unroll
        for (int n = 0; n < NR; ++n) {
            const int ro = (brow + n * 16) * 64;
            bfrag[n][0] = *(const f16x8*)&bsb[ro + c0];
            bfrag[n][1] = *(const f16x8*)&bsb[ro + c1];
        }
        loada(aP, 0);
        asm volatile("s_waitcnt lgkmcnt(0)" ::: "memory");
        __builtin_amdgcn_sched_barrier(0);

        loada(aQ, 1);
        qmfma(aP, 0);
        asm volatile("s_waitcnt lgkmcnt(0)" ::: "memory");
        __builtin_amdgcn_sched_barrier(0);

        loada(aP, 2);
        qmfma(aQ, 1);
        asm volatile("s_waitcnt lgkmcnt(0)" ::: "memory");
        __builtin_amdgcn_sched_barrier(0);

        loada(aQ, 3);
        qmfma(aP, 2);
        asm volatile("s_waitcnt lgkmcnt(0)" ::: "memory");
        __builtin_amdgcn_sched_barrier(0);

        __builtin_amdgcn_s_barrier();
        if (t + 2 < nt) stage(p, t + 2);
        qmfma(aQ, 3);
    }

    const int cn  = lane & 15;
    const int cr4 = (lane >> 4) * 4;
#pragma unroll
    for (int m = 0; m < 4; ++m)
#pragma unroll
        for (int n = 0; n < NR; ++n) {
            const int col = bn + wc * (NR * 16) + n * 16 + cn;
            const float bv = biasz ? biasz[col] : 0.f;
#pragma unroll
            for (int r = 0; r < 4; ++r) {
                const int row = bm + wr * 64 + m * 16 + cr4 + r;
                storeC(&C[(size_t)row * ldc + col], acc[m][n][r] + bv);
            }
        }
}

// ---------------------------------------------------------------------------
// Windowed attention body v2 (unchanged)
// ---------------------------------------------------------------------------
__device__ __forceinline__ void win_attn_body(
    const f16* __restrict__ qkv, f16* __restrict__ out, f16* sm,
    int w, int bx, int b, int h)
{
    const int tid  = threadIdx.x;
    const int lane = tid & 63;
    const int wave = tid >> 6;
    const int q0 = (bx * 4 + wave) * 16;
    const size_t bs = (size_t)b * 1024;

    const int fr  = lane & 15;
    const int grp = lane >> 4;
    const int fk8 = grp * 8;

    f16* vsw = sm + wave * 2560;

    f16x8 aq[2];
    {
        const f16* qp = qkv + (bs + q0 + fr) * 1536 + h * 64 + fk8;
        aq[0] = *(const f16x8*)qp;
        aq[1] = *(const f16x8*)(qp + 32);
#pragma unroll
        for (int e = 0; e < 8; ++e) {
            aq[0][e] *= (f16)0.18033688;
            aq[1][e] *= (f16)0.18033688;
        }
    }

    f16x8 bk[2][2];
#pragma unroll
    for (int g = 0; g < 2; ++g) {
        int krow = q0 - 16 + g * 16 + fr;
        int kcl  = krow < 0 ? 0 : krow;
        const f16* kp = qkv + (bs + kcl) * 1536 + 512 + h * 64 + fk8;
        bk[g][0] = *(const f16x8*)kp;
        bk[g][1] = *(const f16x8*)(kp + 32);
    }

    {
        const int vk = lane & 31;
        const int vd = (lane >> 5) * 32;
        int vrow = q0 - 16 + vk;
        int vcl  = vrow < 0 ? 0 : vrow;
        const f16* vp = qkv + (bs + vcl) * 1536 + 1024 + h * 64 + vd;
#pragma unroll
        for (int t = 0; t < 4; ++t) {
            f16x8 vv = *(const f16x8*)(vp + t * 8);
#pragma unroll
            for (int e = 0; e < 8; ++e)
                vsw[(vd + t * 8 + e) * 40 + vk] = vv[e];
        }
    }

    const f32x4 fz = (f32x4){0.f, 0.f, 0.f, 0.f};
    f32x4 s[2];
#pragma unroll
    for (int g = 0; g < 2; ++g) {
        f32x4 z = __builtin_amdgcn_mfma_f32_16x16x32_f16(
            bk[g][0], aq[0], fz, 0, 0, 0);
        s[g] = __builtin_amdgcn_mfma_f32_16x16x32_f16(
            bk[g][1], aq[1], z, 0, 0, 0);
    }

    unsigned int dw[2][2];
#pragma unroll
    for (int g = 0; g < 2; ++g) {
        float p[4];
#pragma unroll
        for (int r = 0; r < 4; ++r) {
            const int kin  = g * 16 + grp * 4 + r;
            const int kpos = q0 - 16 + kin;
            const int diff = fr - kin + 16;
            const bool ok = (diff >= 0) && (diff < w) && (kpos >= 0);
            p[r] = ok ? exp2f(fminf(s[g][r], 15.9f)) : 0.f;
        }
        f16x2 h0 = { (f16)p[0], (f16)p[1] };
        f16x2 h1 = { (f16)p[2], (f16)p[3] };
        dw[g][0] = __builtin_bit_cast(unsigned int, h0);
        dw[g][1] = __builtin_bit_cast(unsigned int, h1);
    }

    unsigned int pdw[4];
#pragma unroll
    for (int T = 0; T < 2; ++T) {
        unsigned int X = dw[0][T];
        unsigned int Y = dw[1][T];
        asm("v_permlane32_swap_b32 %0, %1" : "+v"(X), "+v"(Y));
        asm("v_permlane16_swap_b32 %0, %1" : "+v"(X), "+v"(Y));
        pdw[T]     = X;
        pdw[2 + T] = Y;
    }
    union { unsigned int u[4]; f16x8 hv; } cu;
    cu.u[0] = pdw[0]; cu.u[1] = pdw[1]; cu.u[2] = pdw[2]; cu.u[3] = pdw[3];
    const f16x8 paf = cu.hv;

    f16x8 onesf;
#pragma unroll
    for (int e = 0; e < 8; ++e) onesf[e] = (f16)1.0f;
    f32x4 lacc = __builtin_amdgcn_mfma_f32_16x16x32_f16(paf, onesf, fz, 0, 0, 0);

    __builtin_amdgcn_wave_barrier();

    f32x4 acc[4];
#pragma unroll
    for (int j = 0; j < 4; ++j) {
        f16x8 bv = *(const f16x8*)&vsw[(j * 16 + fr) * 40 + fk8];
        acc[j] = __builtin_amdgcn_mfma_f32_16x16x32_f16(paf, bv, fz, 0, 0, 0);
    }

    float inv[4];
#pragma unroll
    for (int r = 0; r < 4; ++r) inv[r] = 1.0f / lacc[r];
#pragma unroll
    for (int j = 0; j < 4; ++j)
#pragma unroll
        for (int r = 0; r < 4; ++r) {
            const int q = q0 + grp * 4 + r;
            out[(bs + q) * 1536 + h * 64 + j * 16 + fr] =
                (f16)(acc[j][r] * inv[r]);
        }
}

// ---------------------------------------------------------------------------
// Full attention body (R13 version, kf block restored)
// ---------------------------------------------------------------------------
__device__ __forceinline__ void full_attn_body(
    const f16* __restrict__ qkv, f16* __restrict__ out, f16* sm,
    int bx, int b, int h)
{
    const int tid  = threadIdx.x;
    const int lane = tid & 63;
    const int wave = tid >> 6;
    const int q0 = bx * 128;
    const size_t bs = (size_t)b * 1024;

    const int fr  = lane & 15;
    const int grp = lane >> 4;
    const int fk8 = grp * 8;

    f16x8 aq[2][2];
#pragma unroll
    for (int qt = 0; qt < 2; ++qt) {
        const f16* qp = qkv + (bs + q0 + wave * 32 + qt * 16 + fr) * 1536
                        + h * 64 + fk8;
        aq[qt][0] = *(const f16x8*)qp;
        aq[qt][1] = *(const f16x8*)(qp + 32);
#pragma unroll
        for (int e = 0; e < 8; ++e) {
            aq[qt][0][e] *= (f16)0.18033688;
            aq[qt][1][e] *= (f16)0.18033688;
        }
    }

    f16x8 onesf;
#pragma unroll
    for (int e = 0; e < 8; ++e) onesf[e] = (f16)1.0f;

    const f32x4 fz = (f32x4){0.f, 0.f, 0.f, 0.f};
    f32x4 lacc[2] = {fz, fz};
    f32x4 acc[2][4];
#pragma unroll
    for (int qt = 0; qt < 2; ++qt)
#pragma unroll
        for (int j = 0; j < 4; ++j)
            acc[qt][j] = fz;

    const int kr = tid >> 2, kc = (tid & 3) * 16;
    const int kp = (tid & 31) * 2, cb = (tid >> 5) * 8;

    const f16* kgp = qkv + (bs + kr) * 1536 + 512 + h * 64 + kc;
    const f16* vgp = qkv + (bs + kp) * 1536 + 1024 + h * 64 + cb;

    f16x8 ka, kb, va, vb;
    ka = *(const f16x8*)kgp; kb = *(const f16x8*)(kgp + 8);
    va = *(const f16x8*)vgp; vb = *(const f16x8*)(vgp + 1536);

    {
        f16* ks = sm + kr * 72 + kc;
        *(f16x8*)ks = ka; *(f16x8*)(ks + 8) = kb;
        f16* vs = sm + 9216 + kp;
#pragma unroll
        for (int e = 0; e < 8; ++e) {
            f16x2 pr = { va[e], vb[e] };
            *(f16x2*)&vs[(cb + e) * 72] = pr;
        }
    }
    kgp += 64 * 1536; vgp += 64 * 1536;
    ka = *(const f16x8*)kgp; kb = *(const f16x8*)(kgp + 8);
    va = *(const f16x8*)vgp; vb = *(const f16x8*)(vgp + 1536);

    for (int t = 0; t < 16; ++t) {
        __syncthreads();
        const int p = t & 1;
        const f16* Ksp = sm + p * 4608;
        const f16* Vsp = sm + 9216 + p * 4608;

        if (t + 1 < 16) {
            f16* ks = sm + (p ^ 1) * 4608 + kr * 72 + kc;
            *(f16x8*)ks = ka; *(f16x8*)(ks + 8) = kb;
            f16* vs = sm + 9216 + (p ^ 1) * 4608 + kp;
#pragma unroll
            for (int e = 0; e < 8; ++e) {
                f16x2 pr = { va[e], vb[e] };
                *(f16x2*)&vs[(cb + e) * 72] = pr;
            }
            if (t + 2 < 16) {
                kgp += 64 * 1536; vgp += 64 * 1536;
                ka = *(const f16x8*)kgp; kb = *(const f16x8*)(kgp + 8);
                va = *(const f16x8*)vgp; vb = *(const f16x8*)(vgp + 1536);
            }
        }

        // hoisted K fragments (qt-invariant): K[j*16+fr][c*32 + grp*8 + e]
        f16x8 kf[4][2];
#pragma unroll
        for (int j = 0; j < 4; ++j)
#pragma unroll
            for (int c = 0; c < 2; ++c)
                kf[j][c] = *(const f16x8*)&Ksp[(j * 16 + fr) * 72 + c * 32 + fk8];

        f16x8 paf[2][2];
#pragma unroll
        for (int qt = 0; qt < 2; ++qt) {
            f32x4 s2[4];
#pragma unroll
            for (int j = 0; j < 4; ++j) {
                f32x4 z = __builtin_amdgcn_mfma_f32_16x16x32_f16(
                        kf[j][0], aq[qt][0], fz, 0, 0, 0);
                s2[j] = __builtin_amdgcn_mfma_f32_16x16x32_f16(
                        kf[j][1], aq[qt][1], z, 0, 0, 0);
            }

            unsigned int dw[4][2];
#pragma unroll
            for (int j = 0; j < 4; ++j) {
                float p0 = exp2f(fminf(s2[j][0], 15.9f));
                float p1 = exp2f(fminf(s2[j][1], 15.9f));
                float p2 = exp2f(fminf(s2[j][2], 15.9f));
                float p3 = exp2f(fminf(s2[j][3], 15.9f));
                f16x2 h0 = { (f16)p0, (f16)p1 };
                f16x2 h1 = { (f16)p2, (f16)p3 };
                dw[j][0] = __builtin_bit_cast(unsigned int, h0);
                dw[j][1] = __builtin_bit_cast(unsigned int, h1);
            }

            unsigned int pdw[2][4];
#pragma unroll
            for (int c = 0; c < 2; ++c)
#pragma unroll
                for (int T = 0; T < 2; ++T) {
                    unsigned int X = dw[2 * c][T];
                    unsigned int Y = dw[2 * c + 1][T];
                    asm("v_permlane32_swap_b32 %0, %1" : "+v"(X), "+v"(Y));
                    asm("v_permlane16_swap_b32 %0, %1" : "+v"(X), "+v"(Y));
                    pdw[c][T]     = X;
                    pdw[c][2 + T] = Y;
                }
            union { unsigned int u[4]; f16x8 hv; } cu;
#pragma unroll
            for (int c = 0; c < 2; ++c) {
                cu.u[0] = pdw[c][0]; cu.u[1] = pdw[c][1];
                cu.u[2] = pdw[c][2]; cu.u[3] = pdw[c][3];
                paf[qt][c] = cu.hv;
            }

            lacc[qt] = __builtin_amdgcn_mfma_f32_16x16x32_f16(
                paf[qt][0], onesf, lacc[qt], 0, 0, 0);
            lacc[qt] = __builtin_amdgcn_mfma_f32_16x16x32_f16(
                paf[qt][1], onesf, lacc[qt], 0, 0, 0);
        }

        f16x8 vf[4][2];
#pragma unroll
        for (int j = 0; j < 4; ++j)
#pragma unroll
            for (int c = 0; c < 2; ++c)
                vf[j][c] = *(const f16x8*)&Vsp[(j * 16 + fr) * 72 + c * 32 + fk8];

#pragma unroll
        for (int qt = 0; qt < 2; ++qt)
#pragma unroll
            for (int j = 0; j < 4; ++j)
#pragma unroll
                for (int c = 0; c < 2; ++c)
                    acc[qt][j] = __builtin_amdgcn_mfma_f32_16x16x32_f16(
                        paf[qt][c], vf[j][c], acc[qt][j], 0, 0, 0);
    }

#pragma unroll
    for (int qt = 0; qt < 2; ++qt) {
        float inv[4];
#pragma unroll
        for (int r = 0; r < 4; ++r) inv[r] = 1.0f / lacc[qt][r];
#pragma unroll
        for (int j = 0; j < 4; ++j)
#pragma unroll
            for (int r = 0; r < 4; ++r) {
                const int q = q0 + wave * 32 + qt * 16 + grp * 4 + r;
                out[(bs + q) * 1536 + h * 64 + j * 16 + fr] =
                    (f16)(acc[qt][j][r] * inv[r]);
            }
    }
}

// ---------------------------------------------------------------------------
// standalone kernels (fallback path)
// ---------------------------------------------------------------------------
__global__ __launch_bounds__(256) void win_attn_mfma(
    const f16* __restrict__ qkv, f16* __restrict__ out, int w)
{
    __shared__ __align__(16) f16 sm[4 * 2560];
    win_attn_body(qkv, out, sm, w, blockIdx.x, blockIdx.y, blockIdx.z);
}

__global__ __launch_bounds__(256, 4) void full_attn_mfma(
    const f16* __restrict__ qkv, f16* __restrict__ out)
{
    __shared__ __align__(16) f16 sm[18432];
    full_attn_body(qkv, out, sm, blockIdx.x, blockIdx.y, blockIdx.z);
}

// ---------------------------------------------------------------------------
// fused attention (unchanged)
// ---------------------------------------------------------------------------
__global__ __launch_bounds__(256, 4) void attn_all(
    const f16* __restrict__ q0b, const f16* __restrict__ q1b,
    const f16* __restrict__ q2b, f16* __restrict__ cat)
{
    __shared__ __align__(16) f16 sm[18432];
    const int bid = blockIdx.x;
    if (bid < 1024) {
        full_attn_body(q2b, cat + 1024, sm, bid & 7, (bid >> 3) & 15, bid >> 7);
    } else if (bid < 3072) {
        const int i = bid - 1024;
        win_attn_body(q0b, cat, sm, 5, i & 15, (i >> 4) & 15, i >> 8);
    } else {
        const int i = bid - 3072;
        win_attn_body(q1b, cat + 512, sm, 10, i & 15, (i >> 4) & 15, i >> 8);
    }
}

// ---------------------------------------------------------------------------
// launch
// ---------------------------------------------------------------------------
extern "C" void kernel_launch(void* const* d_in, const int* in_sizes, int n_in,
                              void* d_out, int out_size, void* d_ws, size_t ws_size,
                              hipStream_t stream)
{
    const float* x    = (const float*)d_in[0];   // [16,1024,512]
    const float* Wqkv = (const float*)d_in[1];   // [3,1536,512]
    const float* bqkv = (const float*)d_in[2];   // [3,1536]
    const float* Wo   = (const float*)d_in[3];   // [3,512,512]
    const float* bo   = (const float*)d_in[4];   // [3,512] (flat 1536)
    const float* Wf   = (const float*)d_in[5];   // [512,1536]
    const float* bfin = (const float*)d_in[6];   // [512]
    float* out = (float*)d_out;                  // [16,1024,512] fp32

    f16* xh    = (f16*)d_out;                          // 16.8 MB scratch
    f16* wqkvh = (f16*)((char*)d_out + 16777216);      // 4.7 MB scratch
    char* ws = (char*)d_ws;

    const size_t QKV_EL = 25165824;          // 16384*1536 f16 elements
    const size_t QKV_B  = 50331648;          // bytes

    const bool fused = ws_size >= (size_t)206047232;

    if (fused) {
        f16*   qkv0     = (f16*)ws;
        f16*   attn_cat = (f16*)(ws + 3 * QKV_B);
        f16*   wfh      = (f16*)(ws + 3 * QKV_B + QKV_B);
        f16*   WoT      = (f16*)((char*)wfh + 1572864);
        f16*   Wfo      = (f16*)((char*)WoT + 1572864);
        float* bp       = (float*)((char*)Wfo + 1572864);

        prep_all<<<dim3(6528), 256, 0, stream>>>(
            x, Wqkv, Wf, Wo, bo, bfin, xh, wqkvh, wfh, WoT, bp);

        gemm_mfma_nt<f16><<<dim3(4, 4, 3), 256, 0, stream>>>(
            wfh, 1536, 512, WoT, 512, 262144, nullptr, Wfo, 1536, 512, 512);

        gemm_mfma_8ph<3, f16><<<dim3(8, 128, 3), 512, 0, stream>>>(
            xh, 512, wqkvh, 512, 786432, bqkv, 1536,
            qkv0, 1536, (long)QKV_EL, 512);

        attn_all<<<dim3(5120), 256, 0, stream>>>(
            qkv0, qkv0 + QKV_EL, qkv0 + 2 * QKV_EL, attn_cat);

        gemm_mfma_8ph<2, float><<<dim3(4, 128, 1), 512, 0, stream>>>(
            attn_cat, 1536, Wfo, 1536, 0, bp, 0, out, 512, 0, 1536);
    } else {
        f16*   qkvbuf   = (f16*)ws;
        f16*   attn_cat = (f16*)(ws + QKV_B);
        f16*   wfh      = (f16*)(ws + 2 * QKV_B);
        f16*   WoT      = (f16*)(ws + 2 * QKV_B + 1572864);
        f16*   Wfo      = (f16*)(ws + 2 * QKV_B + 2 * 1572864);
        float* bp       = (float*)(ws + 2 * QKV_B + 3 * 1572864);

        prep_all<<<dim3(6528), 256, 0, stream>>>(
            x, Wqkv, Wf, Wo, bo, bfin, xh, wqkvh, wfh, WoT, bp);

        gemm_mfma_nt<f16><<<dim3(4, 4, 3), 256, 0, stream>>>(
            wfh, 1536, 512, WoT, 512, 262144, nullptr, Wfo, 1536, 512, 512);

        for (int i = 0; i < 3; ++i) {
            gemm_mfma_8ph<3, f16><<<dim3(8, 128, 1), 512, 0, stream>>>(
                xh, 512, wqkvh + (size_t)i * 786432, 512, 0,
                bqkv + i * 1536, 0, qkvbuf, 1536, 0, 512);

            if (i == 0)
                win_attn_mfma<<<dim3(16, 16, 8), 256, 0, stream>>>(
                    qkvbuf, attn_cat + 0 * 512, 5);
            else if (i == 1)
                win_attn_mfma<<<dim3(16, 16, 8), 256, 0, stream>>>(
                    qkvbuf, attn_cat + 1 * 512, 10);
            else
                full_attn_mfma<<<dim3(8, 16, 8), 256, 0, stream>>>(
                    qkvbuf, attn_cat + 2 * 512);
        }

        gemm_mfma_8ph<2, float><<<dim3(4, 128, 1), 512, 0, stream>>>(
            attn_cat, 1536, Wfo, 1536, 0, bp, 0, out, 512, 0, 1536);
    }
}

// Round 11
// 329.357 us; speedup vs baseline: 1.3916x; 1.0071x over previous
//
#include <hip/hip_runtime.h>
#include <hip/hip_bf16.h>
#include <hip/hip_fp16.h>

// R17: gemm_mfma_8ph gains compile-time trip count NT + full unroll.
//   R16 counters: qkv GEMM 100us with MfmaUtil 33.5 / VALUBusy 32.2 — VALU
//   co-binding. Cause: runtime nt -> per-iteration address recompute (~14
//   ds_read addrs), runtime-p LDS base select, runtime boundary guards
//   (~60-80 VALU/wave/K-step vs 120cyc MFMA). Fix: template<NT> + full
//   unroll -> addresses loop-invariant, p/guards compile-time. Bit-identical
//   (same ops, same k-order). qkv NT=8, final NT=24.
// Everything else unchanged from R16.

using f16 = _Float16;
typedef _Float16 f16x8 __attribute__((ext_vector_type(8)));
typedef _Float16 f16x2 __attribute__((ext_vector_type(2)));
typedef float    f32x4 __attribute__((ext_vector_type(4)));

__device__ inline void storeC(float* p, float v) { *p = v; }
__device__ inline void storeC(f16* p, float v)   { *p = (f16)v; }

__device__ inline void async_cp16(const f16* g, f16* l) {
    __builtin_amdgcn_global_load_lds(
        (const __attribute__((address_space(1))) unsigned int*)g,
        (__attribute__((address_space(3))) unsigned int*)l,
        16, 0, 0);
}

// ---------------------------------------------------------------------------
// prep_all (unchanged)
// ---------------------------------------------------------------------------
__global__ __launch_bounds__(256) void prep_all(
    const float* __restrict__ x, const float* __restrict__ Wqkv,
    const float* __restrict__ Wf, const float* __restrict__ Wo,
    const float* __restrict__ bo, const float* __restrict__ bfv,
    f16* __restrict__ xh, f16* __restrict__ wqkvh, f16* __restrict__ wfh,
    f16* __restrict__ WoT, float* __restrict__ bp)
{
    __shared__ float t[32][33];
    const int bid = blockIdx.x;
    const int tid = threadIdx.x;

    if (bid < 5632) {
        const float* in; f16* outp; int base;
        if (bid < 4096)      { in = x;    outp = xh;    base = bid; }
        else if (bid < 5248) { in = Wqkv; outp = wqkvh; base = bid - 4096; }
        else                 { in = Wf;   outp = wfh;   base = bid - 5248; }
        int i = (base * 256 + tid) * 8;
        float4 a = *(const float4*)(in + i);
        float4 b = *(const float4*)(in + i + 4);
        f16x8 h = { (f16)a.x, (f16)a.y, (f16)a.z, (f16)a.w,
                    (f16)b.x, (f16)b.y, (f16)b.z, (f16)b.w };
        *(f16x8*)(outp + i) = h;
    } else if (bid < 6400) {
        const int idx = bid - 5632;
        const int z  = idx >> 8;
        const int bx = (idx & 15) * 32;
        const int by = ((idx >> 4) & 15) * 32;
        const int tx = tid & 31;
        const int ty = tid >> 5;
#pragma unroll
        for (int r = ty; r < 32; r += 8)
            t[r][tx] = Wo[(size_t)z * 262144 + (by + r) * 512 + bx + tx];
        __syncthreads();
#pragma unroll
        for (int r = ty; r < 32; r += 8)
            WoT[(size_t)z * 262144 + (bx + r) * 512 + by + tx] = (f16)t[tx][r];
    } else {
        const int o = (bid - 6400) * 4 + (tid >> 6);
        const int lane = tid & 63;
        float s = 0.f;
        for (int j = lane; j < 1536; j += 64) s += Wf[o * 1536 + j] * bo[j];
#pragma unroll
        for (int msk = 1; msk < 64; msk <<= 1) s += __shfl_xor(s, msk, 64);
        if (lane == 0) bp[o] = s + bfv[o];
    }
}

// ---------------------------------------------------------------------------
// small 128x128 2-phase GEMM (Wfo product only)
// ---------------------------------------------------------------------------
template <typename TC>
__global__ __launch_bounds__(256) void gemm_mfma_nt(
    const f16* __restrict__ A, int lda, long azs,
    const f16* __restrict__ B, int ldb, long bzs,
    const float* __restrict__ bias,
    TC* __restrict__ C, int ldc, long czs,
    int K)
{
    __shared__ __align__(16) f16 As[2][128 * 32];
    __shared__ __align__(16) f16 Bs[2][128 * 32];

    const int tid  = threadIdx.x;
    const int lane = tid & 63;
    const int wave = tid >> 6;
    const int wm = (wave >> 1) * 64;
    const int wn = (wave & 1) * 64;
    const int bm = blockIdx.y * 128;
    const int bn = blockIdx.x * 128;
    const int z  = blockIdx.z;

    const int srow = tid >> 2;
    const int scol = (tid & 3) * 8;
    const int soff = srow * 32 + scol;

    const f16* Ag = A + (size_t)z * azs + (size_t)(bm + srow) * lda + scol;
    const f16* Bg = B + (size_t)z * bzs + (size_t)(bn + srow) * ldb + scol;

    f32x4 acc[4][4];
#pragma unroll
    for (int i = 0; i < 4; ++i)
#pragma unroll
        for (int j = 0; j < 4; ++j)
            acc[i][j] = (f32x4){0.f, 0.f, 0.f, 0.f};

    const int fr = lane & 15;
    const int fk = (lane >> 4) * 8;

    async_cp16(Ag, &As[0][soff]);
    async_cp16(Ag + (size_t)64 * lda, &As[0][soff + 64 * 32]);
    async_cp16(Bg, &Bs[0][soff]);
    async_cp16(Bg + (size_t)64 * ldb, &Bs[0][soff + 64 * 32]);

    const int nt = K >> 5;
    for (int t = 0; t < nt; ++t) {
        __syncthreads();
        const int p = t & 1;
        if (t + 1 < nt) {
            const int k1 = (t + 1) * 32;
            async_cp16(Ag + k1, &As[p ^ 1][soff]);
            async_cp16(Ag + k1 + (size_t)64 * lda, &As[p ^ 1][soff + 64 * 32]);
            async_cp16(Bg + k1, &Bs[p ^ 1][soff]);
            async_cp16(Bg + k1 + (size_t)64 * ldb, &Bs[p ^ 1][soff + 64 * 32]);
        }

        f16x8 af[4], bfr[4];
#pragma unroll
        for (int i = 0; i < 4; ++i)
            af[i] = *(const f16x8*)&As[p][(wm + i * 16 + fr) * 32 + fk];
#pragma unroll
        for (int j = 0; j < 4; ++j)
            bfr[j] = *(const f16x8*)&Bs[p][(wn + j * 16 + fr) * 32 + fk];
#pragma unroll
        for (int i = 0; i < 4; ++i)
#pragma unroll
            for (int j = 0; j < 4; ++j)
                acc[i][j] = __builtin_amdgcn_mfma_f32_16x16x32_f16(
                    af[i], bfr[j], acc[i][j], 0, 0, 0);
    }

    const int cn  = lane & 15;
    const int cr4 = (lane >> 4) * 4;
#pragma unroll
    for (int i = 0; i < 4; ++i) {
#pragma unroll
        for (int j = 0; j < 4; ++j) {
            const int col = bn + wn + j * 16 + cn;
            const float bv = bias ? bias[col] : 0.f;
#pragma unroll
            for (int r = 0; r < 4; ++r) {
                const int row = bm + wm + i * 16 + cr4 + r;
                storeC(&C[(size_t)z * czs + (size_t)row * ldc + col],
                       acc[i][j][r] + bv);
            }
        }
    }
}

// ---------------------------------------------------------------------------
// 8-phase counted-vmcnt GEMM, BM=128, 2 blocks/CU, XCD-chunked swizzle,
// compile-time NT (= K/64) with fully unrolled main loop.
// BN = NR*64. grid = (GX, 128, z); GX = 8 (NR=3) or 4 (NR=2).
// ---------------------------------------------------------------------------
template <int NR, int NT, typename TC>
__global__ __launch_bounds__(512, 4) void gemm_mfma_8ph(
    const f16* __restrict__ A, int lda,
    const f16* __restrict__ B, int ldb, long bzs,
    const float* __restrict__ bias, long bizs,
    TC* __restrict__ C, int ldc, long czs)
{
    __shared__ __align__(16) f16 As[2][128 * 64];
    __shared__ __align__(16) f16 Bs[2][NR * 64 * 64];

    const int z = blockIdx.z;
    B += (size_t)z * bzs;
    C += (size_t)z * czs;
    const float* biasz = bias ? bias + (size_t)z * bizs : nullptr;

    // XCD-chunked bijective swizzle; nwg = GX*128, nwg%8==0.
    constexpr int GX   = (NR == 3) ? 8 : 4;
    constexpr int LGX  = (NR == 3) ? 3 : 2;
    const int raw = blockIdx.y * GX + blockIdx.x;
    const int lid = (raw & 7) * (GX * 16) + (raw >> 3);
    const int bxs = lid & (GX - 1);
    const int bys = lid >> LGX;

    const int tid  = threadIdx.x;
    const int lane = tid & 63;
    const int wave = tid >> 6;
    const int wr = wave >> 2;            // 0..1 (M wave, 64 rows each)
    const int wc = wave & 3;             // 0..3 (N wave, NR*16 cols each)
    const int bm = bys * 128;
    const int bn = bxs * (NR * 64);
    const int fr  = lane & 15;
    const int grp = lane >> 4;

    const int c0 = ((0 + grp) ^ (fr & 7)) * 8;
    const int c1 = ((4 + grp) ^ (fr & 7)) * 8;

    const int srow = tid >> 3;
    const int scol = ((tid & 7) ^ (srow & 7)) * 8;
    const f16* Ag = A + (size_t)(bm + srow) * lda + scol;
    const f16* Bg = B + (size_t)(bn + srow) * ldb + scol;

    f32x4 acc[4][NR];
#pragma unroll
    for (int m = 0; m < 4; ++m)
#pragma unroll
        for (int n = 0; n < NR; ++n)
            acc[m][n] = (f32x4){0.f, 0.f, 0.f, 0.f};

    const int arow = wr * 64 + fr;
    const int brow = wc * (NR * 16) + fr;

    f16x8 bfrag[NR][2];
    f16x8 aP[2], aQ[2];

    auto stage = [&](int p, int kt) {
        const f16* a_ = Ag + (size_t)kt * 64;
        const f16* b_ = Bg + (size_t)kt * 64;
        f16* al = &As[p][tid * 8];
        f16* bl = &Bs[p][tid * 8];
#pragma unroll
        for (int i = 0; i < 2; ++i)
            async_cp16(a_ + (size_t)(i * 64) * lda, al + i * 4096);
#pragma unroll
        for (int i = 0; i < NR; ++i)
            async_cp16(b_ + (size_t)(i * 64) * ldb, bl + i * 4096);
    };

    stage(0, 0);
    stage(1, 1);

#pragma unroll
    for (int t = 0; t < NT; ++t) {
        constexpr int unused = 0; (void)unused;
        const int p = t & 1;            // compile-time after unroll
        if (t + 1 < NT) {
            // one tile (2+NR loads) in flight across the compute
            if constexpr (NR == 3)
                asm volatile("s_waitcnt vmcnt(5)" ::: "memory");
            else
                asm volatile("s_waitcnt vmcnt(4)" ::: "memory");
        } else {
            asm volatile("s_waitcnt vmcnt(0)" ::: "memory");
        }
        __builtin_amdgcn_s_barrier();

        const f16* asb = As[p];
        const f16* bsb = Bs[p];

        auto loada = [&](f16x8 (&d)[2], int m) {
            const int ro = (arow + m * 16) * 64;
            d[0] = *(const f16x8*)&asb[ro + c0];
            d[1] = *(const f16x8*)&asb[ro + c1];
        };
        auto qmfma = [&](const f16x8 (&a_)[2], int m) {
            __builtin_amdgcn_s_setprio(1);
#pragma unroll
            for (int n = 0; n < NR; ++n) {
                f32x4 zz = __builtin_amdgcn_mfma_f32_16x16x32_f16(
                    a_[0], bfrag[n][0], acc[m][n], 0, 0, 0);
                acc[m][n] = __builtin_amdgcn_mfma_f32_16x16x32_f16(
                    a_[1], bfrag[n][1], zz, 0, 0, 0);
            }
            __builtin_amdgcn_s_setprio(0);
        };

#pragma unroll
        for (int n = 0; n < NR; ++n) {
            const int ro = (brow + n * 16) * 64;
            bfrag[n][0] = *(const f16x8*)&bsb[ro + c0];
            bfrag[n][1] = *(const f16x8*)&bsb[ro + c1];
        }
        loada(aP, 0);
        asm volatile("s_waitcnt lgkmcnt(0)" ::: "memory");
        __builtin_amdgcn_sched_barrier(0);

        loada(aQ, 1);
        qmfma(aP, 0);
        asm volatile("s_waitcnt lgkmcnt(0)" ::: "memory");
        __builtin_amdgcn_sched_barrier(0);

        loada(aP, 2);
        qmfma(aQ, 1);
        asm volatile("s_waitcnt lgkmcnt(0)" ::: "memory");
        __builtin_amdgcn_sched_barrier(0);

        loada(aQ, 3);
        qmfma(aP, 2);
        asm volatile("s_waitcnt lgkmcnt(0)" ::: "memory");
        __builtin_amdgcn_sched_barrier(0);

        __builtin_amdgcn_s_barrier();
        if (t + 2 < NT) stage(p, t + 2);
        qmfma(aQ, 3);
    }

    const int cn  = lane & 15;
    const int cr4 = (lane >> 4) * 4;
#pragma unroll
    for (int m = 0; m < 4; ++m)
#pragma unroll
        for (int n = 0; n < NR; ++n) {
            const int col = bn + wc * (NR * 16) + n * 16 + cn;
            const float bv = biasz ? biasz[col] : 0.f;
#pragma unroll
            for (int r = 0; r < 4; ++r) {
                const int row = bm + wr * 64 + m * 16 + cr4 + r;
                storeC(&C[(size_t)row * ldc + col], acc[m][n][r] + bv);
            }
        }
}

// ---------------------------------------------------------------------------
// Windowed attention body v2 (unchanged)
// ---------------------------------------------------------------------------
__device__ __forceinline__ void win_attn_body(
    const f16* __restrict__ qkv, f16* __restrict__ out, f16* sm,
    int w, int bx, int b, int h)
{
    const int tid  = threadIdx.x;
    const int lane = tid & 63;
    const int wave = tid >> 6;
    const int q0 = (bx * 4 + wave) * 16;
    const size_t bs = (size_t)b * 1024;

    const int fr  = lane & 15;
    const int grp = lane >> 4;
    const int fk8 = grp * 8;

    f16* vsw = sm + wave * 2560;

    f16x8 aq[2];
    {
        const f16* qp = qkv + (bs + q0 + fr) * 1536 + h * 64 + fk8;
        aq[0] = *(const f16x8*)qp;
        aq[1] = *(const f16x8*)(qp + 32);
#pragma unroll
        for (int e = 0; e < 8; ++e) {
            aq[0][e] *= (f16)0.18033688;
            aq[1][e] *= (f16)0.18033688;
        }
    }

    f16x8 bk[2][2];
#pragma unroll
    for (int g = 0; g < 2; ++g) {
        int krow = q0 - 16 + g * 16 + fr;
        int kcl  = krow < 0 ? 0 : krow;
        const f16* kp = qkv + (bs + kcl) * 1536 + 512 + h * 64 + fk8;
        bk[g][0] = *(const f16x8*)kp;
        bk[g][1] = *(const f16x8*)(kp + 32);
    }

    {
        const int vk = lane & 31;
        const int vd = (lane >> 5) * 32;
        int vrow = q0 - 16 + vk;
        int vcl  = vrow < 0 ? 0 : vrow;
        const f16* vp = qkv + (bs + vcl) * 1536 + 1024 + h * 64 + vd;
#pragma unroll
        for (int t = 0; t < 4; ++t) {
            f16x8 vv = *(const f16x8*)(vp + t * 8);
#pragma unroll
            for (int e = 0; e < 8; ++e)
                vsw[(vd + t * 8 + e) * 40 + vk] = vv[e];
        }
    }

    const f32x4 fz = (f32x4){0.f, 0.f, 0.f, 0.f};
    f32x4 s[2];
#pragma unroll
    for (int g = 0; g < 2; ++g) {
        f32x4 z = __builtin_amdgcn_mfma_f32_16x16x32_f16(
            bk[g][0], aq[0], fz, 0, 0, 0);
        s[g] = __builtin_amdgcn_mfma_f32_16x16x32_f16(
            bk[g][1], aq[1], z, 0, 0, 0);
    }

    unsigned int dw[2][2];
#pragma unroll
    for (int g = 0; g < 2; ++g) {
        float p[4];
#pragma unroll
        for (int r = 0; r < 4; ++r) {
            const int kin  = g * 16 + grp * 4 + r;
            const int kpos = q0 - 16 + kin;
            const int diff = fr - kin + 16;
            const bool ok = (diff >= 0) && (diff < w) && (kpos >= 0);
            p[r] = ok ? exp2f(fminf(s[g][r], 15.9f)) : 0.f;
        }
        f16x2 h0 = { (f16)p[0], (f16)p[1] };
        f16x2 h1 = { (f16)p[2], (f16)p[3] };
        dw[g][0] = __builtin_bit_cast(unsigned int, h0);
        dw[g][1] = __builtin_bit_cast(unsigned int, h1);
    }

    unsigned int pdw[4];
#pragma unroll
    for (int T = 0; T < 2; ++T) {
        unsigned int X = dw[0][T];
        unsigned int Y = dw[1][T];
        asm("v_permlane32_swap_b32 %0, %1" : "+v"(X), "+v"(Y));
        asm("v_permlane16_swap_b32 %0, %1" : "+v"(X), "+v"(Y));
        pdw[T]     = X;
        pdw[2 + T] = Y;
    }
    union { unsigned int u[4]; f16x8 hv; } cu;
    cu.u[0] = pdw[0]; cu.u[1] = pdw[1]; cu.u[2] = pdw[2]; cu.u[3] = pdw[3];
    const f16x8 paf = cu.hv;

    f16x8 onesf;
#pragma unroll
    for (int e = 0; e < 8; ++e) onesf[e] = (f16)1.0f;
    f32x4 lacc = __builtin_amdgcn_mfma_f32_16x16x32_f16(paf, onesf, fz, 0, 0, 0);

    __builtin_amdgcn_wave_barrier();

    f32x4 acc[4];
#pragma unroll
    for (int j = 0; j < 4; ++j) {
        f16x8 bv = *(const f16x8*)&vsw[(j * 16 + fr) * 40 + fk8];
        acc[j] = __builtin_amdgcn_mfma_f32_16x16x32_f16(paf, bv, fz, 0, 0, 0);
    }

    float inv[4];
#pragma unroll
    for (int r = 0; r < 4; ++r) inv[r] = 1.0f / lacc[r];
#pragma unroll
    for (int j = 0; j < 4; ++j)
#pragma unroll
        for (int r = 0; r < 4; ++r) {
            const int q = q0 + grp * 4 + r;
            out[(bs + q) * 1536 + h * 64 + j * 16 + fr] =
                (f16)(acc[j][r] * inv[r]);
        }
}

// ---------------------------------------------------------------------------
// Full attention body (unchanged)
// ---------------------------------------------------------------------------
__device__ __forceinline__ void full_attn_body(
    const f16* __restrict__ qkv, f16* __restrict__ out, f16* sm,
    int bx, int b, int h)
{
    const int tid  = threadIdx.x;
    const int lane = tid & 63;
    const int wave = tid >> 6;
    const int q0 = bx * 128;
    const size_t bs = (size_t)b * 1024;

    const int fr  = lane & 15;
    const int grp = lane >> 4;
    const int fk8 = grp * 8;

    f16x8 aq[2][2];
#pragma unroll
    for (int qt = 0; qt < 2; ++qt) {
        const f16* qp = qkv + (bs + q0 + wave * 32 + qt * 16 + fr) * 1536
                        + h * 64 + fk8;
        aq[qt][0] = *(const f16x8*)qp;
        aq[qt][1] = *(const f16x8*)(qp + 32);
#pragma unroll
        for (int e = 0; e < 8; ++e) {
            aq[qt][0][e] *= (f16)0.18033688;
            aq[qt][1][e] *= (f16)0.18033688;
        }
    }

    f16x8 onesf;
#pragma unroll
    for (int e = 0; e < 8; ++e) onesf[e] = (f16)1.0f;

    const f32x4 fz = (f32x4){0.f, 0.f, 0.f, 0.f};
    f32x4 lacc[2] = {fz, fz};
    f32x4 acc[2][4];
#pragma unroll
    for (int qt = 0; qt < 2; ++qt)
#pragma unroll
        for (int j = 0; j < 4; ++j)
            acc[qt][j] = fz;

    const int kr = tid >> 2, kc = (tid & 3) * 16;
    const int kp = (tid & 31) * 2, cb = (tid >> 5) * 8;

    const f16* kgp = qkv + (bs + kr) * 1536 + 512 + h * 64 + kc;
    const f16* vgp = qkv + (bs + kp) * 1536 + 1024 + h * 64 + cb;

    f16x8 ka, kb, va, vb;
    ka = *(const f16x8*)kgp; kb = *(const f16x8*)(kgp + 8);
    va = *(const f16x8*)vgp; vb = *(const f16x8*)(vgp + 1536);

    {
        f16* ks = sm + kr * 72 + kc;
        *(f16x8*)ks = ka; *(f16x8*)(ks + 8) = kb;
        f16* vs = sm + 9216 + kp;
#pragma unroll
        for (int e = 0; e < 8; ++e) {
            f16x2 pr = { va[e], vb[e] };
            *(f16x2*)&vs[(cb + e) * 72] = pr;
        }
    }
    kgp += 64 * 1536; vgp += 64 * 1536;
    ka = *(const f16x8*)kgp; kb = *(const f16x8*)(kgp + 8);
    va = *(const f16x8*)vgp; vb = *(const f16x8*)(vgp + 1536);

    for (int t = 0; t < 16; ++t) {
        __syncthreads();
        const int p = t & 1;
        const f16* Ksp = sm + p * 4608;
        const f16* Vsp = sm + 9216 + p * 4608;

        if (t + 1 < 16) {
            f16* ks = sm + (p ^ 1) * 4608 + kr * 72 + kc;
            *(f16x8*)ks = ka; *(f16x8*)(ks + 8) = kb;
            f16* vs = sm + 9216 + (p ^ 1) * 4608 + kp;
#pragma unroll
            for (int e = 0; e < 8; ++e) {
                f16x2 pr = { va[e], vb[e] };
                *(f16x2*)&vs[(cb + e) * 72] = pr;
            }
            if (t + 2 < 16) {
                kgp += 64 * 1536; vgp += 64 * 1536;
                ka = *(const f16x8*)kgp; kb = *(const f16x8*)(kgp + 8);
                va = *(const f16x8*)vgp; vb = *(const f16x8*)(vgp + 1536);
            }
        }

        // hoisted K fragments (qt-invariant): K[j*16+fr][c*32 + grp*8 + e]
        f16x8 kf[4][2];
#pragma unroll
        for (int j = 0; j < 4; ++j)
#pragma unroll
            for (int c = 0; c < 2; ++c)
                kf[j][c] = *(const f16x8*)&Ksp[(j * 16 + fr) * 72 + c * 32 + fk8];

        f16x8 paf[2][2];
#pragma unroll
        for (int qt = 0; qt < 2; ++qt) {
            f32x4 s2[4];
#pragma unroll
            for (int j = 0; j < 4; ++j) {
                f32x4 z = __builtin_amdgcn_mfma_f32_16x16x32_f16(
                        kf[j][0], aq[qt][0], fz, 0, 0, 0);
                s2[j] = __builtin_amdgcn_mfma_f32_16x16x32_f16(
                        kf[j][1], aq[qt][1], z, 0, 0, 0);
            }

            unsigned int dw[4][2];
#pragma unroll
            for (int j = 0; j < 4; ++j) {
                float p0 = exp2f(fminf(s2[j][0], 15.9f));
                float p1 = exp2f(fminf(s2[j][1], 15.9f));
                float p2 = exp2f(fminf(s2[j][2], 15.9f));
                float p3 = exp2f(fminf(s2[j][3], 15.9f));
                f16x2 h0 = { (f16)p0, (f16)p1 };
                f16x2 h1 = { (f16)p2, (f16)p3 };
                dw[j][0] = __builtin_bit_cast(unsigned int, h0);
                dw[j][1] = __builtin_bit_cast(unsigned int, h1);
            }

            unsigned int pdw[2][4];
#pragma unroll
            for (int c = 0; c < 2; ++c)
#pragma unroll
                for (int T = 0; T < 2; ++T) {
                    unsigned int X = dw[2 * c][T];
                    unsigned int Y = dw[2 * c + 1][T];
                    asm("v_permlane32_swap_b32 %0, %1" : "+v"(X), "+v"(Y));
                    asm("v_permlane16_swap_b32 %0, %1" : "+v"(X), "+v"(Y));
                    pdw[c][T]     = X;
                    pdw[c][2 + T] = Y;
                }
            union { unsigned int u[4]; f16x8 hv; } cu;
#pragma unroll
            for (int c = 0; c < 2; ++c) {
                cu.u[0] = pdw[c][0]; cu.u[1] = pdw[c][1];
                cu.u[2] = pdw[c][2]; cu.u[3] = pdw[c][3];
                paf[qt][c] = cu.hv;
            }

            lacc[qt] = __builtin_amdgcn_mfma_f32_16x16x32_f16(
                paf[qt][0], onesf, lacc[qt], 0, 0, 0);
            lacc[qt] = __builtin_amdgcn_mfma_f32_16x16x32_f16(
                paf[qt][1], onesf, lacc[qt], 0, 0, 0);
        }

        f16x8 vf[4][2];
#pragma unroll
        for (int j = 0; j < 4; ++j)
#pragma unroll
            for (int c = 0; c < 2; ++c)
                vf[j][c] = *(const f16x8*)&Vsp[(j * 16 + fr) * 72 + c * 32 + fk8];

#pragma unroll
        for (int qt = 0; qt < 2; ++qt)
#pragma unroll
            for (int j = 0; j < 4; ++j)
#pragma unroll
                for (int c = 0; c < 2; ++c)
                    acc[qt][j] = __builtin_amdgcn_mfma_f32_16x16x32_f16(
                        paf[qt][c], vf[j][c], acc[qt][j], 0, 0, 0);
    }

#pragma unroll
    for (int qt = 0; qt < 2; ++qt) {
        float inv[4];
#pragma unroll
        for (int r = 0; r < 4; ++r) inv[r] = 1.0f / lacc[qt][r];
#pragma unroll
        for (int j = 0; j < 4; ++j)
#pragma unroll
            for (int r = 0; r < 4; ++r) {
                const int q = q0 + wave * 32 + qt * 16 + grp * 4 + r;
                out[(bs + q) * 1536 + h * 64 + j * 16 + fr] =
                    (f16)(acc[qt][j][r] * inv[r]);
            }
    }
}

// ---------------------------------------------------------------------------
// standalone kernels (fallback path)
// ---------------------------------------------------------------------------
__global__ __launch_bounds__(256) void win_attn_mfma(
    const f16* __restrict__ qkv, f16* __restrict__ out, int w)
{
    __shared__ __align__(16) f16 sm[4 * 2560];
    win_attn_body(qkv, out, sm, w, blockIdx.x, blockIdx.y, blockIdx.z);
}

__global__ __launch_bounds__(256, 4) void full_attn_mfma(
    const f16* __restrict__ qkv, f16* __restrict__ out)
{
    __shared__ __align__(16) f16 sm[18432];
    full_attn_body(qkv, out, sm, blockIdx.x, blockIdx.y, blockIdx.z);
}

// ---------------------------------------------------------------------------
// fused attention (unchanged)
// ---------------------------------------------------------------------------
__global__ __launch_bounds__(256, 4) void attn_all(
    const f16* __restrict__ q0b, const f16* __restrict__ q1b,
    const f16* __restrict__ q2b, f16* __restrict__ cat)
{
    __shared__ __align__(16) f16 sm[18432];
    const int bid = blockIdx.x;
    if (bid < 1024) {
        full_attn_body(q2b, cat + 1024, sm, bid & 7, (bid >> 3) & 15, bid >> 7);
    } else if (bid < 3072) {
        const int i = bid - 1024;
        win_attn_body(q0b, cat, sm, 5, i & 15, (i >> 4) & 15, i >> 8);
    } else {
        const int i = bid - 3072;
        win_attn_body(q1b, cat + 512, sm, 10, i & 15, (i >> 4) & 15, i >> 8);
    }
}

// ---------------------------------------------------------------------------
// launch
// ---------------------------------------------------------------------------
extern "C" void kernel_launch(void* const* d_in, const int* in_sizes, int n_in,
                              void* d_out, int out_size, void* d_ws, size_t ws_size,
                              hipStream_t stream)
{
    const float* x    = (const float*)d_in[0];   // [16,1024,512]
    const float* Wqkv = (const float*)d_in[1];   // [3,1536,512]
    const float* bqkv = (const float*)d_in[2];   // [3,1536]
    const float* Wo   = (const float*)d_in[3];   // [3,512,512]
    const float* bo   = (const float*)d_in[4];   // [3,512] (flat 1536)
    const float* Wf   = (const float*)d_in[5];   // [512,1536]
    const float* bfin = (const float*)d_in[6];   // [512]
    float* out = (float*)d_out;                  // [16,1024,512] fp32

    f16* xh    = (f16*)d_out;                          // 16.8 MB scratch
    f16* wqkvh = (f16*)((char*)d_out + 16777216);      // 4.7 MB scratch
    char* ws = (char*)d_ws;

    const size_t QKV_EL = 25165824;          // 16384*1536 f16 elements
    const size_t QKV_B  = 50331648;          // bytes

    const bool fused = ws_size >= (size_t)206047232;

    if (fused) {
        f16*   qkv0     = (f16*)ws;
        f16*   attn_cat = (f16*)(ws + 3 * QKV_B);
        f16*   wfh      = (f16*)(ws + 3 * QKV_B + QKV_B);
        f16*   WoT      = (f16*)((char*)wfh + 1572864);
        f16*   Wfo      = (f16*)((char*)WoT + 1572864);
        float* bp       = (float*)((char*)Wfo + 1572864);

        prep_all<<<dim3(6528), 256, 0, stream>>>(
            x, Wqkv, Wf, Wo, bo, bfin, xh, wqkvh, wfh, WoT, bp);

        gemm_mfma_nt<f16><<<dim3(4, 4, 3), 256, 0, stream>>>(
            wfh, 1536, 512, WoT, 512, 262144, nullptr, Wfo, 1536, 512, 512);

        gemm_mfma_8ph<3, 8, f16><<<dim3(8, 128, 3), 512, 0, stream>>>(
            xh, 512, wqkvh, 512, 786432, bqkv, 1536,
            qkv0, 1536, (long)QKV_EL);

        attn_all<<<dim3(5120), 256, 0, stream>>>(
            qkv0, qkv0 + QKV_EL, qkv0 + 2 * QKV_EL, attn_cat);

        gemm_mfma_8ph<2, 24, float><<<dim3(4, 128, 1), 512, 0, stream>>>(
            attn_cat, 1536, Wfo, 1536, 0, bp, 0, out, 512, 0);
    } else {
        f16*   qkvbuf   = (f16*)ws;
        f16*   attn_cat = (f16*)(ws + QKV_B);
        f16*   wfh      = (f16*)(ws + 2 * QKV_B);
        f16*   WoT      = (f16*)(ws + 2 * QKV_B + 1572864);
        f16*   Wfo      = (f16*)(ws + 2 * QKV_B + 2 * 1572864);
        float* bp       = (float*)(ws + 2 * QKV_B + 3 * 1572864);

        prep_all<<<dim3(6528), 256, 0, stream>>>(
            x, Wqkv, Wf, Wo, bo, bfin, xh, wqkvh, wfh, WoT, bp);

        gemm_mfma_nt<f16><<<dim3(4, 4, 3), 256, 0, stream>>>(
            wfh, 1536, 512, WoT, 512, 262144, nullptr, Wfo, 1536, 512, 512);

        for (int i = 0; i < 3; ++i) {
            gemm_mfma_8ph<3, 8, f16><<<dim3(8, 128, 1), 512, 0, stream>>>(
                xh, 512, wqkvh + (size_t)i * 786432, 512, 0,
                bqkv + i * 1536, 0, qkvbuf, 1536, 0);

            if (i == 0)
                win_attn_mfma<<<dim3(16, 16, 8), 256, 0, stream>>>(
                    qkvbuf, attn_cat + 0 * 512, 5);
            else if (i == 1)
                win_attn_mfma<<<dim3(16, 16, 8), 256, 0, stream>>>(
                    qkvbuf, attn_cat + 1 * 512, 10);
            else
                full_attn_mfma<<<dim3(8, 16, 8), 256, 0, stream>>>(
                    qkvbuf, attn_cat + 2 * 512);
        }

        gemm_mfma_8ph<2, 24, float><<<dim3(4, 128, 1), 512, 0, stream>>>(
            attn_cat, 1536, Wfo, 1536, 0, bp, 0, out, 512, 0);
    }
}